// Round 17
// baseline (472.434 us; speedup 1.0000x reference)
//
#include <hip/hip_runtime.h>
#include <hip/hip_bf16.h>
#include <math.h>

#define D_MODEL   2048
#define D_INNER   4096
#define NHEADS    64
#define HEAD_DIM  64
#define D_STATE   128
#define CHUNK     256
#define CONV_DIM  (D_INNER + 2*D_STATE)            // 4352
#define D_IN_PROJ (2*D_INNER + 2*D_STATE + NHEADS) // 8512
#define LD_ZX     8704                             // D_IN_PROJ padded to 256
#define BATCH     2
#define SEQ       2048
#define NCHUNK    (SEQ/CHUNK)                      // 8
#define EPS_RMS   1e-5f
#define MROWS     4096
#define TSTRIDE   ((size_t)MROWS * 512)            // tail-partial plane stride (f32 elems)

typedef unsigned short u16;
typedef __attribute__((ext_vector_type(8))) unsigned short u16x8;
typedef __attribute__((ext_vector_type(4))) unsigned short u16x4;
typedef __attribute__((ext_vector_type(8))) short bf16x8;   // MFMA A/B frag (8 bf16)
typedef __attribute__((ext_vector_type(4))) float f32x4;    // MFMA C/D frag

__device__ __forceinline__ float us2f(u16 u){
    union { unsigned int i; float f; } c; c.i = ((unsigned int)u) << 16; return c.f;
}
__device__ __forceinline__ u16 f2us(float f){
    union { float f; unsigned int i; } c; c.f = f;
    unsigned int r = c.i + 0x7FFFu + ((c.i >> 16) & 1u);
    return (u16)(r >> 16);
}
__device__ __forceinline__ float siluf(float x){ return x / (1.f + expf(-x)); }

__device__ __forceinline__ void gload_lds16(const void* g, void* l) {
    __builtin_amdgcn_global_load_lds((const __attribute__((address_space(1))) void*)g,
                                     (__attribute__((address_space(3))) void*)l, 16, 0, 0);
}

#define VMCNT(n) asm volatile("s_waitcnt vmcnt(" #n ")" ::: "memory")

// stage one 128x64 bf16 half-tile (row-major, stride ldk) into LDS with T2 swizzle.
__device__ __forceinline__ void stage_half(const u16* __restrict__ g, size_t ldk,
                                           u16* ldsbase, int w, int lane)
{
    #pragma unroll
    for (int cc = 0; cc < 2; cc++) {
        int cb = cc * 512 + w * 64;          // wave-uniform chunk base
        int ci = cb + lane;
        int sc = ci ^ ((ci >> 3) & 7);       // swizzled source chunk (involution)
        gload_lds16(&g[(size_t)(sc >> 3) * ldk + (sc & 7) * 8], ldsbase + cb * 8);
    }
}

// ---------- fused preprocessing: hbf cvt + W_in/W_out transpose+cvt ----------
// grid = 8192 (cvt) + 4352 (WtIn 32x136) + 2048 (WtOut 64x32)
__global__ __launch_bounds__(256)
void prep_kernel(const float* __restrict__ hidden, u16* __restrict__ hbf,
                 const float* __restrict__ W_in, u16* __restrict__ WtIn,
                 const float* __restrict__ W_out, u16* __restrict__ WtOut)
{
    __shared__ u16 tile[64][65];
    int bid = blockIdx.x;
    int t = threadIdx.x;
    if (bid < 8192) {                      // hbf = bf16(hidden), 4 f32/thread
        int i = bid * 256 + t;
        float4 v = *(const float4*)&hidden[(size_t)i * 4];
        u16x4 o; o[0]=f2us(v.x); o[1]=f2us(v.y); o[2]=f2us(v.z); o[3]=f2us(v.w);
        *(u16x4*)&hbf[(size_t)i * 4] = o;
        return;
    }
    const float* in; u16* out; int K, N, k0, n0;
    if (bid < 8192 + 4352) {               // WtIn: K=2048, N=8512 (pad to 8704)
        int b2 = bid - 8192;
        in = W_in; out = WtIn; K = D_MODEL; N = D_IN_PROJ;
        k0 = (b2 % 32) * 64; n0 = (b2 / 32) * 64;
    } else {                               // WtOut: K=4096, N=2048
        int b3 = bid - 8192 - 4352;
        in = W_out; out = WtOut; K = D_INNER; N = D_MODEL;
        k0 = (b3 % 64) * 64; n0 = (b3 / 64) * 64;
    }
    #pragma unroll
    for (int q = 0; q < 16; q++) {
        int lin = q * 256 + t;
        int r = lin >> 6, c = lin & 63;
        int n = n0 + c;
        float v = (n < N) ? in[(size_t)(k0 + r) * N + n] : 0.f;
        tile[r][c] = f2us(v);
    }
    __syncthreads();
    #pragma unroll
    for (int q = 0; q < 4; q++) {
        int lin = q * 256 + t;
        int r = lin >> 4, cg = lin & 15;
        u16x4 v;
        #pragma unroll
        for (int e = 0; e < 4; e++) v[e] = tile[cg*4 + e][r];
        *(u16x4*)&out[(size_t)(n0 + r) * K + k0 + cg*4] = v;
    }
}

// ---------- out = bf16 tmp0 + bf16 tmp1 (f32 result) ----------
__global__ __launch_bounds__(256)
void add2_bf16(float* __restrict__ out, const u16* __restrict__ t0,
               const u16* __restrict__ t1, int n8)
{
    int i = blockIdx.x * 256 + threadIdx.x;
    if (i >= n8) return;
    u16x8 a = *(const u16x8*)&t0[(size_t)i * 8];
    u16x8 b = *(const u16x8*)&t1[(size_t)i * 8];
    float* o = &out[(size_t)i * 8];
    *(float4*)&o[0] = make_float4(us2f(a[0])+us2f(b[0]), us2f(a[1])+us2f(b[1]),
                                  us2f(a[2])+us2f(b[2]), us2f(a[3])+us2f(b[3]));
    *(float4*)&o[4] = make_float4(us2f(a[4])+us2f(b[4]), us2f(a[5])+us2f(b[5]),
                                  us2f(a[6])+us2f(b[6]), us2f(a[7])+us2f(b[7]));
}

// ---------- 8-phase 256x256 MFMA GEMM (T2-swizzled LDS, plain barriers) ----------
// Stage ledger (round-12 proven): p1: Ah1(t+1); p3: Bh0(t+2); p4: Bh1(t+2)+Ah0(t+2).
template<typename TC, bool KSPLIT>
__global__ __launch_bounds__(512, 1)
void gemm_8ph(const u16* __restrict__ Ag, const u16* __restrict__ Btg,
              TC* __restrict__ Cg, u16* __restrict__ Cg2,
              int M, int N, int Kext, int ldk, int ldc)
{
    __shared__ u16 smA[2][2][8192];   // [dbuf][half][128*64]
    __shared__ u16 smB[2][2][8192];
    const int tid = threadIdx.x;
    const int lane = tid & 63, w = tid >> 6;
    const int wm = w >> 2, wn = w & 3;
    const int lr = lane & 15, kh = lane >> 4;
    const int swz = (lr & 7) << 3;

    int orig = blockIdx.x;
    int ntile = gridDim.x;
    int kidx = 0;
    if constexpr (KSPLIT) { kidx = orig & 1; orig >>= 1; ntile >>= 1; }

    const int nbx = N >> 8;
    const int qq = ntile >> 3, r8 = ntile & 7;
    const int xcd = orig & 7, loc = orig >> 3;
    const int wgid = (xcd < r8 ? xcd*(qq+1) : r8*(qq+1) + (xcd-r8)*qq) + loc;
    const int m0 = (wgid / nbx) * 256;
    const int n0 = (wgid % nbx) * 256;

    if constexpr (KSPLIT) {
        Ag  += (size_t)kidx * Kext;
        Btg += (size_t)kidx * Kext;
        Cg2 += (size_t)kidx * M * ldc;
    }
    const int NT = Kext >> 6;

    f32x4 acc[8][4];
    #pragma unroll
    for (int i = 0; i < 8; i++)
        #pragma unroll
        for (int j = 0; j < 4; j++) acc[i][j] = (f32x4){0.f,0.f,0.f,0.f};

    stage_half(&Ag [(size_t)(m0      ) * ldk      ], ldk, &smA[0][0][0], w, lane);
    stage_half(&Ag [(size_t)(m0 + 128) * ldk      ], ldk, &smA[0][1][0], w, lane);
    stage_half(&Btg[(size_t)(n0      ) * ldk      ], ldk, &smB[0][0][0], w, lane);
    stage_half(&Btg[(size_t)(n0 + 128) * ldk      ], ldk, &smB[0][1][0], w, lane);
    stage_half(&Ag [(size_t)(m0      ) * ldk + 64 ], ldk, &smA[1][0][0], w, lane);
    stage_half(&Btg[(size_t)(n0      ) * ldk + 64 ], ldk, &smB[1][0][0], w, lane);
    stage_half(&Btg[(size_t)(n0 + 128) * ldk + 64 ], ldk, &smB[1][1][0], w, lane);
    VMCNT(6);
    __builtin_amdgcn_s_barrier();

    for (int t = 0; t < NT; ++t) {
        const int d = t & 1;
        const u16* As = &smA[d][wm][0];
        const u16* Bs = &smB[d][wn >> 1][0];
        const int rb = (wn & 1) * 64;

        bf16x8 aF[4][2], bLo[2][2], bHi[2][2];

        // ---- phase 1: read A-lo + B-lo; stage Ah1(t+1)
        #pragma unroll
        for (int i = 0; i < 4; i++)
            #pragma unroll
            for (int ks = 0; ks < 2; ks++)
                aF[i][ks] = *(const bf16x8*)&As[(i*16 + lr)*64 + ((ks*32 + kh*8) ^ swz)];
        #pragma unroll
        for (int j = 0; j < 2; j++)
            #pragma unroll
            for (int ks = 0; ks < 2; ks++)
                bLo[j][ks] = *(const bf16x8*)&Bs[(rb + j*16 + lr)*64 + ((ks*32 + kh*8) ^ swz)];
        if (t + 1 < NT)
            stage_half(&Ag[(size_t)(m0 + 128) * ldk + (t+1)*64], ldk, &smA[d^1][1][0], w, lane);
        __builtin_amdgcn_s_barrier();
        __builtin_amdgcn_s_setprio(1);
        #pragma unroll
        for (int i = 0; i < 4; i++)
            #pragma unroll
            for (int j = 0; j < 2; j++)
                #pragma unroll
                for (int ks = 0; ks < 2; ks++)
                    acc[i][j] = __builtin_amdgcn_mfma_f32_16x16x32_bf16(aF[i][ks], bLo[j][ks], acc[i][j], 0, 0, 0);
        __builtin_amdgcn_s_setprio(0);
        __builtin_amdgcn_s_barrier();

        // ---- phase 2: read B-hi
        #pragma unroll
        for (int j = 0; j < 2; j++)
            #pragma unroll
            for (int ks = 0; ks < 2; ks++)
                bHi[j][ks] = *(const bf16x8*)&Bs[(rb + (2+j)*16 + lr)*64 + ((ks*32 + kh*8) ^ swz)];
        __builtin_amdgcn_s_barrier();
        __builtin_amdgcn_s_setprio(1);
        #pragma unroll
        for (int i = 0; i < 4; i++)
            #pragma unroll
            for (int j = 0; j < 2; j++)
                #pragma unroll
                for (int ks = 0; ks < 2; ks++)
                    acc[i][2+j] = __builtin_amdgcn_mfma_f32_16x16x32_bf16(aF[i][ks], bHi[j][ks], acc[i][2+j], 0, 0, 0);
        __builtin_amdgcn_s_setprio(0);
        __builtin_amdgcn_s_barrier();

        // ---- phase 3: read A-hi (overwrites aF); stage Bh0(t+2)
        #pragma unroll
        for (int i = 0; i < 4; i++)
            #pragma unroll
            for (int ks = 0; ks < 2; ks++)
                aF[i][ks] = *(const bf16x8*)&As[(64 + i*16 + lr)*64 + ((ks*32 + kh*8) ^ swz)];
        if (t + 2 < NT)
            stage_half(&Btg[(size_t)(n0) * ldk + (t+2)*64], ldk, &smB[d][0][0], w, lane);
        __builtin_amdgcn_s_barrier();
        __builtin_amdgcn_s_setprio(1);
        #pragma unroll
        for (int i = 0; i < 4; i++)
            #pragma unroll
            for (int j = 0; j < 2; j++)
                #pragma unroll
                for (int ks = 0; ks < 2; ks++)
                    acc[4+i][j] = __builtin_amdgcn_mfma_f32_16x16x32_bf16(aF[i][ks], bLo[j][ks], acc[4+i][j], 0, 0, 0);
        __builtin_amdgcn_s_setprio(0);
        __builtin_amdgcn_s_barrier();

        // ---- phase 4: stage Bh1(t+2)+Ah0(t+2); MFMA; counted vmcnt after
        if (t + 2 < NT) {
            stage_half(&Btg[(size_t)(n0 + 128) * ldk + (t+2)*64], ldk, &smB[d][1][0], w, lane);
            stage_half(&Ag [(size_t)(m0      ) * ldk + (t+2)*64], ldk, &smA[d][0][0], w, lane);
        }
        __builtin_amdgcn_s_barrier();
        __builtin_amdgcn_s_setprio(1);
        #pragma unroll
        for (int i = 0; i < 4; i++)
            #pragma unroll
            for (int j = 0; j < 2; j++)
                #pragma unroll
                for (int ks = 0; ks < 2; ks++)
                    acc[4+i][2+j] = __builtin_amdgcn_mfma_f32_16x16x32_bf16(aF[i][ks], bHi[j][ks], acc[4+i][2+j], 0, 0, 0);
        __builtin_amdgcn_s_setprio(0);
        if (t < NT - 2)       { VMCNT(6); }
        else if (t == NT - 2) { VMCNT(0); }
        __builtin_amdgcn_s_barrier();
    }

    #pragma unroll
    for (int mf = 0; mf < 8; mf++) {
        #pragma unroll
        for (int nf = 0; nf < 4; nf++) {
            int r = m0 + wm*128 + mf*16 + kh*4;
            int cidx = n0 + wn*64 + nf*16 + lr;
            #pragma unroll
            for (int q = 0; q < 4; q++) {
                if constexpr (KSPLIT) {
                    Cg2[(size_t)(r+q)*ldc + cidx] = f2us(acc[mf][nf][q]);
                } else if constexpr (sizeof(TC) == 4) {
                    Cg[(size_t)(r+q)*ldc + cidx] = acc[mf][nf][q];
                } else {
                    Cg[(size_t)(r+q)*ldc + cidx] = f2us(acc[mf][nf][q]);
                }
            }
        }
    }
}

// ---------- GEMM1 tail: N=512, K-split-4, 2-phase 128x128, f32 partials ----------
__global__ __launch_bounds__(256)
void gemm_tail_ks4(const u16* __restrict__ A, const u16* __restrict__ Bt,
                   float* __restrict__ Cp, int M, int ldk)
{
    __shared__ u16 Asm[128][32];
    __shared__ u16 Bsm[128][32];
    const int t = threadIdx.x;
    const int lane = t & 63, w = t >> 6;
    const int wr = w >> 1, wc = w & 1;
    const int lr = lane & 15, kh = lane >> 4;

    const int bid = blockIdx.x;
    const int kidx = bid & 3, tile = bid >> 2;
    const int m0 = (tile >> 2) * 128;
    const int n0 = (tile & 3) * 128;

    const u16* Ak = A  + kidx * 512;
    const u16* Bk = Bt + kidx * 512;
    float* C = Cp + (size_t)kidx * TSTRIDE;

    f32x4 acc[4][4];
    #pragma unroll
    for (int i = 0; i < 4; i++)
        #pragma unroll
        for (int j = 0; j < 4; j++) acc[i][j] = (f32x4){0.f,0.f,0.f,0.f};

    for (int k0 = 0; k0 < 512; k0 += 32) {
        #pragma unroll
        for (int i = 0; i < 2; i++) {
            int cb = i * 256 + w * 64;
            int chunk = cb + lane;
            int row = chunk >> 2, kb = chunk & 3;
            gload_lds16(&Ak[(size_t)(m0 + row) * ldk + k0 + kb * 8], &Asm[0][0] + cb * 8);
            gload_lds16(&Bk[(size_t)(n0 + row) * ldk + k0 + kb * 8], &Bsm[0][0] + cb * 8);
        }
        __syncthreads();
        bf16x8 af[4], bf[4];
        #pragma unroll
        for (int i = 0; i < 4; i++)
            af[i] = *(const bf16x8*)&Asm[wr*64 + i*16 + lr][kh*8];
        #pragma unroll
        for (int j = 0; j < 4; j++)
            bf[j] = *(const bf16x8*)&Bsm[wc*64 + j*16 + lr][kh*8];
        #pragma unroll
        for (int i = 0; i < 4; i++)
            #pragma unroll
            for (int j = 0; j < 4; j++)
                acc[i][j] = __builtin_amdgcn_mfma_f32_16x16x32_bf16(af[i], bf[j], acc[i][j], 0, 0, 0);
        __syncthreads();
    }
    #pragma unroll
    for (int i = 0; i < 4; i++) {
        #pragma unroll
        for (int j = 0; j < 4; j++) {
            int r = m0 + wr*64 + i*16 + kh*4;
            int cidx = n0 + wc*64 + j*16 + lr;
            #pragma unroll
            for (int q = 0; q < 4; q++)
                C[(size_t)(r+q)*512 + cidx] = acc[i][j][q];
        }
    }
}

// ---------------- conv1d + bias + SiLU; B/C channels read 4 tail partials directly ----------------
__global__ __launch_bounds__(256)
void conv_silu(const u16* __restrict__ zx, const float* __restrict__ tailp,
               const float* __restrict__ cw, const float* __restrict__ cb,
               u16* __restrict__ xconv, u16* __restrict__ Bbuf, u16* __restrict__ Cbuf)
{
    int idx = blockIdx.x * 256 + threadIdx.x;
    int cg = idx % (CONV_DIM / 8);
    int r  = idx / (CONV_DIM / 8);
    int c0 = cg * 8;
    int l  = r & (SEQ - 1);

    float y[8];
    {
        float4 b0 = *(const float4*)&cb[c0];
        float4 b1 = *(const float4*)&cb[c0 + 4];
        y[0]=b0.x; y[1]=b0.y; y[2]=b0.z; y[3]=b0.w;
        y[4]=b1.x; y[5]=b1.y; y[6]=b1.z; y[7]=b1.w;
    }
    float cwf[8][4];
    #pragma unroll
    for (int e = 0; e < 8; e++) {
        float4 v = *(const float4*)&cw[(c0 + e) * 4];
        cwf[e][0]=v.x; cwf[e][1]=v.y; cwf[e][2]=v.z; cwf[e][3]=v.w;
    }
    if (c0 < D_INNER) {                      // x channels: zx cols [4096, 8192)
        #pragma unroll
        for (int k = 0; k < 4; k++) {
            if (l + k - 3 >= 0) {
                u16x8 v = *(const u16x8*)&zx[(size_t)(r + k - 3) * LD_ZX + D_INNER + c0];
                #pragma unroll
                for (int e = 0; e < 8; e++) y[e] += us2f(v[e]) * cwf[e][k];
            }
        }
    } else {                                 // B/C channels: sum 4 tail partials
        int tc = c0 - D_INNER;
        #pragma unroll
        for (int k = 0; k < 4; k++) {
            if (l + k - 3 >= 0) {
                const float* tb = &tailp[(size_t)(r + k - 3) * 512 + tc];
                #pragma unroll
                for (int e = 0; e < 8; e++) {
                    float s = tb[e] + tb[TSTRIDE + e] + tb[2*TSTRIDE + e] + tb[3*TSTRIDE + e];
                    y[e] += s * cwf[e][k];
                }
            }
        }
    }
    u16x8 o;
    #pragma unroll
    for (int e = 0; e < 8; e++) {
        float s = y[e] / (1.f + expf(-y[e]));
        o[e] = f2us(s);
    }
    if (c0 < D_INNER)                *(u16x8*)&xconv[(size_t)r * D_INNER + c0] = o;
    else if (c0 < D_INNER + D_STATE) *(u16x8*)&Bbuf[(size_t)r * D_STATE + (c0 - D_INNER)] = o;
    else                             *(u16x8*)&Cbuf[(size_t)r * D_STATE + (c0 - D_INNER - D_STATE)] = o;
}

// ---------------- combo: BT transpose (16) + S precompute (160) + dt_acs (1024) ----------------
__global__ __launch_bounds__(256)
void combo_mid(const u16* __restrict__ Bbuf, const u16* __restrict__ Cbuf,
               u16* __restrict__ BT, u16* __restrict__ Sbuf,
               const float* __restrict__ tailp, const float* __restrict__ Aparam,
               const float* __restrict__ dt_bias, float* __restrict__ dtT,
               float* __restrict__ Acs)
{
    __shared__ u16 tile[64][72];
    __shared__ float sb[CHUNK];
    const int bid = blockIdx.x;
    const int t = threadIdx.x;

    if (bid < 16) {                         // BT[bc][n=128][l=256] = Bbuf^T
        int b = bid >> 3, c = bid & 7;
        const size_t rowbase = (size_t)(b * SEQ + c * CHUNK);
        u16* BTb = BT + (size_t)bid * 128 * 256;
        for (int sub = 0; sub < 8; sub++) {
            int l0 = (sub >> 1) * 64, n0 = (sub & 1) * 64;
            #pragma unroll
            for (int q = 0; q < 2; q++) {
                int lin = q * 256 + t;
                int r = lin >> 3, cc = (lin & 7) * 8;
                *(u16x8*)&tile[r][cc] = *(const u16x8*)&Bbuf[(rowbase + l0 + r) * D_STATE + n0 + cc];
            }
            __syncthreads();
            #pragma unroll
            for (int q = 0; q < 4; q++) {
                int lin = q * 256 + t;
                int rn = lin >> 4, cg = lin & 15;
                u16x4 v;
                #pragma unroll
                for (int e = 0; e < 4; e++) v[e] = tile[cg*4 + e][rn];
                *(u16x4*)&BTb[(size_t)(n0 + rn) * 256 + l0 + cg*4] = v;
            }
            __syncthreads();
        }
        return;
    }
    if (bid < 176) {                        // S precompute (verified frag math from r15)
        int p = (bid - 16) % 10, bc = (bid - 16) / 10;
        int q = (p >= 6) ? 3 : (p >= 3) ? 2 : (p >= 1) ? 1 : 0;
        int st = p - q * (q + 1) / 2;
        int b = bc >> 3, c = bc & 7;
        const int lane = t & 63, w = t >> 6;
        const int lr = lane & 15, kh = lane >> 4;
        const size_t rowbase = (size_t)(b * SEQ + c * CHUNK);

        f32x4 sacc[4];
        #pragma unroll
        for (int i = 0; i < 4; i++) sacc[i] = (f32x4){0.f,0.f,0.f,0.f};
        #pragma unroll
        for (int kk = 0; kk < 4; kk++) {
            bf16x8 bA = *(const bf16x8*)&Bbuf[(rowbase + st*64 + w*16 + lr) * D_STATE + kk*32 + kh*8];
            #pragma unroll
            for (int i = 0; i < 4; i++) {
                bf16x8 af = *(const bf16x8*)&Cbuf[(rowbase + q*64 + i*16 + lr) * D_STATE + kk*32 + kh*8];
                sacc[i] = __builtin_amdgcn_mfma_f32_16x16x32_bf16(bA, af, sacc[i], 0, 0, 0);
            }
        }
        u16* Sb = Sbuf + (size_t)bc * 256 * 256;
        #pragma unroll
        for (int i = 0; i < 4; i++) {
            u16x4 o;
            #pragma unroll
            for (int qq = 0; qq < 4; qq++) o[qq] = f2us(sacc[i][qq]);
            *(u16x4*)&Sb[(size_t)(q*64 + i*16 + lr) * 256 + st*64 + w*16 + kh*4] = o;
        }
        return;
    }
    // dt_acs
    {
        int blk = bid - 176;
        int c = blk & 7, h = (blk >> 3) & 63, b = blk >> 9;
        int lg = c * CHUNK + t;
        int row = b * SEQ + lg;
        const float* tb = &tailp[(size_t)row * 512 + 256 + h];
        float x = tb[0] + tb[TSTRIDE] + tb[2*TSTRIDE] + tb[3*TSTRIDE];
        x += dt_bias[h];
        float dt = (x > 20.f) ? x : log1pf(expf(x));
        float v = dt * Aparam[h];
        sb[t] = v; __syncthreads();
        #pragma unroll
        for (int off = 1; off < 256; off <<= 1) {
            float add = (t >= off) ? sb[t - off] : 0.f;
            __syncthreads();
            v += add; sb[t] = v;
            __syncthreads();
        }
        int o = (b * NHEADS + h) * SEQ + lg;
        dtT[o] = dt;
        Acs[o] = v;
    }
}

// ---------------- per-chunk states via MFMA, bf16 out; BT staged via vector copies ----------------
__global__ __launch_bounds__(256)
void chunk_states_mfma(const u16* __restrict__ xconv, const u16* __restrict__ BT,
                       const float* __restrict__ dtT, const float* __restrict__ Acs,
                       u16* __restrict__ states)
{
    __shared__ u16 Btsh[128][72];   // B^T [n][l]
    __shared__ u16 xtsh[64][72];    // (w*x)^T [p][l]
    __shared__ float acs_sh[CHUNK];
    __shared__ float dt_sh[CHUNK];

    const int blk = blockIdx.x;
    const int h = blk & 63, c = (blk >> 6) & 7, b = blk >> 9;
    const int t = threadIdx.x;
    const int lane = t & 63, w = t >> 6;
    const int wr = w >> 1, wc = w & 1;
    const int lr = lane & 15, kh = lane >> 4;
    const int bh = b * NHEADS + h;
    const int bc = b * NCHUNK + c;
    const size_t rowbase = (size_t)(b * SEQ + c * CHUNK);
    const u16* BTb = BT + (size_t)bc * 128 * 256;

    acs_sh[t] = Acs[(size_t)bh * SEQ + c * CHUNK + t];
    dt_sh[t]  = dtT[(size_t)bh * SEQ + c * CHUNK + t];
    __syncthreads();
    const float acs_last = acs_sh[CHUNK - 1];

    f32x4 acc[4][2];   // [j = n-block][i = p-block]
    #pragma unroll
    for (int j = 0; j < 4; j++)
        #pragma unroll
        for (int i = 0; i < 2; i++) acc[j][i] = (f32x4){0.f,0.f,0.f,0.f};

    for (int lt = 0; lt < 4; lt++) {
        __syncthreads();
        {   // B^T staging: vector copies from precomputed BT
            int n = t >> 1, lc = (t & 1) * 32;
            const u16* src = &BTb[(size_t)n * 256 + lt*64 + lc];
            #pragma unroll
            for (int q = 0; q < 4; q++)
                *(u16x8*)&Btsh[n][lc + q*8] = *(const u16x8*)&src[q*8];
        }
        {   // (w*x)^T staging, wgt folded
            const int s = t & 63;
            const int sg = lt * 64 + s;
            const float wgt = dt_sh[sg] * expf(acs_last - acs_sh[sg]);
            int pg = (t >> 6) * 16;
            const u16* src = &xconv[(rowbase + sg) * D_INNER + h * HEAD_DIM + pg];
            u16x8 v0 = *(const u16x8*)&src[0];
            u16x8 v1 = *(const u16x8*)&src[8];
            #pragma unroll
            for (int e = 0; e < 8; e++) {
                xtsh[pg + e][s]     = f2us(us2f(v0[e]) * wgt);
                xtsh[pg + 8 + e][s] = f2us(us2f(v1[e]) * wgt);
            }
        }
        __syncthreads();
        #pragma unroll
        for (int kk = 0; kk < 2; kk++) {
            bf16x8 xf[2], bf[4];
            #pragma unroll
            for (int i = 0; i < 2; i++)
                xf[i] = *(const bf16x8*)&xtsh[wr*32 + i*16 + lr][kk*32 + kh*8];
            #pragma unroll
            for (int j = 0; j < 4; j++)
                bf[j] = *(const bf16x8*)&Btsh[wc*64 + j*16 + lr][kk*32 + kh*8];
            #pragma unroll
            for (int j = 0; j < 4; j++)
                #pragma unroll
                for (int i = 0; i < 2; i++)
                    acc[j][i] = __builtin_amdgcn_mfma_f32_16x16x32_bf16(bf[j], xf[i], acc[j][i], 0, 0, 0);
        }
    }
    size_t base = ((size_t)(bc * NHEADS + h)) * (HEAD_DIM * D_STATE);
    #pragma unroll
    for (int j = 0; j < 4; j++) {
        #pragma unroll
        for (int i = 0; i < 2; i++) {
            int p = wr*32 + i*16 + lr;
            int n = wc*64 + j*16 + kh*4;
            u16x4 o;
            #pragma unroll
            for (int q = 0; q < 4; q++) o[q] = f2us(acc[j][i][q]);
            *(u16x4*)&states[base + (size_t)p * D_STATE + n] = o;
        }
    }
}

// ---------------- inter-chunk recurrence, bf16 states ----------------
__global__ __launch_bounds__(256)
void state_recurrence(u16* __restrict__ states, const float* __restrict__ Acs)
{
    int idx = blockIdx.x * 256 + threadIdx.x;
    int n8 = idx & 15;
    int p  = (idx >> 4) & 63;
    int bh = idx >> 10;
    int b = bh >> 6, h = bh & 63;
    float E[8];
    #pragma unroll
    for (int e = 0; e < 8; e++) E[e] = 0.f;
    for (int c = 0; c < NCHUNK; c++) {
        size_t off = ((size_t)((b*NCHUNK + c)*NHEADS + h)) * 8192 + (size_t)p * 128 + n8 * 8;
        u16x8 sv = *(const u16x8*)&states[off];
        u16x8 ev;
        #pragma unroll
        for (int e = 0; e < 8; e++) ev[e] = f2us(E[e]);
        *(u16x8*)&states[off] = ev;
        float g = expf(Acs[(size_t)(b*NHEADS + h) * SEQ + c*CHUNK + 255]);
        #pragma unroll
        for (int e = 0; e < 8; e++) E[e] = g * E[e] + us2f(sv[e]);
    }
}

// ---------------- chunk output: prev unioned into Pt (LDS 48 KB -> 3 blocks/CU) ----------------
__global__ __launch_bounds__(256, 1)
void chunk_output_mfma(const u16* __restrict__ xconv, const u16* __restrict__ Sbuf,
                       const u16* __restrict__ Cbuf, const float* __restrict__ dtT,
                       const float* __restrict__ Acs, const u16* __restrict__ states,
                       const float* __restrict__ Dparam, u16* __restrict__ Y)
{
    __shared__ u16 PtU[4][64][72];     // per-wave P [l][s]; prev [64][136] aliased pre-loop
    __shared__ u16 xt[64][72];         // x^T tile [p][s]
    __shared__ float acs_sh[CHUNK];
    __shared__ float dt_sh[CHUNK];
    u16 (*prevS)[136] = (u16(*)[136])&PtU[0][0][0];   // 64*136 = 8704 u16 <= 18432

    const int blk = blockIdx.x;
    const int h = blk & 63, c = (blk >> 6) & 7, b = blk >> 9;
    const int t = threadIdx.x;
    const int lane = t & 63, w = t >> 6;
    const int lr = lane & 15, kh = lane >> 4;
    const int bh = b * NHEADS + h;
    const size_t rowbase = (size_t)(b * SEQ + c * CHUNK);
    const u16* Sblk = Sbuf + (size_t)(b * NCHUNK + c) * 256 * 256;

    acs_sh[t] = Acs[(size_t)bh * SEQ + c * CHUNK + t];
    dt_sh[t]  = dtT[(size_t)bh * SEQ + c * CHUNK + t];

    bf16x8 af[4][4];
    #pragma unroll
    for (int i = 0; i < 4; i++)
        #pragma unroll
        for (int kk = 0; kk < 4; kk++)
            af[i][kk] = *(const bf16x8*)&Cbuf[(rowbase + w*64 + i*16 + lr) * D_STATE + kk*32 + kh*8];

    {   // stage prev into prevS [p][n] (aliases Pt region; consumed before first Pt write)
        int p = t >> 2, ng = (t & 3) * 32;
        const u16* src = &states[((size_t)((b*NCHUNK + c)*NHEADS + h)) * 8192 + (size_t)p * 128 + ng];
        #pragma unroll
        for (int q = 0; q < 4; q++)
            *(u16x8*)&prevS[p][ng + q*8] = *(const u16x8*)&src[q*8];
    }
    __syncthreads();
    float acs_l[4], el[4];
    #pragma unroll
    for (int i = 0; i < 4; i++) { acs_l[i] = acs_sh[w*64 + i*16 + lr]; el[i] = expf(acs_l[i]); }

    // Y_off raw: yacc[j][i] = prev . C (unscaled), then scale by el[i]
    f32x4 yacc[4][4];
    #pragma unroll
    for (int j = 0; j < 4; j++)
        #pragma unroll
        for (int i = 0; i < 4; i++) yacc[j][i] = (f32x4){0.f,0.f,0.f,0.f};
    #pragma unroll
    for (int kk = 0; kk < 4; kk++) {
        bf16x8 pvA[4];
        #pragma unroll
        for (int j = 0; j < 4; j++)
            pvA[j] = *(const bf16x8*)&prevS[j*16 + lr][kk*32 + kh*8];
        #pragma unroll
        for (int j = 0; j < 4; j++)
            #pragma unroll
            for (int i = 0; i < 4; i++)
                yacc[j][i] = __builtin_amdgcn_mfma_f32_16x16x32_bf16(pvA[j], af[i][kk], yacc[j][i], 0, 0, 0);
    }
    #pragma unroll
    for (int j = 0; j < 4; j++)
        #pragma unroll
        for (int i = 0; i < 4; i++)
            #pragma unroll
            for (int q = 0; q < 4; q++)
                yacc[j][i][q] *= el[i];

    for (int st = 0; st < 4; st++) {
        __syncthreads();   // Y_off prevS reads done (st=0) / prior-tile reads done
        {   // stage x^T tile [p][s]
            int s = t & 63, pg = t >> 6;
            const u16* src = &xconv[(rowbase + st*64 + s) * D_INNER + h*HEAD_DIM + pg*16];
            u16x8 v0 = *(const u16x8*)&src[0];
            u16x8 v1 = *(const u16x8*)&src[8];
            #pragma unroll
            for (int q = 0; q < 8; q++) { xt[pg*16 + q][s] = v0[q]; xt[pg*16 + 8 + q][s] = v1[q]; }
        }
        __syncthreads();
        if (st > w) continue;

        // P = mask(S) * dt, S loaded from head-shared Sbuf
        #pragma unroll
        for (int js = 0; js < 4; js++) {
            int s0 = st*64 + js*16;
            float as0 = acs_sh[s0];
            int sgq = s0 + kh*4;
            float eneg[4];
            #pragma unroll
            for (int q = 0; q < 4; q++)
                eneg[q] = expf(fminf(as0 - acs_sh[sgq + q], 60.f)) * dt_sh[sgq + q];
            #pragma unroll
            for (int i = 0; i < 4; i++) {
                int ll = w*64 + i*16 + lr;
                float eladj = expf(acs_l[i] - as0);
                u16x4 sv = *(const u16x4*)&Sblk[(size_t)ll * 256 + sgq];
                u16x4 pv;
                #pragma unroll
                for (int q = 0; q < 4; q++) {
                    float fac = (sgq + q <= ll) ? eladj * eneg[q] : 0.f;
                    pv[q] = f2us(us2f(sv[q]) * fac);
                }
                *(u16x4*)&PtU[w][i*16 + lr][js*16 + kh*4] = pv;
            }
        }
        #pragma unroll
        for (int kk2 = 0; kk2 < 2; kk2++) {
            bf16x8 xA[4], pB[4];
            #pragma unroll
            for (int j = 0; j < 4; j++)
                xA[j] = *(const bf16x8*)&xt[j*16 + lr][kk2*32 + kh*8];
            #pragma unroll
            for (int i = 0; i < 4; i++)
                pB[i] = *(const bf16x8*)&PtU[w][i*16 + lr][kk2*32 + kh*8];
            #pragma unroll
            for (int j = 0; j < 4; j++)
                #pragma unroll
                for (int i = 0; i < 4; i++)
                    yacc[j][i] = __builtin_amdgcn_mfma_f32_16x16x32_bf16(xA[j], pB[i], yacc[j][i], 0, 0, 0);
        }
    }

    float Dh = Dparam[h];
    #pragma unroll
    for (int i = 0; i < 4; i++) {
        #pragma unroll
        for (int j = 0; j < 4; j++) {
            size_t o = (rowbase + w*64 + i*16 + lr) * D_INNER + h*HEAD_DIM + j*16 + kh*4;
            u16x4 xv = *(const u16x4*)&xconv[o];
            u16x4 ov;
            #pragma unroll
            for (int q = 0; q < 4; q++)
                ov[q] = f2us(yacc[j][i][q] + Dh * us2f(xv[q]));
            *(u16x4*)&Y[o] = ov;
        }
    }
}

// ---------------- gated RMSNorm ----------------
__global__ __launch_bounds__(256)
void gated_rmsnorm_k(u16* __restrict__ Y, const u16* __restrict__ zx,
                     const float* __restrict__ nw)
{
    __shared__ float xs[D_INNER];
    __shared__ float red[8];
    int row = blockIdx.x;
    int t = threadIdx.x;
    float ss = 0.f;
    for (int i = t*8; i < D_INNER; i += 2048) {
        u16x8 yv = *(const u16x8*)&Y[(size_t)row * D_INNER + i];
        u16x8 zv = *(const u16x8*)&zx[(size_t)row * LD_ZX + i];
        #pragma unroll
        for (int q = 0; q < 8; q++) {
            float x = us2f(yv[q]) * siluf(us2f(zv[q]));
            xs[i + q] = x;
            ss += x * x;
        }
    }
    #pragma unroll
    for (int off = 32; off > 0; off >>= 1) ss += __shfl_down(ss, off);
    int wid = t >> 6, lane = t & 63;
    if (lane == 0) red[wid] = ss;
    __syncthreads();
    if (t == 0) {
        float tot = red[0] + red[1] + red[2] + red[3];
        red[0] = rsqrtf(tot / (float)D_INNER + EPS_RMS);
    }
    __syncthreads();
    float sc = red[0];
    for (int i = t*8; i < D_INNER; i += 2048) {
        u16x8 o;
        #pragma unroll
        for (int q = 0; q < 8; q++) o[q] = f2us(xs[i + q] * sc * nw[i + q]);
        *(u16x8*)&Y[(size_t)row * D_INNER + i] = o;
    }
}

__global__ void ws_fail_k(float* out, float mb){ out[threadIdx.x] = mb; }

// ---------------- launch ----------------
extern "C" void kernel_launch(void* const* d_in, const int* in_sizes, int n_in,
                              void* d_out, int out_size, void* d_ws, size_t ws_size,
                              hipStream_t stream)
{
    const float* hidden  = (const float*)d_in[0];
    const float* W_in    = (const float*)d_in[1];
    const float* conv_w  = (const float*)d_in[2];
    const float* conv_b  = (const float*)d_in[3];
    const float* Aparam  = (const float*)d_in[4];
    const float* Dparam  = (const float*)d_in[5];
    const float* dt_bias = (const float*)d_in[6];
    const float* norm_w  = (const float*)d_in[7];
    const float* W_out   = (const float*)d_in[8];
    float* out = (float*)d_out;

    const int M = BATCH * SEQ;  // 4096

    size_t off = 0;
    char* wsb = (char*)d_ws;
    u16*   zx     = (u16*)  (wsb + off); off += (size_t)M * LD_ZX * 2;
    u16*   xconv  = (u16*)  (wsb + off); off += (size_t)M * D_INNER * 2;
    u16*   Bbuf   = (u16*)  (wsb + off); off += (size_t)M * D_STATE * 2;
    u16*   Cbuf   = (u16*)  (wsb + off); off += (size_t)M * D_STATE * 2;
    float* dtT    = (float*)(wsb + off); off += (size_t)BATCH * NHEADS * SEQ * 4;
    float* Acs    = (float*)(wsb + off); off += (size_t)BATCH * NHEADS * SEQ * 4;
    u16*   states = (u16*)  (wsb + off); off += (size_t)BATCH * NCHUNK * NHEADS * HEAD_DIM * D_STATE * 2;
    u16*   Ybuf   = (u16*)  (wsb + off); off += (size_t)M * D_INNER * 2;
    u16*   hbf    = (u16*)  (wsb + off); off += (size_t)M * D_MODEL * 2;
    u16*   WtIn   = (u16*)  (wsb + off); off += (size_t)LD_ZX * D_MODEL * 2;
    u16*   WtOut  = (u16*)  (wsb + off); off += (size_t)D_MODEL * D_INNER * 2;
    float* tailp  = (float*)(wsb + off); off += 4 * TSTRIDE * 4;            // 33.5 MB
    u16*   Sbuf   = (u16*)  (wsb + off); off += (size_t)16 * 256 * 256 * 2; // 2 MB
    u16*   BT     = (u16*)  (wsb + off); off += (size_t)16 * 128 * 256 * 2; // 1 MB
    u16*   tmpf   = (u16*)zx;   // GEMM2 bf16 planes alias zx (dead after gated_rmsnorm)

    if (off > ws_size) {
        ws_fail_k<<<1, 64, 0, stream>>>(out, (float)(ws_size >> 20));
        return;
    }

    // fused preprocessing: hbf cvt (8192) + WtIn transpose (4352) + WtOut transpose (2048)
    prep_kernel<<<8192 + 4352 + 2048, 256, 0, stream>>>(hidden, hbf, W_in, WtIn, W_out, WtOut);

    // GEMM1 main: zx[:, 0:8192] — 512 blocks = exactly 2 CU-rounds
    gemm_8ph<u16, false><<<(8192/256) * (M/256), 512, 0, stream>>>(
        hbf, WtIn, zx, nullptr, M, 8192, D_MODEL, D_MODEL, LD_ZX);
    // GEMM1 tail: cols [8192:8704] — K-split-4 f32 partials, consumed by conv/dt directly
    gemm_tail_ks4<<<512, 256, 0, stream>>>(hbf, WtIn + (size_t)8192 * D_MODEL, tailp, M, D_MODEL);

    conv_silu<<<(M * CONV_DIM / 8) / 256, 256, 0, stream>>>(zx, tailp, conv_w, conv_b, xconv, Bbuf, Cbuf);
    // combo: BT transpose (16) + S precompute (160) + dt_acs (1024)
    combo_mid<<<16 + 160 + BATCH * NHEADS * NCHUNK, 256, 0, stream>>>(
        Bbuf, Cbuf, BT, Sbuf, tailp, Aparam, dt_bias, dtT, Acs);
    chunk_states_mfma<<<BATCH * NCHUNK * NHEADS, 256, 0, stream>>>(xconv, BT, dtT, Acs, states);
    state_recurrence<<<(BATCH * NHEADS * 64 * 16) / 256, 256, 0, stream>>>(states, Acs);
    chunk_output_mfma<<<BATCH * NCHUNK * NHEADS, 256, 0, stream>>>(xconv, Sbuf, Cbuf, dtT, Acs, states, Dparam, Ybuf);
    gated_rmsnorm_k<<<M, 256, 0, stream>>>(Ybuf, zx, norm_w);   // last reader of zx

    // GEMM2 K-split-2: 256 blocks = 1 CU-round; both halves bf16; out = t0 + t1
    gemm_8ph<float, true><<<2 * (D_MODEL/256) * (M/256), 512, 0, stream>>>(
        Ybuf, WtOut, out, tmpf, M, D_MODEL, D_INNER/2, D_INNER, D_MODEL);
    add2_bf16<<<(M * D_MODEL / 8 + 255) / 256, 256, 0, stream>>>(
        out, tmpf, tmpf + (size_t)M * D_MODEL, M * D_MODEL / 8);
}

// Round 18
// 468.254 us; speedup vs baseline: 1.0089x; 1.0089x over previous
//
#include <hip/hip_runtime.h>
#include <hip/hip_bf16.h>
#include <math.h>

#define D_MODEL   2048
#define D_INNER   4096
#define NHEADS    64
#define HEAD_DIM  64
#define D_STATE   128
#define CHUNK     256
#define CONV_DIM  (D_INNER + 2*D_STATE)            // 4352
#define D_IN_PROJ (2*D_INNER + 2*D_STATE + NHEADS) // 8512
#define LD_ZX     8704                             // D_IN_PROJ padded to 256
#define BATCH     2
#define SEQ       2048
#define NCHUNK    (SEQ/CHUNK)                      // 8
#define EPS_RMS   1e-5f
#define MROWS     4096
#define TSTRIDE   ((size_t)MROWS * 512)            // tail-partial plane stride (f32 elems)

typedef unsigned short u16;
typedef __attribute__((ext_vector_type(8))) unsigned short u16x8;
typedef __attribute__((ext_vector_type(4))) unsigned short u16x4;
typedef __attribute__((ext_vector_type(8))) short bf16x8;   // MFMA A/B frag (8 bf16)
typedef __attribute__((ext_vector_type(4))) float f32x4;    // MFMA C/D frag

__device__ __forceinline__ float us2f(u16 u){
    union { unsigned int i; float f; } c; c.i = ((unsigned int)u) << 16; return c.f;
}
__device__ __forceinline__ u16 f2us(float f){
    union { float f; unsigned int i; } c; c.f = f;
    unsigned int r = c.i + 0x7FFFu + ((c.i >> 16) & 1u);
    return (u16)(r >> 16);
}
__device__ __forceinline__ float siluf(float x){ return x / (1.f + expf(-x)); }

__device__ __forceinline__ void gload_lds16(const void* g, void* l) {
    __builtin_amdgcn_global_load_lds((const __attribute__((address_space(1))) void*)g,
                                     (__attribute__((address_space(3))) void*)l, 16, 0, 0);
}

#define VMCNT(n) asm volatile("s_waitcnt vmcnt(" #n ")" ::: "memory")

// stage one 128x64 bf16 half-tile (row-major, stride ldk) into LDS with T2 swizzle.
__device__ __forceinline__ void stage_half(const u16* __restrict__ g, size_t ldk,
                                           u16* ldsbase, int w, int lane)
{
    #pragma unroll
    for (int cc = 0; cc < 2; cc++) {
        int cb = cc * 512 + w * 64;          // wave-uniform chunk base
        int ci = cb + lane;
        int sc = ci ^ ((ci >> 3) & 7);       // swizzled source chunk (involution)
        gload_lds16(&g[(size_t)(sc >> 3) * ldk + (sc & 7) * 8], ldsbase + cb * 8);
    }
}

// ---------- elementwise f32 -> bf16 ----------
__global__ __launch_bounds__(256)
void cvt_bf16(const float* __restrict__ in, u16* __restrict__ out, int n4)
{
    int i = blockIdx.x * 256 + threadIdx.x;
    if (i >= n4) return;
    float4 v = *(const float4*)&in[(size_t)i * 4];
    u16x4 o; o[0]=f2us(v.x); o[1]=f2us(v.y); o[2]=f2us(v.z); o[3]=f2us(v.w);
    *(u16x4*)&out[(size_t)i * 4] = o;
}

// ---------- out = bf16 tmp0 + bf16 tmp1 (f32 result) ----------
__global__ __launch_bounds__(256)
void add2_bf16(float* __restrict__ out, const u16* __restrict__ t0,
               const u16* __restrict__ t1, int n8)
{
    int i = blockIdx.x * 256 + threadIdx.x;
    if (i >= n8) return;
    u16x8 a = *(const u16x8*)&t0[(size_t)i * 8];
    u16x8 b = *(const u16x8*)&t1[(size_t)i * 8];
    float* o = &out[(size_t)i * 8];
    *(float4*)&o[0] = make_float4(us2f(a[0])+us2f(b[0]), us2f(a[1])+us2f(b[1]),
                                  us2f(a[2])+us2f(b[2]), us2f(a[3])+us2f(b[3]));
    *(float4*)&o[4] = make_float4(us2f(a[4])+us2f(b[4]), us2f(a[5])+us2f(b[5]),
                                  us2f(a[6])+us2f(b[6]), us2f(a[7])+us2f(b[7]));
}

// ---------- transpose + convert: in f32 [K][N] -> out bf16 [Npad][K], zero-pad n>=N ----------
__global__ __launch_bounds__(256)
void transpose_cvt(const float* __restrict__ in, u16* __restrict__ out, int K, int N)
{
    __shared__ u16 tile[64][65];
    int k0 = blockIdx.x * 64;
    int n0 = blockIdx.y * 64;
    int t = threadIdx.x;
    #pragma unroll
    for (int q = 0; q < 16; q++) {
        int lin = q * 256 + t;
        int r = lin >> 6, c = lin & 63;
        int n = n0 + c;
        float v = (n < N) ? in[(size_t)(k0 + r) * N + n] : 0.f;
        tile[r][c] = f2us(v);
    }
    __syncthreads();
    #pragma unroll
    for (int q = 0; q < 4; q++) {
        int lin = q * 256 + t;
        int r = lin >> 4, cg = lin & 15;
        u16x4 v;
        #pragma unroll
        for (int e = 0; e < 4; e++) v[e] = tile[cg*4 + e][r];
        *(u16x4*)&out[(size_t)(n0 + r) * K + k0 + cg*4] = v;
    }
}

// ---------- 8-phase 256x256 MFMA GEMM (T2-swizzled LDS, plain barriers) ----------
// Stage ledger (round-12 proven): p1: Ah1(t+1); p3: Bh0(t+2); p4: Bh1(t+2)+Ah0(t+2).
// KSPLIT: grid = 2*ntiles; kidx selects K-half; writes bf16 plane Cg2 + kidx*M*ldc.
template<typename TC, bool KSPLIT>
__global__ __launch_bounds__(512, 1)
void gemm_8ph(const u16* __restrict__ Ag, const u16* __restrict__ Btg,
              TC* __restrict__ Cg, u16* __restrict__ Cg2,
              int M, int N, int Kext, int ldk, int ldc)
{
    __shared__ u16 smA[2][2][8192];   // [dbuf][half][128*64]
    __shared__ u16 smB[2][2][8192];
    const int tid = threadIdx.x;
    const int lane = tid & 63, w = tid >> 6;
    const int wm = w >> 2, wn = w & 3;
    const int lr = lane & 15, kh = lane >> 4;
    const int swz = (lr & 7) << 3;

    int orig = blockIdx.x;
    int ntile = gridDim.x;
    int kidx = 0;
    if constexpr (KSPLIT) { kidx = orig & 1; orig >>= 1; ntile >>= 1; }

    const int nbx = N >> 8;
    const int qq = ntile >> 3, r8 = ntile & 7;
    const int xcd = orig & 7, loc = orig >> 3;
    const int wgid = (xcd < r8 ? xcd*(qq+1) : r8*(qq+1) + (xcd-r8)*qq) + loc;
    const int m0 = (wgid / nbx) * 256;
    const int n0 = (wgid % nbx) * 256;

    if constexpr (KSPLIT) {
        Ag  += (size_t)kidx * Kext;
        Btg += (size_t)kidx * Kext;
        Cg2 += (size_t)kidx * M * ldc;
    }
    const int NT = Kext >> 6;

    f32x4 acc[8][4];
    #pragma unroll
    for (int i = 0; i < 8; i++)
        #pragma unroll
        for (int j = 0; j < 4; j++) acc[i][j] = (f32x4){0.f,0.f,0.f,0.f};

    stage_half(&Ag [(size_t)(m0      ) * ldk      ], ldk, &smA[0][0][0], w, lane);
    stage_half(&Ag [(size_t)(m0 + 128) * ldk      ], ldk, &smA[0][1][0], w, lane);
    stage_half(&Btg[(size_t)(n0      ) * ldk      ], ldk, &smB[0][0][0], w, lane);
    stage_half(&Btg[(size_t)(n0 + 128) * ldk      ], ldk, &smB[0][1][0], w, lane);
    stage_half(&Ag [(size_t)(m0      ) * ldk + 64 ], ldk, &smA[1][0][0], w, lane);
    stage_half(&Btg[(size_t)(n0      ) * ldk + 64 ], ldk, &smB[1][0][0], w, lane);
    stage_half(&Btg[(size_t)(n0 + 128) * ldk + 64 ], ldk, &smB[1][1][0], w, lane);
    VMCNT(6);
    __builtin_amdgcn_s_barrier();

    for (int t = 0; t < NT; ++t) {
        const int d = t & 1;
        const u16* As = &smA[d][wm][0];
        const u16* Bs = &smB[d][wn >> 1][0];
        const int rb = (wn & 1) * 64;

        bf16x8 aF[4][2], bLo[2][2], bHi[2][2];

        // ---- phase 1: read A-lo + B-lo; stage Ah1(t+1)
        #pragma unroll
        for (int i = 0; i < 4; i++)
            #pragma unroll
            for (int ks = 0; ks < 2; ks++)
                aF[i][ks] = *(const bf16x8*)&As[(i*16 + lr)*64 + ((ks*32 + kh*8) ^ swz)];
        #pragma unroll
        for (int j = 0; j < 2; j++)
            #pragma unroll
            for (int ks = 0; ks < 2; ks++)
                bLo[j][ks] = *(const bf16x8*)&Bs[(rb + j*16 + lr)*64 + ((ks*32 + kh*8) ^ swz)];
        if (t + 1 < NT)
            stage_half(&Ag[(size_t)(m0 + 128) * ldk + (t+1)*64], ldk, &smA[d^1][1][0], w, lane);
        __builtin_amdgcn_s_barrier();
        __builtin_amdgcn_s_setprio(1);
        #pragma unroll
        for (int i = 0; i < 4; i++)
            #pragma unroll
            for (int j = 0; j < 2; j++)
                #pragma unroll
                for (int ks = 0; ks < 2; ks++)
                    acc[i][j] = __builtin_amdgcn_mfma_f32_16x16x32_bf16(aF[i][ks], bLo[j][ks], acc[i][j], 0, 0, 0);
        __builtin_amdgcn_s_setprio(0);
        __builtin_amdgcn_s_barrier();

        // ---- phase 2: read B-hi
        #pragma unroll
        for (int j = 0; j < 2; j++)
            #pragma unroll
            for (int ks = 0; ks < 2; ks++)
                bHi[j][ks] = *(const bf16x8*)&Bs[(rb + (2+j)*16 + lr)*64 + ((ks*32 + kh*8) ^ swz)];
        __builtin_amdgcn_s_barrier();
        __builtin_amdgcn_s_setprio(1);
        #pragma unroll
        for (int i = 0; i < 4; i++)
            #pragma unroll
            for (int j = 0; j < 2; j++)
                #pragma unroll
                for (int ks = 0; ks < 2; ks++)
                    acc[i][2+j] = __builtin_amdgcn_mfma_f32_16x16x32_bf16(aF[i][ks], bHi[j][ks], acc[i][2+j], 0, 0, 0);
        __builtin_amdgcn_s_setprio(0);
        __builtin_amdgcn_s_barrier();

        // ---- phase 3: read A-hi (overwrites aF); stage Bh0(t+2)
        #pragma unroll
        for (int i = 0; i < 4; i++)
            #pragma unroll
            for (int ks = 0; ks < 2; ks++)
                aF[i][ks] = *(const bf16x8*)&As[(64 + i*16 + lr)*64 + ((ks*32 + kh*8) ^ swz)];
        if (t + 2 < NT)
            stage_half(&Btg[(size_t)(n0) * ldk + (t+2)*64], ldk, &smB[d][0][0], w, lane);
        __builtin_amdgcn_s_barrier();
        __builtin_amdgcn_s_setprio(1);
        #pragma unroll
        for (int i = 0; i < 4; i++)
            #pragma unroll
            for (int j = 0; j < 2; j++)
                #pragma unroll
                for (int ks = 0; ks < 2; ks++)
                    acc[4+i][j] = __builtin_amdgcn_mfma_f32_16x16x32_bf16(aF[i][ks], bLo[j][ks], acc[4+i][j], 0, 0, 0);
        __builtin_amdgcn_s_setprio(0);
        __builtin_amdgcn_s_barrier();

        // ---- phase 4: stage Bh1(t+2)+Ah0(t+2); MFMA; counted vmcnt after
        if (t + 2 < NT) {
            stage_half(&Btg[(size_t)(n0 + 128) * ldk + (t+2)*64], ldk, &smB[d][1][0], w, lane);
            stage_half(&Ag [(size_t)(m0      ) * ldk + (t+2)*64], ldk, &smA[d][0][0], w, lane);
        }
        __builtin_amdgcn_s_barrier();
        __builtin_amdgcn_s_setprio(1);
        #pragma unroll
        for (int i = 0; i < 4; i++)
            #pragma unroll
            for (int j = 0; j < 2; j++)
                #pragma unroll
                for (int ks = 0; ks < 2; ks++)
                    acc[4+i][2+j] = __builtin_amdgcn_mfma_f32_16x16x32_bf16(aF[i][ks], bHi[j][ks], acc[4+i][2+j], 0, 0, 0);
        __builtin_amdgcn_s_setprio(0);
        if (t < NT - 2)       { VMCNT(6); }
        else if (t == NT - 2) { VMCNT(0); }
        __builtin_amdgcn_s_barrier();
    }

    #pragma unroll
    for (int mf = 0; mf < 8; mf++) {
        #pragma unroll
        for (int nf = 0; nf < 4; nf++) {
            int r = m0 + wm*128 + mf*16 + kh*4;
            int cidx = n0 + wn*64 + nf*16 + lr;
            #pragma unroll
            for (int q = 0; q < 4; q++) {
                if constexpr (KSPLIT) {
                    Cg2[(size_t)(r+q)*ldc + cidx] = f2us(acc[mf][nf][q]);
                } else if constexpr (sizeof(TC) == 4) {
                    Cg[(size_t)(r+q)*ldc + cidx] = acc[mf][nf][q];
                } else {
                    Cg[(size_t)(r+q)*ldc + cidx] = f2us(acc[mf][nf][q]);
                }
            }
        }
    }
}

// ---------- GEMM1 tail: N=512, K-split-4, 2-phase 128x128, f32 partials ----------
__global__ __launch_bounds__(256)
void gemm_tail_ks4(const u16* __restrict__ A, const u16* __restrict__ Bt,
                   float* __restrict__ Cp, int M, int ldk)
{
    __shared__ u16 Asm[128][32];
    __shared__ u16 Bsm[128][32];
    const int t = threadIdx.x;
    const int lane = t & 63, w = t >> 6;
    const int wr = w >> 1, wc = w & 1;
    const int lr = lane & 15, kh = lane >> 4;

    const int bid = blockIdx.x;
    const int kidx = bid & 3, tile = bid >> 2;
    const int m0 = (tile >> 2) * 128;
    const int n0 = (tile & 3) * 128;

    const u16* Ak = A  + kidx * 512;
    const u16* Bk = Bt + kidx * 512;
    float* C = Cp + (size_t)kidx * TSTRIDE;

    f32x4 acc[4][4];
    #pragma unroll
    for (int i = 0; i < 4; i++)
        #pragma unroll
        for (int j = 0; j < 4; j++) acc[i][j] = (f32x4){0.f,0.f,0.f,0.f};

    for (int k0 = 0; k0 < 512; k0 += 32) {
        #pragma unroll
        for (int i = 0; i < 2; i++) {
            int cb = i * 256 + w * 64;
            int chunk = cb + lane;
            int row = chunk >> 2, kb = chunk & 3;
            gload_lds16(&Ak[(size_t)(m0 + row) * ldk + k0 + kb * 8], &Asm[0][0] + cb * 8);
            gload_lds16(&Bk[(size_t)(n0 + row) * ldk + k0 + kb * 8], &Bsm[0][0] + cb * 8);
        }
        __syncthreads();
        bf16x8 af[4], bf[4];
        #pragma unroll
        for (int i = 0; i < 4; i++)
            af[i] = *(const bf16x8*)&Asm[wr*64 + i*16 + lr][kh*8];
        #pragma unroll
        for (int j = 0; j < 4; j++)
            bf[j] = *(const bf16x8*)&Bsm[wc*64 + j*16 + lr][kh*8];
        #pragma unroll
        for (int i = 0; i < 4; i++)
            #pragma unroll
            for (int j = 0; j < 4; j++)
                acc[i][j] = __builtin_amdgcn_mfma_f32_16x16x32_bf16(af[i], bf[j], acc[i][j], 0, 0, 0);
        __syncthreads();
    }
    #pragma unroll
    for (int i = 0; i < 4; i++) {
        #pragma unroll
        for (int j = 0; j < 4; j++) {
            int r = m0 + wr*64 + i*16 + kh*4;
            int cidx = n0 + wc*64 + j*16 + lr;
            #pragma unroll
            for (int q = 0; q < 4; q++)
                C[(size_t)(r+q)*512 + cidx] = acc[i][j][q];
        }
    }
}

// ---------------- conv1d + bias + SiLU; B/C channels read 4 tail partials directly ----------------
__global__ __launch_bounds__(256)
void conv_silu(const u16* __restrict__ zx, const float* __restrict__ tailp,
               const float* __restrict__ cw, const float* __restrict__ cb,
               u16* __restrict__ xconv, u16* __restrict__ Bbuf, u16* __restrict__ Cbuf)
{
    int idx = blockIdx.x * 256 + threadIdx.x;
    int cg = idx % (CONV_DIM / 8);
    int r  = idx / (CONV_DIM / 8);
    int c0 = cg * 8;
    int l  = r & (SEQ - 1);

    float y[8];
    {
        float4 b0 = *(const float4*)&cb[c0];
        float4 b1 = *(const float4*)&cb[c0 + 4];
        y[0]=b0.x; y[1]=b0.y; y[2]=b0.z; y[3]=b0.w;
        y[4]=b1.x; y[5]=b1.y; y[6]=b1.z; y[7]=b1.w;
    }
    float cwf[8][4];
    #pragma unroll
    for (int e = 0; e < 8; e++) {
        float4 v = *(const float4*)&cw[(c0 + e) * 4];
        cwf[e][0]=v.x; cwf[e][1]=v.y; cwf[e][2]=v.z; cwf[e][3]=v.w;
    }
    if (c0 < D_INNER) {                      // x channels: zx cols [4096, 8192)
        #pragma unroll
        for (int k = 0; k < 4; k++) {
            if (l + k - 3 >= 0) {
                u16x8 v = *(const u16x8*)&zx[(size_t)(r + k - 3) * LD_ZX + D_INNER + c0];
                #pragma unroll
                for (int e = 0; e < 8; e++) y[e] += us2f(v[e]) * cwf[e][k];
            }
        }
    } else {                                 // B/C channels: sum 4 tail partials
        int tc = c0 - D_INNER;
        #pragma unroll
        for (int k = 0; k < 4; k++) {
            if (l + k - 3 >= 0) {
                const float* tb = &tailp[(size_t)(r + k - 3) * 512 + tc];
                #pragma unroll
                for (int e = 0; e < 8; e++) {
                    float s = tb[e] + tb[TSTRIDE + e] + tb[2*TSTRIDE + e] + tb[3*TSTRIDE + e];
                    y[e] += s * cwf[e][k];
                }
            }
        }
    }
    u16x8 o;
    #pragma unroll
    for (int e = 0; e < 8; e++) {
        float s = y[e] / (1.f + expf(-y[e]));
        o[e] = f2us(s);
    }
    if (c0 < D_INNER)                *(u16x8*)&xconv[(size_t)r * D_INNER + c0] = o;
    else if (c0 < D_INNER + D_STATE) *(u16x8*)&Bbuf[(size_t)r * D_STATE + (c0 - D_INNER)] = o;
    else                             *(u16x8*)&Cbuf[(size_t)r * D_STATE + (c0 - D_INNER - D_STATE)] = o;
}

// ---------------- dt softplus + per-chunk cumsum (dt from tail partials) ----------------
__global__ __launch_bounds__(256)
void dt_acs(const float* __restrict__ tailp, const float* __restrict__ Aparam,
            const float* __restrict__ dt_bias, float* __restrict__ dtT,
            float* __restrict__ Acs)
{
    __shared__ float sb[CHUNK];
    int blk = blockIdx.x;
    int c = blk & 7, h = (blk >> 3) & 63, b = blk >> 9;
    int t = threadIdx.x;
    int lg = c * CHUNK + t;
    int row = b * SEQ + lg;
    const float* tb = &tailp[(size_t)row * 512 + 256 + h];
    float x = tb[0] + tb[TSTRIDE] + tb[2*TSTRIDE] + tb[3*TSTRIDE];
    x += dt_bias[h];
    float dt = (x > 20.f) ? x : log1pf(expf(x));
    float v = dt * Aparam[h];
    sb[t] = v; __syncthreads();
    #pragma unroll
    for (int off = 1; off < 256; off <<= 1) {
        float add = (t >= off) ? sb[t - off] : 0.f;
        __syncthreads();
        v += add; sb[t] = v;
        __syncthreads();
    }
    int o = (b * NHEADS + h) * SEQ + lg;
    dtT[o] = dt;
    Acs[o] = v;
}

// ---------------- S precompute: S[bc][l][s] = C_l . B_s (head-shared, lower-tri tiles) ----------------
__global__ __launch_bounds__(256)
void s_precompute(const u16* __restrict__ Bbuf, const u16* __restrict__ Cbuf,
                  u16* __restrict__ Sbuf)
{
    int p = blockIdx.x % 10, bc = blockIdx.x / 10;
    int q = (p >= 6) ? 3 : (p >= 3) ? 2 : (p >= 1) ? 1 : 0;
    int st = p - q * (q + 1) / 2;
    int b = bc >> 3, c = bc & 7;
    const int lane = threadIdx.x & 63, w = threadIdx.x >> 6;
    const int lr = lane & 15, kh = lane >> 4;
    const size_t rowbase = (size_t)(b * SEQ + c * CHUNK);

    f32x4 sacc[4];
    #pragma unroll
    for (int i = 0; i < 4; i++) sacc[i] = (f32x4){0.f,0.f,0.f,0.f};
    #pragma unroll
    for (int kk = 0; kk < 4; kk++) {
        bf16x8 bA = *(const bf16x8*)&Bbuf[(rowbase + st*64 + w*16 + lr) * D_STATE + kk*32 + kh*8];
        #pragma unroll
        for (int i = 0; i < 4; i++) {
            bf16x8 af = *(const bf16x8*)&Cbuf[(rowbase + q*64 + i*16 + lr) * D_STATE + kk*32 + kh*8];
            sacc[i] = __builtin_amdgcn_mfma_f32_16x16x32_bf16(bA, af, sacc[i], 0, 0, 0);
        }
    }
    u16* Sb = Sbuf + (size_t)bc * 256 * 256;
    #pragma unroll
    for (int i = 0; i < 4; i++) {
        u16x4 o;
        #pragma unroll
        for (int qq = 0; qq < 4; qq++) o[qq] = f2us(sacc[i][qq]);
        *(u16x4*)&Sb[(size_t)(q*64 + i*16 + lr) * 256 + st*64 + w*16 + kh*4] = o;
    }
}

// ---------------- per-chunk states via MFMA, bf16 out, swapped operands ----------------
__global__ __launch_bounds__(256)
void chunk_states_mfma(const u16* __restrict__ xconv, const u16* __restrict__ Bbuf,
                       const float* __restrict__ dtT, const float* __restrict__ Acs,
                       u16* __restrict__ states)
{
    __shared__ u16 Btsh[128][72];   // B^T [n][l]
    __shared__ u16 xtsh[64][72];    // (w*x)^T [p][l]
    __shared__ float acs_sh[CHUNK];
    __shared__ float dt_sh[CHUNK];

    const int blk = blockIdx.x;
    const int h = blk & 63, c = (blk >> 6) & 7, b = blk >> 9;
    const int t = threadIdx.x;
    const int lane = t & 63, w = t >> 6;
    const int wr = w >> 1, wc = w & 1;
    const int lr = lane & 15, kh = lane >> 4;
    const int bh = b * NHEADS + h;
    const size_t rowbase = (size_t)(b * SEQ + c * CHUNK);

    acs_sh[t] = Acs[(size_t)bh * SEQ + c * CHUNK + t];
    dt_sh[t]  = dtT[(size_t)bh * SEQ + c * CHUNK + t];
    __syncthreads();
    const float acs_last = acs_sh[CHUNK - 1];

    f32x4 acc[4][2];   // [j = n-block][i = p-block]
    #pragma unroll
    for (int j = 0; j < 4; j++)
        #pragma unroll
        for (int i = 0; i < 2; i++) acc[j][i] = (f32x4){0.f,0.f,0.f,0.f};

    for (int lt = 0; lt < 4; lt++) {
        __syncthreads();
        const int s = t & 63;
        const int sg = lt * 64 + s;
        const float wgt = dt_sh[sg] * expf(acs_last - acs_sh[sg]);
        {
            int ng = (t >> 6) * 32;
            const u16* src = &Bbuf[(rowbase + sg) * D_STATE + ng];
            #pragma unroll
            for (int q = 0; q < 4; q++) {
                u16x8 v = *(const u16x8*)&src[q * 8];
                #pragma unroll
                for (int e = 0; e < 8; e++)
                    Btsh[ng + q*8 + e][s] = v[e];
            }
        }
        {
            int pg = (t >> 6) * 16;
            const u16* src = &xconv[(rowbase + sg) * D_INNER + h * HEAD_DIM + pg];
            u16x8 v0 = *(const u16x8*)&src[0];
            u16x8 v1 = *(const u16x8*)&src[8];
            #pragma unroll
            for (int e = 0; e < 8; e++) {
                xtsh[pg + e][s]     = f2us(us2f(v0[e]) * wgt);
                xtsh[pg + 8 + e][s] = f2us(us2f(v1[e]) * wgt);
            }
        }
        __syncthreads();
        #pragma unroll
        for (int kk = 0; kk < 2; kk++) {
            bf16x8 xf[2], bf[4];
            #pragma unroll
            for (int i = 0; i < 2; i++)
                xf[i] = *(const bf16x8*)&xtsh[wr*32 + i*16 + lr][kk*32 + kh*8];
            #pragma unroll
            for (int j = 0; j < 4; j++)
                bf[j] = *(const bf16x8*)&Btsh[wc*64 + j*16 + lr][kk*32 + kh*8];
            #pragma unroll
            for (int j = 0; j < 4; j++)
                #pragma unroll
                for (int i = 0; i < 2; i++)
                    acc[j][i] = __builtin_amdgcn_mfma_f32_16x16x32_bf16(bf[j], xf[i], acc[j][i], 0, 0, 0);
        }
    }
    size_t base = ((size_t)((b*NCHUNK + c)*NHEADS + h)) * (HEAD_DIM * D_STATE);
    #pragma unroll
    for (int j = 0; j < 4; j++) {
        #pragma unroll
        for (int i = 0; i < 2; i++) {
            int p = wr*32 + i*16 + lr;
            int n = wc*64 + j*16 + kh*4;
            u16x4 o;
            #pragma unroll
            for (int q = 0; q < 4; q++) o[q] = f2us(acc[j][i][q]);
            *(u16x4*)&states[base + (size_t)p * D_STATE + n] = o;
        }
    }
}

// ---------------- inter-chunk recurrence, bf16 states ----------------
__global__ __launch_bounds__(256)
void state_recurrence(u16* __restrict__ states, const float* __restrict__ Acs)
{
    int idx = blockIdx.x * 256 + threadIdx.x;
    int n8 = idx & 15;
    int p  = (idx >> 4) & 63;
    int bh = idx >> 10;
    int b = bh >> 6, h = bh & 63;
    float E[8];
    #pragma unroll
    for (int e = 0; e < 8; e++) E[e] = 0.f;
    for (int c = 0; c < NCHUNK; c++) {
        size_t off = ((size_t)((b*NCHUNK + c)*NHEADS + h)) * 8192 + (size_t)p * 128 + n8 * 8;
        u16x8 sv = *(const u16x8*)&states[off];
        u16x8 ev;
        #pragma unroll
        for (int e = 0; e < 8; e++) ev[e] = f2us(E[e]);
        *(u16x8*)&states[off] = ev;
        float g = expf(Acs[(size_t)(b*NHEADS + h) * SEQ + c*CHUNK + 255]);
        #pragma unroll
        for (int e = 0; e < 8; e++) E[e] = g * E[e] + us2f(sv[e]);
    }
}

// ---------------- chunk output: Y_off-first; S read from precomputed head-shared Sbuf ----------------
__global__ __launch_bounds__(256, 1)
void chunk_output_mfma(const u16* __restrict__ xconv, const u16* __restrict__ Sbuf,
                       const u16* __restrict__ Cbuf, const float* __restrict__ dtT,
                       const float* __restrict__ Acs, const u16* __restrict__ states,
                       const float* __restrict__ Dparam, u16* __restrict__ Y)
{
    __shared__ u16 Bsm[64][136];       // prev [p][n] only
    __shared__ u16 xt[64][72];         // x^T tile [p][s]
    __shared__ u16 Pt[4][64][72];      // per-wave P [l][s]
    __shared__ float acs_sh[CHUNK];
    __shared__ float dt_sh[CHUNK];

    const int blk = blockIdx.x;
    const int h = blk & 63, c = (blk >> 6) & 7, b = blk >> 9;
    const int t = threadIdx.x;
    const int lane = t & 63, w = t >> 6;
    const int lr = lane & 15, kh = lane >> 4;
    const int bh = b * NHEADS + h;
    const size_t rowbase = (size_t)(b * SEQ + c * CHUNK);
    const u16* Sblk = Sbuf + (size_t)(b * NCHUNK + c) * 256 * 256;

    acs_sh[t] = Acs[(size_t)bh * SEQ + c * CHUNK + t];
    dt_sh[t]  = dtT[(size_t)bh * SEQ + c * CHUNK + t];

    bf16x8 af[4][4];
    #pragma unroll
    for (int i = 0; i < 4; i++)
        #pragma unroll
        for (int kk = 0; kk < 4; kk++)
            af[i][kk] = *(const bf16x8*)&Cbuf[(rowbase + w*64 + i*16 + lr) * D_STATE + kk*32 + kh*8];

    {   // stage prev into Bsm [p][n]
        int p = t >> 2, ng = (t & 3) * 32;
        const u16* src = &states[((size_t)((b*NCHUNK + c)*NHEADS + h)) * 8192 + (size_t)p * 128 + ng];
        #pragma unroll
        for (int q = 0; q < 4; q++)
            *(u16x8*)&Bsm[p][ng + q*8] = *(const u16x8*)&src[q*8];
    }
    __syncthreads();
    float acs_l[4], el[4];
    #pragma unroll
    for (int i = 0; i < 4; i++) { acs_l[i] = acs_sh[w*64 + i*16 + lr]; el[i] = expf(acs_l[i]); }

    // Y_off raw: yacc[j][i] = prev . C (unscaled), then scale by el[i]
    f32x4 yacc[4][4];
    #pragma unroll
    for (int j = 0; j < 4; j++)
        #pragma unroll
        for (int i = 0; i < 4; i++) yacc[j][i] = (f32x4){0.f,0.f,0.f,0.f};
    #pragma unroll
    for (int kk = 0; kk < 4; kk++) {
        bf16x8 pvA[4];
        #pragma unroll
        for (int j = 0; j < 4; j++)
            pvA[j] = *(const bf16x8*)&Bsm[j*16 + lr][kk*32 + kh*8];
        #pragma unroll
        for (int j = 0; j < 4; j++)
            #pragma unroll
            for (int i = 0; i < 4; i++)
                yacc[j][i] = __builtin_amdgcn_mfma_f32_16x16x32_bf16(pvA[j], af[i][kk], yacc[j][i], 0, 0, 0);
    }
    #pragma unroll
    for (int j = 0; j < 4; j++)
        #pragma unroll
        for (int i = 0; i < 4; i++)
            #pragma unroll
            for (int q = 0; q < 4; q++)
                yacc[j][i][q] *= el[i];

    for (int st = 0; st < 4; st++) {
        __syncthreads();
        {   // stage x^T tile [p][s]
            int s = t & 63, pg = t >> 6;
            const u16* src = &xconv[(rowbase + st*64 + s) * D_INNER + h*HEAD_DIM + pg*16];
            u16x8 v0 = *(const u16x8*)&src[0];
            u16x8 v1 = *(const u16x8*)&src[8];
            #pragma unroll
            for (int q = 0; q < 8; q++) { xt[pg*16 + q][s] = v0[q]; xt[pg*16 + 8 + q][s] = v1[q]; }
        }
        __syncthreads();
        if (st > w) continue;

        // P = mask(S) * dt, S loaded from head-shared Sbuf
        #pragma unroll
        for (int js = 0; js < 4; js++) {
            int s0 = st*64 + js*16;
            float as0 = acs_sh[s0];
            int sgq = s0 + kh*4;
            float eneg[4];
            #pragma unroll
            for (int q = 0; q < 4; q++)
                eneg[q] = expf(fminf(as0 - acs_sh[sgq + q], 60.f)) * dt_sh[sgq + q];
            #pragma unroll
            for (int i = 0; i < 4; i++) {
                int ll = w*64 + i*16 + lr;
                float eladj = expf(acs_l[i] - as0);
                u16x4 sv = *(const u16x4*)&Sblk[(size_t)ll * 256 + sgq];
                u16x4 pv;
                #pragma unroll
                for (int q = 0; q < 4; q++) {
                    float fac = (sgq + q <= ll) ? eladj * eneg[q] : 0.f;
                    pv[q] = f2us(us2f(sv[q]) * fac);
                }
                *(u16x4*)&Pt[w][i*16 + lr][js*16 + kh*4] = pv;
            }
        }
        #pragma unroll
        for (int kk2 = 0; kk2 < 2; kk2++) {
            bf16x8 xA[4], pB[4];
            #pragma unroll
            for (int j = 0; j < 4; j++)
                xA[j] = *(const bf16x8*)&xt[j*16 + lr][kk2*32 + kh*8];
            #pragma unroll
            for (int i = 0; i < 4; i++)
                pB[i] = *(const bf16x8*)&Pt[w][i*16 + lr][kk2*32 + kh*8];
            #pragma unroll
            for (int j = 0; j < 4; j++)
                #pragma unroll
                for (int i = 0; i < 4; i++)
                    yacc[j][i] = __builtin_amdgcn_mfma_f32_16x16x32_bf16(xA[j], pB[i], yacc[j][i], 0, 0, 0);
        }
    }

    float Dh = Dparam[h];
    #pragma unroll
    for (int i = 0; i < 4; i++) {
        #pragma unroll
        for (int j = 0; j < 4; j++) {
            size_t o = (rowbase + w*64 + i*16 + lr) * D_INNER + h*HEAD_DIM + j*16 + kh*4;
            u16x4 xv = *(const u16x4*)&xconv[o];
            u16x4 ov;
            #pragma unroll
            for (int q = 0; q < 4; q++)
                ov[q] = f2us(yacc[j][i][q] + Dh * us2f(xv[q]));
            *(u16x4*)&Y[o] = ov;
        }
    }
}

// ---------------- gated RMSNorm ----------------
__global__ __launch_bounds__(256)
void gated_rmsnorm_k(u16* __restrict__ Y, const u16* __restrict__ zx,
                     const float* __restrict__ nw)
{
    __shared__ float xs[D_INNER];
    __shared__ float red[8];
    int row = blockIdx.x;
    int t = threadIdx.x;
    float ss = 0.f;
    for (int i = t*8; i < D_INNER; i += 2048) {
        u16x8 yv = *(const u16x8*)&Y[(size_t)row * D_INNER + i];
        u16x8 zv = *(const u16x8*)&zx[(size_t)row * LD_ZX + i];
        #pragma unroll
        for (int q = 0; q < 8; q++) {
            float x = us2f(yv[q]) * siluf(us2f(zv[q]));
            xs[i + q] = x;
            ss += x * x;
        }
    }
    #pragma unroll
    for (int off = 32; off > 0; off >>= 1) ss += __shfl_down(ss, off);
    int wid = t >> 6, lane = t & 63;
    if (lane == 0) red[wid] = ss;
    __syncthreads();
    if (t == 0) {
        float tot = red[0] + red[1] + red[2] + red[3];
        red[0] = rsqrtf(tot / (float)D_INNER + EPS_RMS);
    }
    __syncthreads();
    float sc = red[0];
    for (int i = t*8; i < D_INNER; i += 2048) {
        u16x8 o;
        #pragma unroll
        for (int q = 0; q < 8; q++) o[q] = f2us(xs[i + q] * sc * nw[i + q]);
        *(u16x8*)&Y[(size_t)row * D_INNER + i] = o;
    }
}

__global__ void ws_fail_k(float* out, float mb){ out[threadIdx.x] = mb; }

// ---------------- launch ----------------
extern "C" void kernel_launch(void* const* d_in, const int* in_sizes, int n_in,
                              void* d_out, int out_size, void* d_ws, size_t ws_size,
                              hipStream_t stream)
{
    const float* hidden  = (const float*)d_in[0];
    const float* W_in    = (const float*)d_in[1];
    const float* conv_w  = (const float*)d_in[2];
    const float* conv_b  = (const float*)d_in[3];
    const float* Aparam  = (const float*)d_in[4];
    const float* Dparam  = (const float*)d_in[5];
    const float* dt_bias = (const float*)d_in[6];
    const float* norm_w  = (const float*)d_in[7];
    const float* W_out   = (const float*)d_in[8];
    float* out = (float*)d_out;

    const int M = BATCH * SEQ;  // 4096

    size_t off = 0;
    char* wsb = (char*)d_ws;
    u16*   zx     = (u16*)  (wsb + off); off += (size_t)M * LD_ZX * 2;
    u16*   xconv  = (u16*)  (wsb + off); off += (size_t)M * D_INNER * 2;
    u16*   Bbuf   = (u16*)  (wsb + off); off += (size_t)M * D_STATE * 2;
    u16*   Cbuf   = (u16*)  (wsb + off); off += (size_t)M * D_STATE * 2;
    float* dtT    = (float*)(wsb + off); off += (size_t)BATCH * NHEADS * SEQ * 4;
    float* Acs    = (float*)(wsb + off); off += (size_t)BATCH * NHEADS * SEQ * 4;
    u16*   states = (u16*)  (wsb + off); off += (size_t)BATCH * NCHUNK * NHEADS * HEAD_DIM * D_STATE * 2;
    u16*   Ybuf   = (u16*)  (wsb + off); off += (size_t)M * D_INNER * 2;
    u16*   hbf    = (u16*)  (wsb + off); off += (size_t)M * D_MODEL * 2;
    u16*   WtIn   = (u16*)  (wsb + off); off += (size_t)LD_ZX * D_MODEL * 2;
    u16*   WtOut  = (u16*)  (wsb + off); off += (size_t)D_MODEL * D_INNER * 2;
    float* tailp  = (float*)(wsb + off); off += 4 * TSTRIDE * 4;            // 33.5 MB
    u16*   Sbuf   = (u16*)  (wsb + off); off += (size_t)16 * 256 * 256 * 2; // 2 MB
    u16*   tmpf   = (u16*)zx;   // GEMM2 bf16 planes alias zx (dead after gated_rmsnorm)

    if (off > ws_size) {
        ws_fail_k<<<1, 64, 0, stream>>>(out, (float)(ws_size >> 20));
        return;
    }

    cvt_bf16<<<(M * D_MODEL / 4 + 255) / 256, 256, 0, stream>>>(hidden, hbf, M * D_MODEL / 4);
    transpose_cvt<<<dim3(D_MODEL/64, LD_ZX/64), 256, 0, stream>>>(W_in, WtIn, D_MODEL, D_IN_PROJ);
    transpose_cvt<<<dim3(D_INNER/64, D_MODEL/64), 256, 0, stream>>>(W_out, WtOut, D_INNER, D_MODEL);

    // GEMM1 main: zx[:, 0:8192] — 512 blocks = exactly 2 CU-rounds
    gemm_8ph<u16, false><<<(8192/256) * (M/256), 512, 0, stream>>>(
        hbf, WtIn, zx, nullptr, M, 8192, D_MODEL, D_MODEL, LD_ZX);
    // GEMM1 tail: cols [8192:8704] — K-split-4 f32 partials, consumed by conv/dt directly
    gemm_tail_ks4<<<512, 256, 0, stream>>>(hbf, WtIn + (size_t)8192 * D_MODEL, tailp, M, D_MODEL);

    conv_silu<<<(M * CONV_DIM / 8) / 256, 256, 0, stream>>>(zx, tailp, conv_w, conv_b, xconv, Bbuf, Cbuf);
    s_precompute<<<160, 256, 0, stream>>>(Bbuf, Cbuf, Sbuf);
    dt_acs<<<BATCH * NHEADS * NCHUNK, 256, 0, stream>>>(tailp, Aparam, dt_bias, dtT, Acs);
    chunk_states_mfma<<<BATCH * NCHUNK * NHEADS, 256, 0, stream>>>(xconv, Bbuf, dtT, Acs, states);
    state_recurrence<<<(BATCH * NHEADS * 64 * 16) / 256, 256, 0, stream>>>(states, Acs);
    chunk_output_mfma<<<BATCH * NCHUNK * NHEADS, 256, 0, stream>>>(xconv, Sbuf, Cbuf, dtT, Acs, states, Dparam, Ybuf);
    gated_rmsnorm_k<<<M, 256, 0, stream>>>(Ybuf, zx, norm_w);   // last reader of zx

    // GEMM2 K-split-2: 256 blocks = 1 CU-round; both halves bf16; out = t0 + t1
    gemm_8ph<float, true><<<2 * (D_MODEL/256) * (M/256), 512, 0, stream>>>(
        Ybuf, WtOut, out, tmpf, M, D_MODEL, D_INNER/2, D_INNER, D_MODEL);
    add2_bf16<<<(M * D_MODEL / 8 + 255) / 256, 256, 0, stream>>>(
        out, tmpf, tmpf + (size_t)M * D_MODEL, M * D_MODEL / 8);
}

// Round 19
// 449.955 us; speedup vs baseline: 1.0500x; 1.0407x over previous
//
#include <hip/hip_runtime.h>
#include <hip/hip_bf16.h>
#include <math.h>

#define D_MODEL   2048
#define D_INNER   4096
#define NHEADS    64
#define HEAD_DIM  64
#define D_STATE   128
#define CHUNK     256
#define CONV_DIM  (D_INNER + 2*D_STATE)            // 4352
#define D_IN_PROJ (2*D_INNER + 2*D_STATE + NHEADS) // 8512
#define LD_ZX     8704                             // D_IN_PROJ padded to 256
#define BATCH     2
#define SEQ       2048
#define NCHUNK    (SEQ/CHUNK)                      // 8
#define EPS_RMS   1e-5f
#define MROWS     4096
#define TSTRIDE   ((size_t)MROWS * 512)            // tail-partial plane stride (f32 elems)

typedef unsigned short u16;
typedef __attribute__((ext_vector_type(8))) unsigned short u16x8;
typedef __attribute__((ext_vector_type(4))) unsigned short u16x4;
typedef __attribute__((ext_vector_type(8))) short bf16x8;   // MFMA A/B frag (8 bf16)
typedef __attribute__((ext_vector_type(4))) float f32x4;    // MFMA C/D frag

__device__ __forceinline__ float us2f(u16 u){
    union { unsigned int i; float f; } c; c.i = ((unsigned int)u) << 16; return c.f;
}
__device__ __forceinline__ u16 f2us(float f){
    union { float f; unsigned int i; } c; c.f = f;
    unsigned int r = c.i + 0x7FFFu + ((c.i >> 16) & 1u);
    return (u16)(r >> 16);
}
__device__ __forceinline__ float siluf(float x){ return x / (1.f + expf(-x)); }

__device__ __forceinline__ void gload_lds16(const void* g, void* l) {
    __builtin_amdgcn_global_load_lds((const __attribute__((address_space(1))) void*)g,
                                     (__attribute__((address_space(3))) void*)l, 16, 0, 0);
}

#define VMCNT(n) asm volatile("s_waitcnt vmcnt(" #n ")" ::: "memory")

// stage one 128x64 bf16 half-tile (row-major, stride ldk) into LDS with T2 swizzle.
__device__ __forceinline__ void stage_half(const u16* __restrict__ g, size_t ldk,
                                           u16* ldsbase, int w, int lane)
{
    #pragma unroll
    for (int cc = 0; cc < 2; cc++) {
        int cb = cc * 512 + w * 64;          // wave-uniform chunk base
        int ci = cb + lane;
        int sc = ci ^ ((ci >> 3) & 7);       // swizzled source chunk (involution)
        gload_lds16(&g[(size_t)(sc >> 3) * ldk + (sc & 7) * 8], ldsbase + cb * 8);
    }
}

// ---------- elementwise f32 -> bf16 ----------
__global__ __launch_bounds__(256)
void cvt_bf16(const float* __restrict__ in, u16* __restrict__ out, int n4)
{
    int i = blockIdx.x * 256 + threadIdx.x;
    if (i >= n4) return;
    float4 v = *(const float4*)&in[(size_t)i * 4];
    u16x4 o; o[0]=f2us(v.x); o[1]=f2us(v.y); o[2]=f2us(v.z); o[3]=f2us(v.w);
    *(u16x4*)&out[(size_t)i * 4] = o;
}

// ---------- out = bf16 tmp0 + bf16 tmp1 (f32 result) ----------
__global__ __launch_bounds__(256)
void add2_bf16(float* __restrict__ out, const u16* __restrict__ t0,
               const u16* __restrict__ t1, int n8)
{
    int i = blockIdx.x * 256 + threadIdx.x;
    if (i >= n8) return;
    u16x8 a = *(const u16x8*)&t0[(size_t)i * 8];
    u16x8 b = *(const u16x8*)&t1[(size_t)i * 8];
    float* o = &out[(size_t)i * 8];
    *(float4*)&o[0] = make_float4(us2f(a[0])+us2f(b[0]), us2f(a[1])+us2f(b[1]),
                                  us2f(a[2])+us2f(b[2]), us2f(a[3])+us2f(b[3]));
    *(float4*)&o[4] = make_float4(us2f(a[4])+us2f(b[4]), us2f(a[5])+us2f(b[5]),
                                  us2f(a[6])+us2f(b[6]), us2f(a[7])+us2f(b[7]));
}

// ---------- transpose + convert: in f32 [K][N] -> out bf16 [Npad][K], zero-pad n>=N ----------
__global__ __launch_bounds__(256)
void transpose_cvt(const float* __restrict__ in, u16* __restrict__ out, int K, int N)
{
    __shared__ u16 tile[64][65];
    int k0 = blockIdx.x * 64;
    int n0 = blockIdx.y * 64;
    int t = threadIdx.x;
    #pragma unroll
    for (int q = 0; q < 16; q++) {
        int lin = q * 256 + t;
        int r = lin >> 6, c = lin & 63;
        int n = n0 + c;
        float v = (n < N) ? in[(size_t)(k0 + r) * N + n] : 0.f;
        tile[r][c] = f2us(v);
    }
    __syncthreads();
    #pragma unroll
    for (int q = 0; q < 4; q++) {
        int lin = q * 256 + t;
        int r = lin >> 4, cg = lin & 15;
        u16x4 v;
        #pragma unroll
        for (int e = 0; e < 4; e++) v[e] = tile[cg*4 + e][r];
        *(u16x4*)&out[(size_t)(n0 + r) * K + k0 + cg*4] = v;
    }
}

// ---------- 8-phase 256x256 MFMA GEMM (T2-swizzled LDS, plain barriers) ----------
// Stage ledger (round-12 proven): p1: Ah1(t+1); p3: Bh0(t+2); p4: Bh1(t+2)+Ah0(t+2).
// KSPLIT: grid = 2*ntiles; kidx selects K-half; writes bf16 plane Cg2 + kidx*M*ldc.
// Block map: XCD swizzle (m204) then 8x8 supertile (each XCD's 64 contiguous wgids
// cover an 8x8 tile region -> B K-slices shared by 4-8 concurrent blocks per XCD).
template<typename TC, bool KSPLIT>
__global__ __launch_bounds__(512, 1)
void gemm_8ph(const u16* __restrict__ Ag, const u16* __restrict__ Btg,
              TC* __restrict__ Cg, u16* __restrict__ Cg2,
              int M, int N, int Kext, int ldk, int ldc)
{
    __shared__ u16 smA[2][2][8192];   // [dbuf][half][128*64]
    __shared__ u16 smB[2][2][8192];
    const int tid = threadIdx.x;
    const int lane = tid & 63, w = tid >> 6;
    const int wm = w >> 2, wn = w & 3;
    const int lr = lane & 15, kh = lane >> 4;
    const int swz = (lr & 7) << 3;

    int orig = blockIdx.x;
    int ntile = gridDim.x;
    int kidx = 0;
    if constexpr (KSPLIT) { kidx = orig & 1; orig >>= 1; ntile >>= 1; }

    const int nbx = N >> 8;
    const int nby = ntile / nbx;
    const int qq = ntile >> 3, r8 = ntile & 7;
    const int xcd = orig & 7, loc = orig >> 3;
    const int wgid = (xcd < r8 ? xcd*(qq+1) : r8*(qq+1) + (xcd-r8)*qq) + loc;

    int mt, nt;
    if (((nbx & 7) | (nby & 7)) == 0 && (ntile & 63) == 0) {   // 8x8 supertile map
        int scols = nbx >> 3;
        int sg = wgid >> 6, sloc = wgid & 63;
        int sr = sg / scols, sc = sg - sr * scols;
        mt = sr * 8 + (sloc >> 3);
        nt = sc * 8 + (sloc & 7);
    } else {
        mt = wgid / nbx; nt = wgid % nbx;
    }
    const int m0 = mt * 256;
    const int n0 = nt * 256;

    if constexpr (KSPLIT) {
        Ag  += (size_t)kidx * Kext;
        Btg += (size_t)kidx * Kext;
        Cg2 += (size_t)kidx * M * ldc;
    }
    const int NT = Kext >> 6;

    f32x4 acc[8][4];
    #pragma unroll
    for (int i = 0; i < 8; i++)
        #pragma unroll
        for (int j = 0; j < 4; j++) acc[i][j] = (f32x4){0.f,0.f,0.f,0.f};

    stage_half(&Ag [(size_t)(m0      ) * ldk      ], ldk, &smA[0][0][0], w, lane);
    stage_half(&Ag [(size_t)(m0 + 128) * ldk      ], ldk, &smA[0][1][0], w, lane);
    stage_half(&Btg[(size_t)(n0      ) * ldk      ], ldk, &smB[0][0][0], w, lane);
    stage_half(&Btg[(size_t)(n0 + 128) * ldk      ], ldk, &smB[0][1][0], w, lane);
    stage_half(&Ag [(size_t)(m0      ) * ldk + 64 ], ldk, &smA[1][0][0], w, lane);
    stage_half(&Btg[(size_t)(n0      ) * ldk + 64 ], ldk, &smB[1][0][0], w, lane);
    stage_half(&Btg[(size_t)(n0 + 128) * ldk + 64 ], ldk, &smB[1][1][0], w, lane);
    VMCNT(6);
    __builtin_amdgcn_s_barrier();

    for (int t = 0; t < NT; ++t) {
        const int d = t & 1;
        const u16* As = &smA[d][wm][0];
        const u16* Bs = &smB[d][wn >> 1][0];
        const int rb = (wn & 1) * 64;

        bf16x8 aF[4][2], bLo[2][2], bHi[2][2];

        // ---- phase 1: read A-lo + B-lo; stage Ah1(t+1)
        #pragma unroll
        for (int i = 0; i < 4; i++)
            #pragma unroll
            for (int ks = 0; ks < 2; ks++)
                aF[i][ks] = *(const bf16x8*)&As[(i*16 + lr)*64 + ((ks*32 + kh*8) ^ swz)];
        #pragma unroll
        for (int j = 0; j < 2; j++)
            #pragma unroll
            for (int ks = 0; ks < 2; ks++)
                bLo[j][ks] = *(const bf16x8*)&Bs[(rb + j*16 + lr)*64 + ((ks*32 + kh*8) ^ swz)];
        if (t + 1 < NT)
            stage_half(&Ag[(size_t)(m0 + 128) * ldk + (t+1)*64], ldk, &smA[d^1][1][0], w, lane);
        __builtin_amdgcn_s_barrier();
        __builtin_amdgcn_s_setprio(1);
        #pragma unroll
        for (int i = 0; i < 4; i++)
            #pragma unroll
            for (int j = 0; j < 2; j++)
                #pragma unroll
                for (int ks = 0; ks < 2; ks++)
                    acc[i][j] = __builtin_amdgcn_mfma_f32_16x16x32_bf16(aF[i][ks], bLo[j][ks], acc[i][j], 0, 0, 0);
        __builtin_amdgcn_s_setprio(0);
        __builtin_amdgcn_s_barrier();

        // ---- phase 2: read B-hi
        #pragma unroll
        for (int j = 0; j < 2; j++)
            #pragma unroll
            for (int ks = 0; ks < 2; ks++)
                bHi[j][ks] = *(const bf16x8*)&Bs[(rb + (2+j)*16 + lr)*64 + ((ks*32 + kh*8) ^ swz)];
        __builtin_amdgcn_s_barrier();
        __builtin_amdgcn_s_setprio(1);
        #pragma unroll
        for (int i = 0; i < 4; i++)
            #pragma unroll
            for (int j = 0; j < 2; j++)
                #pragma unroll
                for (int ks = 0; ks < 2; ks++)
                    acc[i][2+j] = __builtin_amdgcn_mfma_f32_16x16x32_bf16(aF[i][ks], bHi[j][ks], acc[i][2+j], 0, 0, 0);
        __builtin_amdgcn_s_setprio(0);
        __builtin_amdgcn_s_barrier();

        // ---- phase 3: read A-hi (overwrites aF); stage Bh0(t+2)
        #pragma unroll
        for (int i = 0; i < 4; i++)
            #pragma unroll
            for (int ks = 0; ks < 2; ks++)
                aF[i][ks] = *(const bf16x8*)&As[(64 + i*16 + lr)*64 + ((ks*32 + kh*8) ^ swz)];
        if (t + 2 < NT)
            stage_half(&Btg[(size_t)(n0) * ldk + (t+2)*64], ldk, &smB[d][0][0], w, lane);
        __builtin_amdgcn_s_barrier();
        __builtin_amdgcn_s_setprio(1);
        #pragma unroll
        for (int i = 0; i < 4; i++)
            #pragma unroll
            for (int j = 0; j < 2; j++)
                #pragma unroll
                for (int ks = 0; ks < 2; ks++)
                    acc[4+i][j] = __builtin_amdgcn_mfma_f32_16x16x32_bf16(aF[i][ks], bLo[j][ks], acc[4+i][j], 0, 0, 0);
        __builtin_amdgcn_s_setprio(0);
        __builtin_amdgcn_s_barrier();

        // ---- phase 4: stage Bh1(t+2)+Ah0(t+2); MFMA; counted vmcnt after
        if (t + 2 < NT) {
            stage_half(&Btg[(size_t)(n0 + 128) * ldk + (t+2)*64], ldk, &smB[d][1][0], w, lane);
            stage_half(&Ag [(size_t)(m0      ) * ldk + (t+2)*64], ldk, &smA[d][0][0], w, lane);
        }
        __builtin_amdgcn_s_barrier();
        __builtin_amdgcn_s_setprio(1);
        #pragma unroll
        for (int i = 0; i < 4; i++)
            #pragma unroll
            for (int j = 0; j < 2; j++)
                #pragma unroll
                for (int ks = 0; ks < 2; ks++)
                    acc[4+i][2+j] = __builtin_amdgcn_mfma_f32_16x16x32_bf16(aF[i][ks], bHi[j][ks], acc[4+i][2+j], 0, 0, 0);
        __builtin_amdgcn_s_setprio(0);
        if (t < NT - 2)       { VMCNT(6); }
        else if (t == NT - 2) { VMCNT(0); }
        __builtin_amdgcn_s_barrier();
    }

    #pragma unroll
    for (int mf = 0; mf < 8; mf++) {
        #pragma unroll
        for (int nf = 0; nf < 4; nf++) {
            int r = m0 + wm*128 + mf*16 + kh*4;
            int cidx = n0 + wn*64 + nf*16 + lr;
            #pragma unroll
            for (int q = 0; q < 4; q++) {
                if constexpr (KSPLIT) {
                    Cg2[(size_t)(r+q)*ldc + cidx] = f2us(acc[mf][nf][q]);
                } else if constexpr (sizeof(TC) == 4) {
                    Cg[(size_t)(r+q)*ldc + cidx] = acc[mf][nf][q];
                } else {
                    Cg[(size_t)(r+q)*ldc + cidx] = f2us(acc[mf][nf][q]);
                }
            }
        }
    }
}

// ---------- GEMM1 tail: N=512, K-split-4, 2-phase 128x128, f32 partials ----------
__global__ __launch_bounds__(256)
void gemm_tail_ks4(const u16* __restrict__ A, const u16* __restrict__ Bt,
                   float* __restrict__ Cp, int M, int ldk)
{
    __shared__ u16 Asm[128][32];
    __shared__ u16 Bsm[128][32];
    const int t = threadIdx.x;
    const int lane = t & 63, w = t >> 6;
    const int wr = w >> 1, wc = w & 1;
    const int lr = lane & 15, kh = lane >> 4;

    const int bid = blockIdx.x;
    const int kidx = bid & 3, tile = bid >> 2;
    const int m0 = (tile >> 2) * 128;
    const int n0 = (tile & 3) * 128;

    const u16* Ak = A  + kidx * 512;
    const u16* Bk = Bt + kidx * 512;
    float* C = Cp + (size_t)kidx * TSTRIDE;

    f32x4 acc[4][4];
    #pragma unroll
    for (int i = 0; i < 4; i++)
        #pragma unroll
        for (int j = 0; j < 4; j++) acc[i][j] = (f32x4){0.f,0.f,0.f,0.f};

    for (int k0 = 0; k0 < 512; k0 += 32) {
        #pragma unroll
        for (int i = 0; i < 2; i++) {
            int cb = i * 256 + w * 64;
            int chunk = cb + lane;
            int row = chunk >> 2, kb = chunk & 3;
            gload_lds16(&Ak[(size_t)(m0 + row) * ldk + k0 + kb * 8], &Asm[0][0] + cb * 8);
            gload_lds16(&Bk[(size_t)(n0 + row) * ldk + k0 + kb * 8], &Bsm[0][0] + cb * 8);
        }
        __syncthreads();
        bf16x8 af[4], bf[4];
        #pragma unroll
        for (int i = 0; i < 4; i++)
            af[i] = *(const bf16x8*)&Asm[wr*64 + i*16 + lr][kh*8];
        #pragma unroll
        for (int j = 0; j < 4; j++)
            bf[j] = *(const bf16x8*)&Bsm[wc*64 + j*16 + lr][kh*8];
        #pragma unroll
        for (int i = 0; i < 4; i++)
            #pragma unroll
            for (int j = 0; j < 4; j++)
                acc[i][j] = __builtin_amdgcn_mfma_f32_16x16x32_bf16(af[i], bf[j], acc[i][j], 0, 0, 0);
        __syncthreads();
    }
    #pragma unroll
    for (int i = 0; i < 4; i++) {
        #pragma unroll
        for (int j = 0; j < 4; j++) {
            int r = m0 + wr*64 + i*16 + kh*4;
            int cidx = n0 + wc*64 + j*16 + lr;
            #pragma unroll
            for (int q = 0; q < 4; q++)
                C[(size_t)(r+q)*512 + cidx] = acc[i][j][q];
        }
    }
}

// ---------------- conv1d + bias + SiLU; B/C channels read 4 tail partials directly ----------------
__global__ __launch_bounds__(256)
void conv_silu(const u16* __restrict__ zx, const float* __restrict__ tailp,
               const float* __restrict__ cw, const float* __restrict__ cb,
               u16* __restrict__ xconv, u16* __restrict__ Bbuf, u16* __restrict__ Cbuf)
{
    int idx = blockIdx.x * 256 + threadIdx.x;
    int cg = idx % (CONV_DIM / 8);
    int r  = idx / (CONV_DIM / 8);
    int c0 = cg * 8;
    int l  = r & (SEQ - 1);

    float y[8];
    {
        float4 b0 = *(const float4*)&cb[c0];
        float4 b1 = *(const float4*)&cb[c0 + 4];
        y[0]=b0.x; y[1]=b0.y; y[2]=b0.z; y[3]=b0.w;
        y[4]=b1.x; y[5]=b1.y; y[6]=b1.z; y[7]=b1.w;
    }
    float cwf[8][4];
    #pragma unroll
    for (int e = 0; e < 8; e++) {
        float4 v = *(const float4*)&cw[(c0 + e) * 4];
        cwf[e][0]=v.x; cwf[e][1]=v.y; cwf[e][2]=v.z; cwf[e][3]=v.w;
    }
    if (c0 < D_INNER) {                      // x channels: zx cols [4096, 8192)
        #pragma unroll
        for (int k = 0; k < 4; k++) {
            if (l + k - 3 >= 0) {
                u16x8 v = *(const u16x8*)&zx[(size_t)(r + k - 3) * LD_ZX + D_INNER + c0];
                #pragma unroll
                for (int e = 0; e < 8; e++) y[e] += us2f(v[e]) * cwf[e][k];
            }
        }
    } else {                                 // B/C channels: sum 4 tail partials
        int tc = c0 - D_INNER;
        #pragma unroll
        for (int k = 0; k < 4; k++) {
            if (l + k - 3 >= 0) {
                const float* tb = &tailp[(size_t)(r + k - 3) * 512 + tc];
                #pragma unroll
                for (int e = 0; e < 8; e++) {
                    float s = tb[e] + tb[TSTRIDE + e] + tb[2*TSTRIDE + e] + tb[3*TSTRIDE + e];
                    y[e] += s * cwf[e][k];
                }
            }
        }
    }
    u16x8 o;
    #pragma unroll
    for (int e = 0; e < 8; e++) {
        float s = y[e] / (1.f + expf(-y[e]));
        o[e] = f2us(s);
    }
    if (c0 < D_INNER)                *(u16x8*)&xconv[(size_t)r * D_INNER + c0] = o;
    else if (c0 < D_INNER + D_STATE) *(u16x8*)&Bbuf[(size_t)r * D_STATE + (c0 - D_INNER)] = o;
    else                             *(u16x8*)&Cbuf[(size_t)r * D_STATE + (c0 - D_INNER - D_STATE)] = o;
}

// ---------------- dt softplus + per-chunk cumsum (dt from tail partials) ----------------
__global__ __launch_bounds__(256)
void dt_acs(const float* __restrict__ tailp, const float* __restrict__ Aparam,
            const float* __restrict__ dt_bias, float* __restrict__ dtT,
            float* __restrict__ Acs)
{
    __shared__ float sb[CHUNK];
    int blk = blockIdx.x;
    int c = blk & 7, h = (blk >> 3) & 63, b = blk >> 9;
    int t = threadIdx.x;
    int lg = c * CHUNK + t;
    int row = b * SEQ + lg;
    const float* tb = &tailp[(size_t)row * 512 + 256 + h];
    float x = tb[0] + tb[TSTRIDE] + tb[2*TSTRIDE] + tb[3*TSTRIDE];
    x += dt_bias[h];
    float dt = (x > 20.f) ? x : log1pf(expf(x));
    float v = dt * Aparam[h];
    sb[t] = v; __syncthreads();
    #pragma unroll
    for (int off = 1; off < 256; off <<= 1) {
        float add = (t >= off) ? sb[t - off] : 0.f;
        __syncthreads();
        v += add; sb[t] = v;
        __syncthreads();
    }
    int o = (b * NHEADS + h) * SEQ + lg;
    dtT[o] = dt;
    Acs[o] = v;
}

// ---------------- S precompute: S[bc][l][s] = C_l . B_s (head-shared, lower-tri tiles) ----------------
__global__ __launch_bounds__(256)
void s_precompute(const u16* __restrict__ Bbuf, const u16* __restrict__ Cbuf,
                  u16* __restrict__ Sbuf)
{
    int p = blockIdx.x % 10, bc = blockIdx.x / 10;
    int q = (p >= 6) ? 3 : (p >= 3) ? 2 : (p >= 1) ? 1 : 0;
    int st = p - q * (q + 1) / 2;
    int b = bc >> 3, c = bc & 7;
    const int lane = threadIdx.x & 63, w = threadIdx.x >> 6;
    const int lr = lane & 15, kh = lane >> 4;
    const size_t rowbase = (size_t)(b * SEQ + c * CHUNK);

    f32x4 sacc[4];
    #pragma unroll
    for (int i = 0; i < 4; i++) sacc[i] = (f32x4){0.f,0.f,0.f,0.f};
    #pragma unroll
    for (int kk = 0; kk < 4; kk++) {
        bf16x8 bA = *(const bf16x8*)&Bbuf[(rowbase + st*64 + w*16 + lr) * D_STATE + kk*32 + kh*8];
        #pragma unroll
        for (int i = 0; i < 4; i++) {
            bf16x8 af = *(const bf16x8*)&Cbuf[(rowbase + q*64 + i*16 + lr) * D_STATE + kk*32 + kh*8];
            sacc[i] = __builtin_amdgcn_mfma_f32_16x16x32_bf16(bA, af, sacc[i], 0, 0, 0);
        }
    }
    u16* Sb = Sbuf + (size_t)bc * 256 * 256;
    #pragma unroll
    for (int i = 0; i < 4; i++) {
        u16x4 o;
        #pragma unroll
        for (int qq = 0; qq < 4; qq++) o[qq] = f2us(sacc[i][qq]);
        *(u16x4*)&Sb[(size_t)(q*64 + i*16 + lr) * 256 + st*64 + w*16 + kh*4] = o;
    }
}

// ---------------- per-chunk states via MFMA, bf16 out, swapped operands ----------------
__global__ __launch_bounds__(256)
void chunk_states_mfma(const u16* __restrict__ xconv, const u16* __restrict__ Bbuf,
                       const float* __restrict__ dtT, const float* __restrict__ Acs,
                       u16* __restrict__ states)
{
    __shared__ u16 Btsh[128][72];   // B^T [n][l]
    __shared__ u16 xtsh[64][72];    // (w*x)^T [p][l]
    __shared__ float acs_sh[CHUNK];
    __shared__ float dt_sh[CHUNK];

    const int blk = blockIdx.x;
    const int h = blk & 63, c = (blk >> 6) & 7, b = blk >> 9;
    const int t = threadIdx.x;
    const int lane = t & 63, w = t >> 6;
    const int wr = w >> 1, wc = w & 1;
    const int lr = lane & 15, kh = lane >> 4;
    const int bh = b * NHEADS + h;
    const size_t rowbase = (size_t)(b * SEQ + c * CHUNK);

    acs_sh[t] = Acs[(size_t)bh * SEQ + c * CHUNK + t];
    dt_sh[t]  = dtT[(size_t)bh * SEQ + c * CHUNK + t];
    __syncthreads();
    const float acs_last = acs_sh[CHUNK - 1];

    f32x4 acc[4][2];   // [j = n-block][i = p-block]
    #pragma unroll
    for (int j = 0; j < 4; j++)
        #pragma unroll
        for (int i = 0; i < 2; i++) acc[j][i] = (f32x4){0.f,0.f,0.f,0.f};

    for (int lt = 0; lt < 4; lt++) {
        __syncthreads();
        const int s = t & 63;
        const int sg = lt * 64 + s;
        const float wgt = dt_sh[sg] * expf(acs_last - acs_sh[sg]);
        {
            int ng = (t >> 6) * 32;
            const u16* src = &Bbuf[(rowbase + sg) * D_STATE + ng];
            #pragma unroll
            for (int q = 0; q < 4; q++) {
                u16x8 v = *(const u16x8*)&src[q * 8];
                #pragma unroll
                for (int e = 0; e < 8; e++)
                    Btsh[ng + q*8 + e][s] = v[e];
            }
        }
        {
            int pg = (t >> 6) * 16;
            const u16* src = &xconv[(rowbase + sg) * D_INNER + h * HEAD_DIM + pg];
            u16x8 v0 = *(const u16x8*)&src[0];
            u16x8 v1 = *(const u16x8*)&src[8];
            #pragma unroll
            for (int e = 0; e < 8; e++) {
                xtsh[pg + e][s]     = f2us(us2f(v0[e]) * wgt);
                xtsh[pg + 8 + e][s] = f2us(us2f(v1[e]) * wgt);
            }
        }
        __syncthreads();
        #pragma unroll
        for (int kk = 0; kk < 2; kk++) {
            bf16x8 xf[2], bf[4];
            #pragma unroll
            for (int i = 0; i < 2; i++)
                xf[i] = *(const bf16x8*)&xtsh[wr*32 + i*16 + lr][kk*32 + kh*8];
            #pragma unroll
            for (int j = 0; j < 4; j++)
                bf[j] = *(const bf16x8*)&Btsh[wc*64 + j*16 + lr][kk*32 + kh*8];
            #pragma unroll
            for (int j = 0; j < 4; j++)
                #pragma unroll
                for (int i = 0; i < 2; i++)
                    acc[j][i] = __builtin_amdgcn_mfma_f32_16x16x32_bf16(bf[j], xf[i], acc[j][i], 0, 0, 0);
        }
    }
    size_t base = ((size_t)((b*NCHUNK + c)*NHEADS + h)) * (HEAD_DIM * D_STATE);
    #pragma unroll
    for (int j = 0; j < 4; j++) {
        #pragma unroll
        for (int i = 0; i < 2; i++) {
            int p = wr*32 + i*16 + lr;
            int n = wc*64 + j*16 + kh*4;
            u16x4 o;
            #pragma unroll
            for (int q = 0; q < 4; q++) o[q] = f2us(acc[j][i][q]);
            *(u16x4*)&states[base + (size_t)p * D_STATE + n] = o;
        }
    }
}

// ---------------- inter-chunk recurrence, bf16 states ----------------
__global__ __launch_bounds__(256)
void state_recurrence(u16* __restrict__ states, const float* __restrict__ Acs)
{
    int idx = blockIdx.x * 256 + threadIdx.x;
    int n8 = idx & 15;
    int p  = (idx >> 4) & 63;
    int bh = idx >> 10;
    int b = bh >> 6, h = bh & 63;
    float E[8];
    #pragma unroll
    for (int e = 0; e < 8; e++) E[e] = 0.f;
    for (int c = 0; c < NCHUNK; c++) {
        size_t off = ((size_t)((b*NCHUNK + c)*NHEADS + h)) * 8192 + (size_t)p * 128 + n8 * 8;
        u16x8 sv = *(const u16x8*)&states[off];
        u16x8 ev;
        #pragma unroll
        for (int e = 0; e < 8; e++) ev[e] = f2us(E[e]);
        *(u16x8*)&states[off] = ev;
        float g = expf(Acs[(size_t)(b*NHEADS + h) * SEQ + c*CHUNK + 255]);
        #pragma unroll
        for (int e = 0; e < 8; e++) E[e] = g * E[e] + us2f(sv[e]);
    }
}

// ---------------- chunk output: Y_off-first; S read from precomputed head-shared Sbuf ----------------
__global__ __launch_bounds__(256, 1)
void chunk_output_mfma(const u16* __restrict__ xconv, const u16* __restrict__ Sbuf,
                       const u16* __restrict__ Cbuf, const float* __restrict__ dtT,
                       const float* __restrict__ Acs, const u16* __restrict__ states,
                       const float* __restrict__ Dparam, u16* __restrict__ Y)
{
    __shared__ u16 Bsm[64][136];       // prev [p][n] only
    __shared__ u16 xt[64][72];         // x^T tile [p][s]
    __shared__ u16 Pt[4][64][72];      // per-wave P [l][s]
    __shared__ float acs_sh[CHUNK];
    __shared__ float dt_sh[CHUNK];

    const int blk = blockIdx.x;
    const int h = blk & 63, c = (blk >> 6) & 7, b = blk >> 9;
    const int t = threadIdx.x;
    const int lane = t & 63, w = t >> 6;
    const int lr = lane & 15, kh = lane >> 4;
    const int bh = b * NHEADS + h;
    const size_t rowbase = (size_t)(b * SEQ + c * CHUNK);
    const u16* Sblk = Sbuf + (size_t)(b * NCHUNK + c) * 256 * 256;

    acs_sh[t] = Acs[(size_t)bh * SEQ + c * CHUNK + t];
    dt_sh[t]  = dtT[(size_t)bh * SEQ + c * CHUNK + t];

    bf16x8 af[4][4];
    #pragma unroll
    for (int i = 0; i < 4; i++)
        #pragma unroll
        for (int kk = 0; kk < 4; kk++)
            af[i][kk] = *(const bf16x8*)&Cbuf[(rowbase + w*64 + i*16 + lr) * D_STATE + kk*32 + kh*8];

    {   // stage prev into Bsm [p][n]
        int p = t >> 2, ng = (t & 3) * 32;
        const u16* src = &states[((size_t)((b*NCHUNK + c)*NHEADS + h)) * 8192 + (size_t)p * 128 + ng];
        #pragma unroll
        for (int q = 0; q < 4; q++)
            *(u16x8*)&Bsm[p][ng + q*8] = *(const u16x8*)&src[q*8];
    }
    __syncthreads();
    float acs_l[4], el[4];
    #pragma unroll
    for (int i = 0; i < 4; i++) { acs_l[i] = acs_sh[w*64 + i*16 + lr]; el[i] = expf(acs_l[i]); }

    // Y_off raw: yacc[j][i] = prev . C (unscaled), then scale by el[i]
    f32x4 yacc[4][4];
    #pragma unroll
    for (int j = 0; j < 4; j++)
        #pragma unroll
        for (int i = 0; i < 4; i++) yacc[j][i] = (f32x4){0.f,0.f,0.f,0.f};
    #pragma unroll
    for (int kk = 0; kk < 4; kk++) {
        bf16x8 pvA[4];
        #pragma unroll
        for (int j = 0; j < 4; j++)
            pvA[j] = *(const bf16x8*)&Bsm[j*16 + lr][kk*32 + kh*8];
        #pragma unroll
        for (int j = 0; j < 4; j++)
            #pragma unroll
            for (int i = 0; i < 4; i++)
                yacc[j][i] = __builtin_amdgcn_mfma_f32_16x16x32_bf16(pvA[j], af[i][kk], yacc[j][i], 0, 0, 0);
    }
    #pragma unroll
    for (int j = 0; j < 4; j++)
        #pragma unroll
        for (int i = 0; i < 4; i++)
            #pragma unroll
            for (int q = 0; q < 4; q++)
                yacc[j][i][q] *= el[i];

    for (int st = 0; st < 4; st++) {
        __syncthreads();
        {   // stage x^T tile [p][s]
            int s = t & 63, pg = t >> 6;
            const u16* src = &xconv[(rowbase + st*64 + s) * D_INNER + h*HEAD_DIM + pg*16];
            u16x8 v0 = *(const u16x8*)&src[0];
            u16x8 v1 = *(const u16x8*)&src[8];
            #pragma unroll
            for (int q = 0; q < 8; q++) { xt[pg*16 + q][s] = v0[q]; xt[pg*16 + 8 + q][s] = v1[q]; }
        }
        __syncthreads();
        if (st > w) continue;

        // P = mask(S) * dt, S loaded from head-shared Sbuf
        #pragma unroll
        for (int js = 0; js < 4; js++) {
            int s0 = st*64 + js*16;
            float as0 = acs_sh[s0];
            int sgq = s0 + kh*4;
            float eneg[4];
            #pragma unroll
            for (int q = 0; q < 4; q++)
                eneg[q] = expf(fminf(as0 - acs_sh[sgq + q], 60.f)) * dt_sh[sgq + q];
            #pragma unroll
            for (int i = 0; i < 4; i++) {
                int ll = w*64 + i*16 + lr;
                float eladj = expf(acs_l[i] - as0);
                u16x4 sv = *(const u16x4*)&Sblk[(size_t)ll * 256 + sgq];
                u16x4 pv;
                #pragma unroll
                for (int q = 0; q < 4; q++) {
                    float fac = (sgq + q <= ll) ? eladj * eneg[q] : 0.f;
                    pv[q] = f2us(us2f(sv[q]) * fac);
                }
                *(u16x4*)&Pt[w][i*16 + lr][js*16 + kh*4] = pv;
            }
        }
        #pragma unroll
        for (int kk2 = 0; kk2 < 2; kk2++) {
            bf16x8 xA[4], pB[4];
            #pragma unroll
            for (int j = 0; j < 4; j++)
                xA[j] = *(const bf16x8*)&xt[j*16 + lr][kk2*32 + kh*8];
            #pragma unroll
            for (int i = 0; i < 4; i++)
                pB[i] = *(const bf16x8*)&Pt[w][i*16 + lr][kk2*32 + kh*8];
            #pragma unroll
            for (int j = 0; j < 4; j++)
                #pragma unroll
                for (int i = 0; i < 4; i++)
                    yacc[j][i] = __builtin_amdgcn_mfma_f32_16x16x32_bf16(xA[j], pB[i], yacc[j][i], 0, 0, 0);
        }
    }

    float Dh = Dparam[h];
    #pragma unroll
    for (int i = 0; i < 4; i++) {
        #pragma unroll
        for (int j = 0; j < 4; j++) {
            size_t o = (rowbase + w*64 + i*16 + lr) * D_INNER + h*HEAD_DIM + j*16 + kh*4;
            u16x4 xv = *(const u16x4*)&xconv[o];
            u16x4 ov;
            #pragma unroll
            for (int q = 0; q < 4; q++)
                ov[q] = f2us(yacc[j][i][q] + Dh * us2f(xv[q]));
            *(u16x4*)&Y[o] = ov;
        }
    }
}

// ---------------- gated RMSNorm (register-resident, no LDS xs[]) ----------------
__global__ __launch_bounds__(256)
void gated_rmsnorm_k(u16* __restrict__ Y, const u16* __restrict__ zx,
                     const float* __restrict__ nw)
{
    __shared__ float red[4];
    int row = blockIdx.x;
    int t = threadIdx.x;
    float x[16];
    float ss = 0.f;
    #pragma unroll
    for (int g = 0; g < 2; g++) {
        int i = g * 2048 + t * 8;
        u16x8 yv = *(const u16x8*)&Y[(size_t)row * D_INNER + i];
        u16x8 zv = *(const u16x8*)&zx[(size_t)row * LD_ZX + i];
        #pragma unroll
        for (int q = 0; q < 8; q++) {
            float xv = us2f(yv[q]) * siluf(us2f(zv[q]));
            x[g*8 + q] = xv;
            ss += xv * xv;
        }
    }
    #pragma unroll
    for (int off = 32; off > 0; off >>= 1) ss += __shfl_down(ss, off);
    int wid = t >> 6, lane = t & 63;
    if (lane == 0) red[wid] = ss;
    __syncthreads();
    float tot = red[0] + red[1] + red[2] + red[3];
    float sc = rsqrtf(tot / (float)D_INNER + EPS_RMS);
    #pragma unroll
    for (int g = 0; g < 2; g++) {
        int i = g * 2048 + t * 8;
        float4 w0 = *(const float4*)&nw[i];
        float4 w1 = *(const float4*)&nw[i + 4];
        float wv[8] = {w0.x, w0.y, w0.z, w0.w, w1.x, w1.y, w1.z, w1.w};
        u16x8 o;
        #pragma unroll
        for (int q = 0; q < 8; q++) o[q] = f2us(x[g*8 + q] * sc * wv[q]);
        *(u16x8*)&Y[(size_t)row * D_INNER + i] = o;
    }
}

__global__ void ws_fail_k(float* out, float mb){ out[threadIdx.x] = mb; }

// ---------------- launch ----------------
extern "C" void kernel_launch(void* const* d_in, const int* in_sizes, int n_in,
                              void* d_out, int out_size, void* d_ws, size_t ws_size,
                              hipStream_t stream)
{
    const float* hidden  = (const float*)d_in[0];
    const float* W_in    = (const float*)d_in[1];
    const float* conv_w  = (const float*)d_in[2];
    const float* conv_b  = (const float*)d_in[3];
    const float* Aparam  = (const float*)d_in[4];
    const float* Dparam  = (const float*)d_in[5];
    const float* dt_bias = (const float*)d_in[6];
    const float* norm_w  = (const float*)d_in[7];
    const float* W_out   = (const float*)d_in[8];
    float* out = (float*)d_out;

    const int M = BATCH * SEQ;  // 4096

    size_t off = 0;
    char* wsb = (char*)d_ws;
    u16*   zx     = (u16*)  (wsb + off); off += (size_t)M * LD_ZX * 2;
    u16*   xconv  = (u16*)  (wsb + off); off += (size_t)M * D_INNER * 2;
    u16*   Bbuf   = (u16*)  (wsb + off); off += (size_t)M * D_STATE * 2;
    u16*   Cbuf   = (u16*)  (wsb + off); off += (size_t)M * D_STATE * 2;
    float* dtT    = (float*)(wsb + off); off += (size_t)BATCH * NHEADS * SEQ * 4;
    float* Acs    = (float*)(wsb + off); off += (size_t)BATCH * NHEADS * SEQ * 4;
    u16*   states = (u16*)  (wsb + off); off += (size_t)BATCH * NCHUNK * NHEADS * HEAD_DIM * D_STATE * 2;
    u16*   Ybuf   = (u16*)  (wsb + off); off += (size_t)M * D_INNER * 2;
    u16*   hbf    = (u16*)  (wsb + off); off += (size_t)M * D_MODEL * 2;
    u16*   WtIn   = (u16*)  (wsb + off); off += (size_t)LD_ZX * D_MODEL * 2;
    u16*   WtOut  = (u16*)  (wsb + off); off += (size_t)D_MODEL * D_INNER * 2;
    float* tailp  = (float*)(wsb + off); off += 4 * TSTRIDE * 4;            // 33.5 MB
    u16*   Sbuf   = (u16*)  (wsb + off); off += (size_t)16 * 256 * 256 * 2; // 2 MB
    u16*   tmpf   = (u16*)zx;   // GEMM2 bf16 planes alias zx (dead after gated_rmsnorm)

    if (off > ws_size) {
        ws_fail_k<<<1, 64, 0, stream>>>(out, (float)(ws_size >> 20));
        return;
    }

    cvt_bf16<<<(M * D_MODEL / 4 + 255) / 256, 256, 0, stream>>>(hidden, hbf, M * D_MODEL / 4);
    transpose_cvt<<<dim3(D_MODEL/64, LD_ZX/64), 256, 0, stream>>>(W_in, WtIn, D_MODEL, D_IN_PROJ);
    transpose_cvt<<<dim3(D_INNER/64, D_MODEL/64), 256, 0, stream>>>(W_out, WtOut, D_INNER, D_MODEL);

    // GEMM1 main: zx[:, 0:8192] — 512 blocks = exactly 2 CU-rounds, 8x8 supertiled
    gemm_8ph<u16, false><<<(8192/256) * (M/256), 512, 0, stream>>>(
        hbf, WtIn, zx, nullptr, M, 8192, D_MODEL, D_MODEL, LD_ZX);
    // GEMM1 tail: cols [8192:8704] — K-split-4 f32 partials, consumed by conv/dt directly
    gemm_tail_ks4<<<512, 256, 0, stream>>>(hbf, WtIn + (size_t)8192 * D_MODEL, tailp, M, D_MODEL);

    conv_silu<<<(M * CONV_DIM / 8) / 256, 256, 0, stream>>>(zx, tailp, conv_w, conv_b, xconv, Bbuf, Cbuf);
    s_precompute<<<160, 256, 0, stream>>>(Bbuf, Cbuf, Sbuf);
    dt_acs<<<BATCH * NHEADS * NCHUNK, 256, 0, stream>>>(tailp, Aparam, dt_bias, dtT, Acs);
    chunk_states_mfma<<<BATCH * NCHUNK * NHEADS, 256, 0, stream>>>(xconv, Bbuf, dtT, Acs, states);
    state_recurrence<<<(BATCH * NHEADS * 64 * 16) / 256, 256, 0, stream>>>(states, Acs);
    chunk_output_mfma<<<BATCH * NCHUNK * NHEADS, 256, 0, stream>>>(xconv, Sbuf, Cbuf, dtT, Acs, states, Dparam, Ybuf);
    gated_rmsnorm_k<<<M, 256, 0, stream>>>(Ybuf, zx, norm_w);   // last reader of zx

    // GEMM2 K-split-2: 256 blocks = 1 CU-round; both halves bf16; out = t0 + t1
    gemm_8ph<float, true><<<2 * (D_MODEL/256) * (M/256), 512, 0, stream>>>(
        Ybuf, WtOut, out, tmpf, M, D_MODEL, D_INNER/2, D_INNER, D_MODEL);
    add2_bf16<<<(M * D_MODEL / 8 + 255) / 256, 256, 0, stream>>>(
        out, tmpf, tmpf + (size_t)M * D_MODEL, M * D_MODEL / 8);
}

// Round 20
// 443.596 us; speedup vs baseline: 1.0650x; 1.0143x over previous
//
#include <hip/hip_runtime.h>
#include <hip/hip_bf16.h>
#include <math.h>

#define D_MODEL   2048
#define D_INNER   4096
#define NHEADS    64
#define HEAD_DIM  64
#define D_STATE   128
#define CHUNK     256
#define CONV_DIM  (D_INNER + 2*D_STATE)            // 4352
#define D_IN_PROJ (2*D_INNER + 2*D_STATE + NHEADS) // 8512
#define LD_ZX     8704                             // D_IN_PROJ padded to 256
#define BATCH     2
#define SEQ       2048
#define NCHUNK    (SEQ/CHUNK)                      // 8
#define EPS_RMS   1e-5f
#define MROWS     4096
#define TSTRIDE   ((size_t)MROWS * 512)            // tail-partial plane stride (f32 elems)

typedef unsigned short u16;
typedef __attribute__((ext_vector_type(8))) unsigned short u16x8;
typedef __attribute__((ext_vector_type(4))) unsigned short u16x4;
typedef __attribute__((ext_vector_type(8))) short bf16x8;   // MFMA A/B frag (8 bf16)
typedef __attribute__((ext_vector_type(4))) float f32x4;    // MFMA C/D frag

__device__ __forceinline__ float us2f(u16 u){
    union { unsigned int i; float f; } c; c.i = ((unsigned int)u) << 16; return c.f;
}
__device__ __forceinline__ u16 f2us(float f){
    union { float f; unsigned int i; } c; c.f = f;
    unsigned int r = c.i + 0x7FFFu + ((c.i >> 16) & 1u);
    return (u16)(r >> 16);
}
__device__ __forceinline__ float siluf(float x){ return x / (1.f + expf(-x)); }

__device__ __forceinline__ void gload_lds16(const void* g, void* l) {
    __builtin_amdgcn_global_load_lds((const __attribute__((address_space(1))) void*)g,
                                     (__attribute__((address_space(3))) void*)l, 16, 0, 0);
}

#define VMCNT(n) asm volatile("s_waitcnt vmcnt(" #n ")" ::: "memory")

// stage one 128x64 bf16 half-tile (row-major, stride ldk) into LDS with T2 swizzle.
__device__ __forceinline__ void stage_half(const u16* __restrict__ g, size_t ldk,
                                           u16* ldsbase, int w, int lane)
{
    #pragma unroll
    for (int cc = 0; cc < 2; cc++) {
        int cb = cc * 512 + w * 64;          // wave-uniform chunk base
        int ci = cb + lane;
        int sc = ci ^ ((ci >> 3) & 7);       // swizzled source chunk (involution)
        gload_lds16(&g[(size_t)(sc >> 3) * ldk + (sc & 7) * 8], ldsbase + cb * 8);
    }
}

// ---------- fused preprocessing: hbf cvt + W_in/W_out transpose+cvt ----------
// grid = 8192 (cvt) + 4352 (WtIn) + 2048 (WtOut)
__global__ __launch_bounds__(256)
void prep_kernel(const float* __restrict__ hidden, u16* __restrict__ hbf,
                 const float* __restrict__ W_in, u16* __restrict__ WtIn,
                 const float* __restrict__ W_out, u16* __restrict__ WtOut)
{
    __shared__ u16 tile[64][65];
    int bid = blockIdx.x;
    int t = threadIdx.x;
    if (bid < 8192) {                      // hbf = bf16(hidden), 4 f32/thread
        int i = bid * 256 + t;
        float4 v = *(const float4*)&hidden[(size_t)i * 4];
        u16x4 o; o[0]=f2us(v.x); o[1]=f2us(v.y); o[2]=f2us(v.z); o[3]=f2us(v.w);
        *(u16x4*)&hbf[(size_t)i * 4] = o;
        return;
    }
    const float* in; u16* out; int K, N, k0, n0;
    if (bid < 8192 + 4352) {               // WtIn: K=2048, N=8512 (pad to 8704)
        int b2 = bid - 8192;
        in = W_in; out = WtIn; K = D_MODEL; N = D_IN_PROJ;
        k0 = (b2 % 32) * 64; n0 = (b2 / 32) * 64;
    } else {                               // WtOut: K=4096, N=2048
        int b3 = bid - 8192 - 4352;
        in = W_out; out = WtOut; K = D_INNER; N = D_MODEL;
        k0 = (b3 % 64) * 64; n0 = (b3 / 64) * 64;
    }
    #pragma unroll
    for (int q = 0; q < 16; q++) {
        int lin = q * 256 + t;
        int r = lin >> 6, c = lin & 63;
        int n = n0 + c;
        float v = (n < N) ? in[(size_t)(k0 + r) * N + n] : 0.f;
        tile[r][c] = f2us(v);
    }
    __syncthreads();
    #pragma unroll
    for (int q = 0; q < 4; q++) {
        int lin = q * 256 + t;
        int r = lin >> 4, cg = lin & 15;
        u16x4 v;
        #pragma unroll
        for (int e = 0; e < 4; e++) v[e] = tile[cg*4 + e][r];
        *(u16x4*)&out[(size_t)(n0 + r) * K + k0 + cg*4] = v;
    }
}

// ---------- out = bf16 tmp0 + bf16 tmp1 (f32 result) ----------
__global__ __launch_bounds__(256)
void add2_bf16(float* __restrict__ out, const u16* __restrict__ t0,
               const u16* __restrict__ t1, int n8)
{
    int i = blockIdx.x * 256 + threadIdx.x;
    if (i >= n8) return;
    u16x8 a = *(const u16x8*)&t0[(size_t)i * 8];
    u16x8 b = *(const u16x8*)&t1[(size_t)i * 8];
    float* o = &out[(size_t)i * 8];
    *(float4*)&o[0] = make_float4(us2f(a[0])+us2f(b[0]), us2f(a[1])+us2f(b[1]),
                                  us2f(a[2])+us2f(b[2]), us2f(a[3])+us2f(b[3]));
    *(float4*)&o[4] = make_float4(us2f(a[4])+us2f(b[4]), us2f(a[5])+us2f(b[5]),
                                  us2f(a[6])+us2f(b[6]), us2f(a[7])+us2f(b[7]));
}

// ---------- 8-phase 256x256 MFMA GEMM (T2-swizzled LDS, plain barriers) ----------
// Stage ledger (round-12 proven): p1: Ah1(t+1); p3: Bh0(t+2); p4: Bh1(t+2)+Ah0(t+2).
// KSPLIT: grid = 2*ntiles; kidx selects K-half; writes bf16 plane Cg2 + kidx*M*ldc.
// Block map: XCD swizzle (m204) then 8x8 supertile (r19 verified: FETCH 270->98 MB).
template<typename TC, bool KSPLIT>
__global__ __launch_bounds__(512, 1)
void gemm_8ph(const u16* __restrict__ Ag, const u16* __restrict__ Btg,
              TC* __restrict__ Cg, u16* __restrict__ Cg2,
              int M, int N, int Kext, int ldk, int ldc)
{
    __shared__ u16 smA[2][2][8192];   // [dbuf][half][128*64]
    __shared__ u16 smB[2][2][8192];
    const int tid = threadIdx.x;
    const int lane = tid & 63, w = tid >> 6;
    const int wm = w >> 2, wn = w & 3;
    const int lr = lane & 15, kh = lane >> 4;
    const int swz = (lr & 7) << 3;

    int orig = blockIdx.x;
    int ntile = gridDim.x;
    int kidx = 0;
    if constexpr (KSPLIT) { kidx = orig & 1; orig >>= 1; ntile >>= 1; }

    const int nbx = N >> 8;
    const int nby = ntile / nbx;
    const int qq = ntile >> 3, r8 = ntile & 7;
    const int xcd = orig & 7, loc = orig >> 3;
    const int wgid = (xcd < r8 ? xcd*(qq+1) : r8*(qq+1) + (xcd-r8)*qq) + loc;

    int mt, nt;
    if (((nbx & 7) | (nby & 7)) == 0 && (ntile & 63) == 0) {   // 8x8 supertile map
        int scols = nbx >> 3;
        int sg = wgid >> 6, sloc = wgid & 63;
        int sr = sg / scols, sc = sg - sr * scols;
        mt = sr * 8 + (sloc >> 3);
        nt = sc * 8 + (sloc & 7);
    } else {
        mt = wgid / nbx; nt = wgid % nbx;
    }
    const int m0 = mt * 256;
    const int n0 = nt * 256;

    if constexpr (KSPLIT) {
        Ag  += (size_t)kidx * Kext;
        Btg += (size_t)kidx * Kext;
        Cg2 += (size_t)kidx * M * ldc;
    }
    const int NT = Kext >> 6;

    f32x4 acc[8][4];
    #pragma unroll
    for (int i = 0; i < 8; i++)
        #pragma unroll
        for (int j = 0; j < 4; j++) acc[i][j] = (f32x4){0.f,0.f,0.f,0.f};

    stage_half(&Ag [(size_t)(m0      ) * ldk      ], ldk, &smA[0][0][0], w, lane);
    stage_half(&Ag [(size_t)(m0 + 128) * ldk      ], ldk, &smA[0][1][0], w, lane);
    stage_half(&Btg[(size_t)(n0      ) * ldk      ], ldk, &smB[0][0][0], w, lane);
    stage_half(&Btg[(size_t)(n0 + 128) * ldk      ], ldk, &smB[0][1][0], w, lane);
    stage_half(&Ag [(size_t)(m0      ) * ldk + 64 ], ldk, &smA[1][0][0], w, lane);
    stage_half(&Btg[(size_t)(n0      ) * ldk + 64 ], ldk, &smB[1][0][0], w, lane);
    stage_half(&Btg[(size_t)(n0 + 128) * ldk + 64 ], ldk, &smB[1][1][0], w, lane);
    VMCNT(6);
    __builtin_amdgcn_s_barrier();

    for (int t = 0; t < NT; ++t) {
        const int d = t & 1;
        const u16* As = &smA[d][wm][0];
        const u16* Bs = &smB[d][wn >> 1][0];
        const int rb = (wn & 1) * 64;

        bf16x8 aF[4][2], bLo[2][2], bHi[2][2];

        // ---- phase 1: read A-lo + B-lo; stage Ah1(t+1)
        #pragma unroll
        for (int i = 0; i < 4; i++)
            #pragma unroll
            for (int ks = 0; ks < 2; ks++)
                aF[i][ks] = *(const bf16x8*)&As[(i*16 + lr)*64 + ((ks*32 + kh*8) ^ swz)];
        #pragma unroll
        for (int j = 0; j < 2; j++)
            #pragma unroll
            for (int ks = 0; ks < 2; ks++)
                bLo[j][ks] = *(const bf16x8*)&Bs[(rb + j*16 + lr)*64 + ((ks*32 + kh*8) ^ swz)];
        if (t + 1 < NT)
            stage_half(&Ag[(size_t)(m0 + 128) * ldk + (t+1)*64], ldk, &smA[d^1][1][0], w, lane);
        __builtin_amdgcn_s_barrier();
        __builtin_amdgcn_s_setprio(1);
        #pragma unroll
        for (int i = 0; i < 4; i++)
            #pragma unroll
            for (int j = 0; j < 2; j++)
                #pragma unroll
                for (int ks = 0; ks < 2; ks++)
                    acc[i][j] = __builtin_amdgcn_mfma_f32_16x16x32_bf16(aF[i][ks], bLo[j][ks], acc[i][j], 0, 0, 0);
        __builtin_amdgcn_s_setprio(0);
        __builtin_amdgcn_s_barrier();

        // ---- phase 2: read B-hi
        #pragma unroll
        for (int j = 0; j < 2; j++)
            #pragma unroll
            for (int ks = 0; ks < 2; ks++)
                bHi[j][ks] = *(const bf16x8*)&Bs[(rb + (2+j)*16 + lr)*64 + ((ks*32 + kh*8) ^ swz)];
        __builtin_amdgcn_s_barrier();
        __builtin_amdgcn_s_setprio(1);
        #pragma unroll
        for (int i = 0; i < 4; i++)
            #pragma unroll
            for (int j = 0; j < 2; j++)
                #pragma unroll
                for (int ks = 0; ks < 2; ks++)
                    acc[i][2+j] = __builtin_amdgcn_mfma_f32_16x16x32_bf16(aF[i][ks], bHi[j][ks], acc[i][2+j], 0, 0, 0);
        __builtin_amdgcn_s_setprio(0);
        __builtin_amdgcn_s_barrier();

        // ---- phase 3: read A-hi (overwrites aF); stage Bh0(t+2)
        #pragma unroll
        for (int i = 0; i < 4; i++)
            #pragma unroll
            for (int ks = 0; ks < 2; ks++)
                aF[i][ks] = *(const bf16x8*)&As[(64 + i*16 + lr)*64 + ((ks*32 + kh*8) ^ swz)];
        if (t + 2 < NT)
            stage_half(&Btg[(size_t)(n0) * ldk + (t+2)*64], ldk, &smB[d][0][0], w, lane);
        __builtin_amdgcn_s_barrier();
        __builtin_amdgcn_s_setprio(1);
        #pragma unroll
        for (int i = 0; i < 4; i++)
            #pragma unroll
            for (int j = 0; j < 2; j++)
                #pragma unroll
                for (int ks = 0; ks < 2; ks++)
                    acc[4+i][j] = __builtin_amdgcn_mfma_f32_16x16x32_bf16(aF[i][ks], bLo[j][ks], acc[4+i][j], 0, 0, 0);
        __builtin_amdgcn_s_setprio(0);
        __builtin_amdgcn_s_barrier();

        // ---- phase 4: stage Bh1(t+2)+Ah0(t+2); MFMA; counted vmcnt after
        if (t + 2 < NT) {
            stage_half(&Btg[(size_t)(n0 + 128) * ldk + (t+2)*64], ldk, &smB[d][1][0], w, lane);
            stage_half(&Ag [(size_t)(m0      ) * ldk + (t+2)*64], ldk, &smA[d][0][0], w, lane);
        }
        __builtin_amdgcn_s_barrier();
        __builtin_amdgcn_s_setprio(1);
        #pragma unroll
        for (int i = 0; i < 4; i++)
            #pragma unroll
            for (int j = 0; j < 2; j++)
                #pragma unroll
                for (int ks = 0; ks < 2; ks++)
                    acc[4+i][2+j] = __builtin_amdgcn_mfma_f32_16x16x32_bf16(aF[i][ks], bHi[j][ks], acc[4+i][2+j], 0, 0, 0);
        __builtin_amdgcn_s_setprio(0);
        if (t < NT - 2)       { VMCNT(6); }
        else if (t == NT - 2) { VMCNT(0); }
        __builtin_amdgcn_s_barrier();
    }

    #pragma unroll
    for (int mf = 0; mf < 8; mf++) {
        #pragma unroll
        for (int nf = 0; nf < 4; nf++) {
            int r = m0 + wm*128 + mf*16 + kh*4;
            int cidx = n0 + wn*64 + nf*16 + lr;
            #pragma unroll
            for (int q = 0; q < 4; q++) {
                if constexpr (KSPLIT) {
                    Cg2[(size_t)(r+q)*ldc + cidx] = f2us(acc[mf][nf][q]);
                } else if constexpr (sizeof(TC) == 4) {
                    Cg[(size_t)(r+q)*ldc + cidx] = acc[mf][nf][q];
                } else {
                    Cg[(size_t)(r+q)*ldc + cidx] = f2us(acc[mf][nf][q]);
                }
            }
        }
    }
}

// ---------- GEMM1 tail: N=512, K-split-4, 2-phase 128x128, f32 partials ----------
__global__ __launch_bounds__(256)
void gemm_tail_ks4(const u16* __restrict__ A, const u16* __restrict__ Bt,
                   float* __restrict__ Cp, int M, int ldk)
{
    __shared__ u16 Asm[128][32];
    __shared__ u16 Bsm[128][32];
    const int t = threadIdx.x;
    const int lane = t & 63, w = t >> 6;
    const int wr = w >> 1, wc = w & 1;
    const int lr = lane & 15, kh = lane >> 4;

    const int bid = blockIdx.x;
    const int kidx = bid & 3, tile = bid >> 2;
    const int m0 = (tile >> 2) * 128;
    const int n0 = (tile & 3) * 128;

    const u16* Ak = A  + kidx * 512;
    const u16* Bk = Bt + kidx * 512;
    float* C = Cp + (size_t)kidx * TSTRIDE;

    f32x4 acc[4][4];
    #pragma unroll
    for (int i = 0; i < 4; i++)
        #pragma unroll
        for (int j = 0; j < 4; j++) acc[i][j] = (f32x4){0.f,0.f,0.f,0.f};

    for (int k0 = 0; k0 < 512; k0 += 32) {
        #pragma unroll
        for (int i = 0; i < 2; i++) {
            int cb = i * 256 + w * 64;
            int chunk = cb + lane;
            int row = chunk >> 2, kb = chunk & 3;
            gload_lds16(&Ak[(size_t)(m0 + row) * ldk + k0 + kb * 8], &Asm[0][0] + cb * 8);
            gload_lds16(&Bk[(size_t)(n0 + row) * ldk + k0 + kb * 8], &Bsm[0][0] + cb * 8);
        }
        __syncthreads();
        bf16x8 af[4], bf[4];
        #pragma unroll
        for (int i = 0; i < 4; i++)
            af[i] = *(const bf16x8*)&Asm[wr*64 + i*16 + lr][kh*8];
        #pragma unroll
        for (int j = 0; j < 4; j++)
            bf[j] = *(const bf16x8*)&Bsm[wc*64 + j*16 + lr][kh*8];
        #pragma unroll
        for (int i = 0; i < 4; i++)
            #pragma unroll
            for (int j = 0; j < 4; j++)
                acc[i][j] = __builtin_amdgcn_mfma_f32_16x16x32_bf16(af[i], bf[j], acc[i][j], 0, 0, 0);
        __syncthreads();
    }
    #pragma unroll
    for (int i = 0; i < 4; i++) {
        #pragma unroll
        for (int j = 0; j < 4; j++) {
            int r = m0 + wr*64 + i*16 + kh*4;
            int cidx = n0 + wc*64 + j*16 + lr;
            #pragma unroll
            for (int q = 0; q < 4; q++)
                C[(size_t)(r+q)*512 + cidx] = acc[i][j][q];
        }
    }
}

// ---------------- conv1d + bias + SiLU; B/C channels read 4 tail partials directly ----------------
__global__ __launch_bounds__(256)
void conv_silu(const u16* __restrict__ zx, const float* __restrict__ tailp,
               const float* __restrict__ cw, const float* __restrict__ cb,
               u16* __restrict__ xconv, u16* __restrict__ Bbuf, u16* __restrict__ Cbuf)
{
    int idx = blockIdx.x * 256 + threadIdx.x;
    int cg = idx % (CONV_DIM / 8);
    int r  = idx / (CONV_DIM / 8);
    int c0 = cg * 8;
    int l  = r & (SEQ - 1);

    float y[8];
    {
        float4 b0 = *(const float4*)&cb[c0];
        float4 b1 = *(const float4*)&cb[c0 + 4];
        y[0]=b0.x; y[1]=b0.y; y[2]=b0.z; y[3]=b0.w;
        y[4]=b1.x; y[5]=b1.y; y[6]=b1.z; y[7]=b1.w;
    }
    float cwf[8][4];
    #pragma unroll
    for (int e = 0; e < 8; e++) {
        float4 v = *(const float4*)&cw[(c0 + e) * 4];
        cwf[e][0]=v.x; cwf[e][1]=v.y; cwf[e][2]=v.z; cwf[e][3]=v.w;
    }
    if (c0 < D_INNER) {                      // x channels: zx cols [4096, 8192)
        #pragma unroll
        for (int k = 0; k < 4; k++) {
            if (l + k - 3 >= 0) {
                u16x8 v = *(const u16x8*)&zx[(size_t)(r + k - 3) * LD_ZX + D_INNER + c0];
                #pragma unroll
                for (int e = 0; e < 8; e++) y[e] += us2f(v[e]) * cwf[e][k];
            }
        }
    } else {                                 // B/C channels: sum 4 tail partials
        int tc = c0 - D_INNER;
        #pragma unroll
        for (int k = 0; k < 4; k++) {
            if (l + k - 3 >= 0) {
                const float* tb = &tailp[(size_t)(r + k - 3) * 512 + tc];
                #pragma unroll
                for (int e = 0; e < 8; e++) {
                    float s = tb[e] + tb[TSTRIDE + e] + tb[2*TSTRIDE + e] + tb[3*TSTRIDE + e];
                    y[e] += s * cwf[e][k];
                }
            }
        }
    }
    u16x8 o;
    #pragma unroll
    for (int e = 0; e < 8; e++) {
        float s = y[e] / (1.f + expf(-y[e]));
        o[e] = f2us(s);
    }
    if (c0 < D_INNER)                *(u16x8*)&xconv[(size_t)r * D_INNER + c0] = o;
    else if (c0 < D_INNER + D_STATE) *(u16x8*)&Bbuf[(size_t)r * D_STATE + (c0 - D_INNER)] = o;
    else                             *(u16x8*)&Cbuf[(size_t)r * D_STATE + (c0 - D_INNER - D_STATE)] = o;
}

// ---------------- dt softplus + per-chunk cumsum (dt from tail partials) ----------------
__global__ __launch_bounds__(256)
void dt_acs(const float* __restrict__ tailp, const float* __restrict__ Aparam,
            const float* __restrict__ dt_bias, float* __restrict__ dtT,
            float* __restrict__ Acs)
{
    __shared__ float sb[CHUNK];
    int blk = blockIdx.x;
    int c = blk & 7, h = (blk >> 3) & 63, b = blk >> 9;
    int t = threadIdx.x;
    int lg = c * CHUNK + t;
    int row = b * SEQ + lg;
    const float* tb = &tailp[(size_t)row * 512 + 256 + h];
    float x = tb[0] + tb[TSTRIDE] + tb[2*TSTRIDE] + tb[3*TSTRIDE];
    x += dt_bias[h];
    float dt = (x > 20.f) ? x : log1pf(expf(x));
    float v = dt * Aparam[h];
    sb[t] = v; __syncthreads();
    #pragma unroll
    for (int off = 1; off < 256; off <<= 1) {
        float add = (t >= off) ? sb[t - off] : 0.f;
        __syncthreads();
        v += add; sb[t] = v;
        __syncthreads();
    }
    int o = (b * NHEADS + h) * SEQ + lg;
    dtT[o] = dt;
    Acs[o] = v;
}

// ---------------- S precompute: S[bc][l][s] = C_l . B_s (head-shared, lower-tri tiles) ----------------
__global__ __launch_bounds__(256)
void s_precompute(const u16* __restrict__ Bbuf, const u16* __restrict__ Cbuf,
                  u16* __restrict__ Sbuf)
{
    int p = blockIdx.x % 10, bc = blockIdx.x / 10;
    int q = (p >= 6) ? 3 : (p >= 3) ? 2 : (p >= 1) ? 1 : 0;
    int st = p - q * (q + 1) / 2;
    int b = bc >> 3, c = bc & 7;
    const int lane = threadIdx.x & 63, w = threadIdx.x >> 6;
    const int lr = lane & 15, kh = lane >> 4;
    const size_t rowbase = (size_t)(b * SEQ + c * CHUNK);

    f32x4 sacc[4];
    #pragma unroll
    for (int i = 0; i < 4; i++) sacc[i] = (f32x4){0.f,0.f,0.f,0.f};
    #pragma unroll
    for (int kk = 0; kk < 4; kk++) {
        bf16x8 bA = *(const bf16x8*)&Bbuf[(rowbase + st*64 + w*16 + lr) * D_STATE + kk*32 + kh*8];
        #pragma unroll
        for (int i = 0; i < 4; i++) {
            bf16x8 af = *(const bf16x8*)&Cbuf[(rowbase + q*64 + i*16 + lr) * D_STATE + kk*32 + kh*8];
            sacc[i] = __builtin_amdgcn_mfma_f32_16x16x32_bf16(bA, af, sacc[i], 0, 0, 0);
        }
    }
    u16* Sb = Sbuf + (size_t)bc * 256 * 256;
    #pragma unroll
    for (int i = 0; i < 4; i++) {
        u16x4 o;
        #pragma unroll
        for (int qq = 0; qq < 4; qq++) o[qq] = f2us(sacc[i][qq]);
        *(u16x4*)&Sb[(size_t)(q*64 + i*16 + lr) * 256 + st*64 + w*16 + kh*4] = o;
    }
}

// ---------------- per-chunk states via MFMA, bf16 out, swapped operands ----------------
__global__ __launch_bounds__(256)
void chunk_states_mfma(const u16* __restrict__ xconv, const u16* __restrict__ Bbuf,
                       const float* __restrict__ dtT, const float* __restrict__ Acs,
                       u16* __restrict__ states)
{
    __shared__ u16 Btsh[128][72];   // B^T [n][l]
    __shared__ u16 xtsh[64][72];    // (w*x)^T [p][l]
    __shared__ float acs_sh[CHUNK];
    __shared__ float dt_sh[CHUNK];

    const int blk = blockIdx.x;
    const int h = blk & 63, c = (blk >> 6) & 7, b = blk >> 9;
    const int t = threadIdx.x;
    const int lane = t & 63, w = t >> 6;
    const int wr = w >> 1, wc = w & 1;
    const int lr = lane & 15, kh = lane >> 4;
    const int bh = b * NHEADS + h;
    const size_t rowbase = (size_t)(b * SEQ + c * CHUNK);

    acs_sh[t] = Acs[(size_t)bh * SEQ + c * CHUNK + t];
    dt_sh[t]  = dtT[(size_t)bh * SEQ + c * CHUNK + t];
    __syncthreads();
    const float acs_last = acs_sh[CHUNK - 1];

    f32x4 acc[4][2];   // [j = n-block][i = p-block]
    #pragma unroll
    for (int j = 0; j < 4; j++)
        #pragma unroll
        for (int i = 0; i < 2; i++) acc[j][i] = (f32x4){0.f,0.f,0.f,0.f};

    for (int lt = 0; lt < 4; lt++) {
        __syncthreads();
        const int s = t & 63;
        const int sg = lt * 64 + s;
        const float wgt = dt_sh[sg] * expf(acs_last - acs_sh[sg]);
        {
            int ng = (t >> 6) * 32;
            const u16* src = &Bbuf[(rowbase + sg) * D_STATE + ng];
            #pragma unroll
            for (int q = 0; q < 4; q++) {
                u16x8 v = *(const u16x8*)&src[q * 8];
                #pragma unroll
                for (int e = 0; e < 8; e++)
                    Btsh[ng + q*8 + e][s] = v[e];
            }
        }
        {
            int pg = (t >> 6) * 16;
            const u16* src = &xconv[(rowbase + sg) * D_INNER + h * HEAD_DIM + pg];
            u16x8 v0 = *(const u16x8*)&src[0];
            u16x8 v1 = *(const u16x8*)&src[8];
            #pragma unroll
            for (int e = 0; e < 8; e++) {
                xtsh[pg + e][s]     = f2us(us2f(v0[e]) * wgt);
                xtsh[pg + 8 + e][s] = f2us(us2f(v1[e]) * wgt);
            }
        }
        __syncthreads();
        #pragma unroll
        for (int kk = 0; kk < 2; kk++) {
            bf16x8 xf[2], bf[4];
            #pragma unroll
            for (int i = 0; i < 2; i++)
                xf[i] = *(const bf16x8*)&xtsh[wr*32 + i*16 + lr][kk*32 + kh*8];
            #pragma unroll
            for (int j = 0; j < 4; j++)
                bf[j] = *(const bf16x8*)&Btsh[wc*64 + j*16 + lr][kk*32 + kh*8];
            #pragma unroll
            for (int j = 0; j < 4; j++)
                #pragma unroll
                for (int i = 0; i < 2; i++)
                    acc[j][i] = __builtin_amdgcn_mfma_f32_16x16x32_bf16(bf[j], xf[i], acc[j][i], 0, 0, 0);
        }
    }
    size_t base = ((size_t)((b*NCHUNK + c)*NHEADS + h)) * (HEAD_DIM * D_STATE);
    #pragma unroll
    for (int j = 0; j < 4; j++) {
        #pragma unroll
        for (int i = 0; i < 2; i++) {
            int p = wr*32 + i*16 + lr;
            int n = wc*64 + j*16 + kh*4;
            u16x4 o;
            #pragma unroll
            for (int q = 0; q < 4; q++) o[q] = f2us(acc[j][i][q]);
            *(u16x4*)&states[base + (size_t)p * D_STATE + n] = o;
        }
    }
}

// ---------------- inter-chunk recurrence, bf16 states ----------------
__global__ __launch_bounds__(256)
void state_recurrence(u16* __restrict__ states, const float* __restrict__ Acs)
{
    int idx = blockIdx.x * 256 + threadIdx.x;
    int n8 = idx & 15;
    int p  = (idx >> 4) & 63;
    int bh = idx >> 10;
    int b = bh >> 6, h = bh & 63;
    float E[8];
    #pragma unroll
    for (int e = 0; e < 8; e++) E[e] = 0.f;
    for (int c = 0; c < NCHUNK; c++) {
        size_t off = ((size_t)((b*NCHUNK + c)*NHEADS + h)) * 8192 + (size_t)p * 128 + n8 * 8;
        u16x8 sv = *(const u16x8*)&states[off];
        u16x8 ev;
        #pragma unroll
        for (int e = 0; e < 8; e++) ev[e] = f2us(E[e]);
        *(u16x8*)&states[off] = ev;
        float g = expf(Acs[(size_t)(b*NHEADS + h) * SEQ + c*CHUNK + 255]);
        #pragma unroll
        for (int e = 0; e < 8; e++) E[e] = g * E[e] + us2f(sv[e]);
    }
}

// ---------------- chunk output: prev read from global (no Bsm); LDS 48 KB -> 3 blocks/CU ----------------
__global__ __launch_bounds__(256, 3)
void chunk_output_mfma(const u16* __restrict__ xconv, const u16* __restrict__ Sbuf,
                       const u16* __restrict__ Cbuf, const float* __restrict__ dtT,
                       const float* __restrict__ Acs, const u16* __restrict__ states,
                       const float* __restrict__ Dparam, u16* __restrict__ Y)
{
    __shared__ u16 xt[64][72];         // x^T tile [p][s]
    __shared__ u16 Pt[4][64][72];      // per-wave P [l][s]
    __shared__ float acs_sh[CHUNK];
    __shared__ float dt_sh[CHUNK];

    const int blk = blockIdx.x;
    const int h = blk & 63, c = (blk >> 6) & 7, b = blk >> 9;
    const int t = threadIdx.x;
    const int lane = t & 63, w = t >> 6;
    const int lr = lane & 15, kh = lane >> 4;
    const int bh = b * NHEADS + h;
    const size_t rowbase = (size_t)(b * SEQ + c * CHUNK);
    const u16* Sblk = Sbuf + (size_t)(b * NCHUNK + c) * 256 * 256;
    const u16* prevg = &states[((size_t)((b*NCHUNK + c)*NHEADS + h)) * 8192];

    acs_sh[t] = Acs[(size_t)bh * SEQ + c * CHUNK + t];
    dt_sh[t]  = dtT[(size_t)bh * SEQ + c * CHUNK + t];

    bf16x8 af[4][4];
    #pragma unroll
    for (int i = 0; i < 4; i++)
        #pragma unroll
        for (int kk = 0; kk < 4; kk++)
            af[i][kk] = *(const bf16x8*)&Cbuf[(rowbase + w*64 + i*16 + lr) * D_STATE + kk*32 + kh*8];

    __syncthreads();
    float acs_l[4], el[4];
    #pragma unroll
    for (int i = 0; i < 4; i++) { acs_l[i] = acs_sh[w*64 + i*16 + lr]; el[i] = expf(acs_l[i]); }

    // Y_off raw: yacc[j][i] = prev . C (prev frags straight from global bf16 states)
    f32x4 yacc[4][4];
    #pragma unroll
    for (int j = 0; j < 4; j++)
        #pragma unroll
        for (int i = 0; i < 4; i++) yacc[j][i] = (f32x4){0.f,0.f,0.f,0.f};
    #pragma unroll
    for (int kk = 0; kk < 4; kk++) {
        bf16x8 pvA[4];
        #pragma unroll
        for (int j = 0; j < 4; j++)
            pvA[j] = *(const bf16x8*)&prevg[(size_t)(j*16 + lr) * 128 + kk*32 + kh*8];
        #pragma unroll
        for (int j = 0; j < 4; j++)
            #pragma unroll
            for (int i = 0; i < 4; i++)
                yacc[j][i] = __builtin_amdgcn_mfma_f32_16x16x32_bf16(pvA[j], af[i][kk], yacc[j][i], 0, 0, 0);
    }
    #pragma unroll
    for (int j = 0; j < 4; j++)
        #pragma unroll
        for (int i = 0; i < 4; i++)
            #pragma unroll
            for (int q = 0; q < 4; q++)
                yacc[j][i][q] *= el[i];

    for (int st = 0; st < 4; st++) {
        __syncthreads();
        {   // stage x^T tile [p][s]
            int s = t & 63, pg = t >> 6;
            const u16* src = &xconv[(rowbase + st*64 + s) * D_INNER + h*HEAD_DIM + pg*16];
            u16x8 v0 = *(const u16x8*)&src[0];
            u16x8 v1 = *(const u16x8*)&src[8];
            #pragma unroll
            for (int q = 0; q < 8; q++) { xt[pg*16 + q][s] = v0[q]; xt[pg*16 + 8 + q][s] = v1[q]; }
        }
        __syncthreads();
        if (st > w) continue;

        // P = mask(S) * dt, S loaded from head-shared Sbuf
        #pragma unroll
        for (int js = 0; js < 4; js++) {
            int s0 = st*64 + js*16;
            float as0 = acs_sh[s0];
            int sgq = s0 + kh*4;
            float eneg[4];
            #pragma unroll
            for (int q = 0; q < 4; q++)
                eneg[q] = expf(fminf(as0 - acs_sh[sgq + q], 60.f)) * dt_sh[sgq + q];
            #pragma unroll
            for (int i = 0; i < 4; i++) {
                int ll = w*64 + i*16 + lr;
                float eladj = expf(acs_l[i] - as0);
                u16x4 sv = *(const u16x4*)&Sblk[(size_t)ll * 256 + sgq];
                u16x4 pv;
                #pragma unroll
                for (int q = 0; q < 4; q++) {
                    float fac = (sgq + q <= ll) ? eladj * eneg[q] : 0.f;
                    pv[q] = f2us(us2f(sv[q]) * fac);
                }
                *(u16x4*)&Pt[w][i*16 + lr][js*16 + kh*4] = pv;
            }
        }
        #pragma unroll
        for (int kk2 = 0; kk2 < 2; kk2++) {
            bf16x8 xA[4], pB[4];
            #pragma unroll
            for (int j = 0; j < 4; j++)
                xA[j] = *(const bf16x8*)&xt[j*16 + lr][kk2*32 + kh*8];
            #pragma unroll
            for (int i = 0; i < 4; i++)
                pB[i] = *(const bf16x8*)&Pt[w][i*16 + lr][kk2*32 + kh*8];
            #pragma unroll
            for (int j = 0; j < 4; j++)
                #pragma unroll
                for (int i = 0; i < 4; i++)
                    yacc[j][i] = __builtin_amdgcn_mfma_f32_16x16x32_bf16(xA[j], pB[i], yacc[j][i], 0, 0, 0);
        }
    }

    float Dh = Dparam[h];
    #pragma unroll
    for (int i = 0; i < 4; i++) {
        #pragma unroll
        for (int j = 0; j < 4; j++) {
            size_t o = (rowbase + w*64 + i*16 + lr) * D_INNER + h*HEAD_DIM + j*16 + kh*4;
            u16x4 xv = *(const u16x4*)&xconv[o];
            u16x4 ov;
            #pragma unroll
            for (int q = 0; q < 4; q++)
                ov[q] = f2us(yacc[j][i][q] + Dh * us2f(xv[q]));
            *(u16x4*)&Y[o] = ov;
        }
    }
}

// ---------------- gated RMSNorm (register-resident) ----------------
__global__ __launch_bounds__(256)
void gated_rmsnorm_k(u16* __restrict__ Y, const u16* __restrict__ zx,
                     const float* __restrict__ nw)
{
    __shared__ float red[4];
    int row = blockIdx.x;
    int t = threadIdx.x;
    float x[16];
    float ss = 0.f;
    #pragma unroll
    for (int g = 0; g < 2; g++) {
        int i = g * 2048 + t * 8;
        u16x8 yv = *(const u16x8*)&Y[(size_t)row * D_INNER + i];
        u16x8 zv = *(const u16x8*)&zx[(size_t)row * LD_ZX + i];
        #pragma unroll
        for (int q = 0; q < 8; q++) {
            float xv = us2f(yv[q]) * siluf(us2f(zv[q]));
            x[g*8 + q] = xv;
            ss += xv * xv;
        }
    }
    #pragma unroll
    for (int off = 32; off > 0; off >>= 1) ss += __shfl_down(ss, off);
    int wid = t >> 6, lane = t & 63;
    if (lane == 0) red[wid] = ss;
    __syncthreads();
    float tot = red[0] + red[1] + red[2] + red[3];
    float sc = rsqrtf(tot / (float)D_INNER + EPS_RMS);
    #pragma unroll
    for (int g = 0; g < 2; g++) {
        int i = g * 2048 + t * 8;
        float4 w0 = *(const float4*)&nw[i];
        float4 w1 = *(const float4*)&nw[i + 4];
        float wv[8] = {w0.x, w0.y, w0.z, w0.w, w1.x, w1.y, w1.z, w1.w};
        u16x8 o;
        #pragma unroll
        for (int q = 0; q < 8; q++) o[q] = f2us(x[g*8 + q] * sc * wv[q]);
        *(u16x8*)&Y[(size_t)row * D_INNER + i] = o;
    }
}

__global__ void ws_fail_k(float* out, float mb){ out[threadIdx.x] = mb; }

// ---------------- launch ----------------
extern "C" void kernel_launch(void* const* d_in, const int* in_sizes, int n_in,
                              void* d_out, int out_size, void* d_ws, size_t ws_size,
                              hipStream_t stream)
{
    const float* hidden  = (const float*)d_in[0];
    const float* W_in    = (const float*)d_in[1];
    const float* conv_w  = (const float*)d_in[2];
    const float* conv_b  = (const float*)d_in[3];
    const float* Aparam  = (const float*)d_in[4];
    const float* Dparam  = (const float*)d_in[5];
    const float* dt_bias = (const float*)d_in[6];
    const float* norm_w  = (const float*)d_in[7];
    const float* W_out   = (const float*)d_in[8];
    float* out = (float*)d_out;

    const int M = BATCH * SEQ;  // 4096

    size_t off = 0;
    char* wsb = (char*)d_ws;
    u16*   zx     = (u16*)  (wsb + off); off += (size_t)M * LD_ZX * 2;
    u16*   xconv  = (u16*)  (wsb + off); off += (size_t)M * D_INNER * 2;
    u16*   Bbuf   = (u16*)  (wsb + off); off += (size_t)M * D_STATE * 2;
    u16*   Cbuf   = (u16*)  (wsb + off); off += (size_t)M * D_STATE * 2;
    float* dtT    = (float*)(wsb + off); off += (size_t)BATCH * NHEADS * SEQ * 4;
    float* Acs    = (float*)(wsb + off); off += (size_t)BATCH * NHEADS * SEQ * 4;
    u16*   states = (u16*)  (wsb + off); off += (size_t)BATCH * NCHUNK * NHEADS * HEAD_DIM * D_STATE * 2;
    u16*   Ybuf   = (u16*)  (wsb + off); off += (size_t)M * D_INNER * 2;
    u16*   hbf    = (u16*)  (wsb + off); off += (size_t)M * D_MODEL * 2;
    u16*   WtIn   = (u16*)  (wsb + off); off += (size_t)LD_ZX * D_MODEL * 2;
    u16*   WtOut  = (u16*)  (wsb + off); off += (size_t)D_MODEL * D_INNER * 2;
    float* tailp  = (float*)(wsb + off); off += 4 * TSTRIDE * 4;            // 33.5 MB
    u16*   Sbuf   = (u16*)  (wsb + off); off += (size_t)16 * 256 * 256 * 2; // 2 MB
    u16*   tmpf   = (u16*)zx;   // GEMM2 bf16 planes alias zx (dead after gated_rmsnorm)

    if (off > ws_size) {
        ws_fail_k<<<1, 64, 0, stream>>>(out, (float)(ws_size >> 20));
        return;
    }

    // fused preprocessing: hbf cvt (8192) + WtIn transpose (4352) + WtOut transpose (2048)
    prep_kernel<<<8192 + 4352 + 2048, 256, 0, stream>>>(hidden, hbf, W_in, WtIn, W_out, WtOut);

    // GEMM1 main: zx[:, 0:8192] — 512 blocks, 8x8 supertiled (FETCH 98 MB, r19)
    gemm_8ph<u16, false><<<(8192/256) * (M/256), 512, 0, stream>>>(
        hbf, WtIn, zx, nullptr, M, 8192, D_MODEL, D_MODEL, LD_ZX);
    // GEMM1 tail: cols [8192:8704] — K-split-4 f32 partials, consumed by conv/dt directly
    gemm_tail_ks4<<<512, 256, 0, stream>>>(hbf, WtIn + (size_t)8192 * D_MODEL, tailp, M, D_MODEL);

    conv_silu<<<(M * CONV_DIM / 8) / 256, 256, 0, stream>>>(zx, tailp, conv_w, conv_b, xconv, Bbuf, Cbuf);
    s_precompute<<<160, 256, 0, stream>>>(Bbuf, Cbuf, Sbuf);
    dt_acs<<<BATCH * NHEADS * NCHUNK, 256, 0, stream>>>(tailp, Aparam, dt_bias, dtT, Acs);
    chunk_states_mfma<<<BATCH * NCHUNK * NHEADS, 256, 0, stream>>>(xconv, Bbuf, dtT, Acs, states);
    state_recurrence<<<(BATCH * NHEADS * 64 * 16) / 256, 256, 0, stream>>>(states, Acs);
    chunk_output_mfma<<<BATCH * NCHUNK * NHEADS, 256, 0, stream>>>(xconv, Sbuf, Cbuf, dtT, Acs, states, Dparam, Ybuf);
    gated_rmsnorm_k<<<M, 256, 0, stream>>>(Ybuf, zx, norm_w);   // last reader of zx

    // GEMM2 K-split-2: 256 blocks = 1 CU-round; both halves bf16; out = t0 + t1
    gemm_8ph<float, true><<<2 * (D_MODEL/256) * (M/256), 512, 0, stream>>>(
        Ybuf, WtOut, out, tmpf, M, D_MODEL, D_INNER/2, D_INNER, D_MODEL);
    add2_bf16<<<(M * D_MODEL / 8 + 255) / 256, 256, 0, stream>>>(
        out, tmpf, tmpf + (size_t)M * D_MODEL, M * D_MODEL / 8);
}

// Round 21
// 440.213 us; speedup vs baseline: 1.0732x; 1.0077x over previous
//
#include <hip/hip_runtime.h>
#include <hip/hip_bf16.h>
#include <math.h>

#define D_MODEL   2048
#define D_INNER   4096
#define NHEADS    64
#define HEAD_DIM  64
#define D_STATE   128
#define CHUNK     256
#define CONV_DIM  (D_INNER + 2*D_STATE)            // 4352
#define D_IN_PROJ (2*D_INNER + 2*D_STATE + NHEADS) // 8512
#define LD_ZX     8704                             // D_IN_PROJ padded to 256
#define BATCH     2
#define SEQ       2048
#define NCHUNK    (SEQ/CHUNK)                      // 8
#define EPS_RMS   1e-5f
#define MROWS     4096
#define TSTRIDE   ((size_t)MROWS * 512)            // tail-partial plane stride (f32 elems)

typedef unsigned short u16;
typedef __attribute__((ext_vector_type(8))) unsigned short u16x8;
typedef __attribute__((ext_vector_type(4))) unsigned short u16x4;
typedef __attribute__((ext_vector_type(8))) short bf16x8;   // MFMA A/B frag (8 bf16)
typedef __attribute__((ext_vector_type(4))) float f32x4;    // MFMA C/D frag

__device__ __forceinline__ float us2f(u16 u){
    union { unsigned int i; float f; } c; c.i = ((unsigned int)u) << 16; return c.f;
}
__device__ __forceinline__ u16 f2us(float f){
    union { float f; unsigned int i; } c; c.f = f;
    unsigned int r = c.i + 0x7FFFu + ((c.i >> 16) & 1u);
    return (u16)(r >> 16);
}
__device__ __forceinline__ float siluf(float x){ return x / (1.f + expf(-x)); }

__device__ __forceinline__ void gload_lds16(const void* g, void* l) {
    __builtin_amdgcn_global_load_lds((const __attribute__((address_space(1))) void*)g,
                                     (__attribute__((address_space(3))) void*)l, 16, 0, 0);
}

#define VMCNT(n) asm volatile("s_waitcnt vmcnt(" #n ")" ::: "memory")

// stage one 128x64 bf16 half-tile (row-major, stride ldk) into LDS with T2 swizzle.
__device__ __forceinline__ void stage_half(const u16* __restrict__ g, size_t ldk,
                                           u16* ldsbase, int w, int lane)
{
    #pragma unroll
    for (int cc = 0; cc < 2; cc++) {
        int cb = cc * 512 + w * 64;          // wave-uniform chunk base
        int ci = cb + lane;
        int sc = ci ^ ((ci >> 3) & 7);       // swizzled source chunk (involution)
        gload_lds16(&g[(size_t)(sc >> 3) * ldk + (sc & 7) * 8], ldsbase + cb * 8);
    }
}

// ---------- fused preprocessing: hbf cvt + W_in/W_out transpose+cvt ----------
__global__ __launch_bounds__(256)
void prep_kernel(const float* __restrict__ hidden, u16* __restrict__ hbf,
                 const float* __restrict__ W_in, u16* __restrict__ WtIn,
                 const float* __restrict__ W_out, u16* __restrict__ WtOut)
{
    __shared__ u16 tile[64][65];
    int bid = blockIdx.x;
    int t = threadIdx.x;
    if (bid < 8192) {                      // hbf = bf16(hidden), 4 f32/thread
        int i = bid * 256 + t;
        float4 v = *(const float4*)&hidden[(size_t)i * 4];
        u16x4 o; o[0]=f2us(v.x); o[1]=f2us(v.y); o[2]=f2us(v.z); o[3]=f2us(v.w);
        *(u16x4*)&hbf[(size_t)i * 4] = o;
        return;
    }
    const float* in; u16* out; int K, N, k0, n0;
    if (bid < 8192 + 4352) {               // WtIn: K=2048, N=8512 (pad to 8704)
        int b2 = bid - 8192;
        in = W_in; out = WtIn; K = D_MODEL; N = D_IN_PROJ;
        k0 = (b2 % 32) * 64; n0 = (b2 / 32) * 64;
    } else {                               // WtOut: K=4096, N=2048
        int b3 = bid - 8192 - 4352;
        in = W_out; out = WtOut; K = D_INNER; N = D_MODEL;
        k0 = (b3 % 64) * 64; n0 = (b3 / 64) * 64;
    }
    #pragma unroll
    for (int q = 0; q < 16; q++) {
        int lin = q * 256 + t;
        int r = lin >> 6, c = lin & 63;
        int n = n0 + c;
        float v = (n < N) ? in[(size_t)(k0 + r) * N + n] : 0.f;
        tile[r][c] = f2us(v);
    }
    __syncthreads();
    #pragma unroll
    for (int q = 0; q < 4; q++) {
        int lin = q * 256 + t;
        int r = lin >> 4, cg = lin & 15;
        u16x4 v;
        #pragma unroll
        for (int e = 0; e < 4; e++) v[e] = tile[cg*4 + e][r];
        *(u16x4*)&out[(size_t)(n0 + r) * K + k0 + cg*4] = v;
    }
}

// ---------- out = bf16 tmp0 + bf16 tmp1 (f32 result) ----------
__global__ __launch_bounds__(256)
void add2_bf16(float* __restrict__ out, const u16* __restrict__ t0,
               const u16* __restrict__ t1, int n8)
{
    int i = blockIdx.x * 256 + threadIdx.x;
    if (i >= n8) return;
    u16x8 a = *(const u16x8*)&t0[(size_t)i * 8];
    u16x8 b = *(const u16x8*)&t1[(size_t)i * 8];
    float* o = &out[(size_t)i * 8];
    *(float4*)&o[0] = make_float4(us2f(a[0])+us2f(b[0]), us2f(a[1])+us2f(b[1]),
                                  us2f(a[2])+us2f(b[2]), us2f(a[3])+us2f(b[3]));
    *(float4*)&o[4] = make_float4(us2f(a[4])+us2f(b[4]), us2f(a[5])+us2f(b[5]),
                                  us2f(a[6])+us2f(b[6]), us2f(a[7])+us2f(b[7]));
}

// ---------- 8-phase 256x256 MFMA GEMM (T2-swizzled LDS, plain barriers) ----------
// Stage ledger (round-12 proven): p1: Ah1(t+1); p3: Bh0(t+2); p4: Bh1(t+2)+Ah0(t+2).
// KSPLIT: grid = 2*ntiles; kidx selects K-half; writes bf16 plane Cg2 + kidx*M*ldc.
// Block map: XCD swizzle (m204) then 8x8 supertile (r19 verified: FETCH 270->98 MB).
template<typename TC, bool KSPLIT>
__global__ __launch_bounds__(512, 1)
void gemm_8ph(const u16* __restrict__ Ag, const u16* __restrict__ Btg,
              TC* __restrict__ Cg, u16* __restrict__ Cg2,
              int M, int N, int Kext, int ldk, int ldc)
{
    __shared__ u16 smA[2][2][8192];   // [dbuf][half][128*64]
    __shared__ u16 smB[2][2][8192];
    const int tid = threadIdx.x;
    const int lane = tid & 63, w = tid >> 6;
    const int wm = w >> 2, wn = w & 3;
    const int lr = lane & 15, kh = lane >> 4;
    const int swz = (lr & 7) << 3;

    int orig = blockIdx.x;
    int ntile = gridDim.x;
    int kidx = 0;
    if constexpr (KSPLIT) { kidx = orig & 1; orig >>= 1; ntile >>= 1; }

    const int nbx = N >> 8;
    const int nby = ntile / nbx;
    const int qq = ntile >> 3, r8 = ntile & 7;
    const int xcd = orig & 7, loc = orig >> 3;
    const int wgid = (xcd < r8 ? xcd*(qq+1) : r8*(qq+1) + (xcd-r8)*qq) + loc;

    int mt, nt;
    if (((nbx & 7) | (nby & 7)) == 0 && (ntile & 63) == 0) {   // 8x8 supertile map
        int scols = nbx >> 3;
        int sg = wgid >> 6, sloc = wgid & 63;
        int sr = sg / scols, sc = sg - sr * scols;
        mt = sr * 8 + (sloc >> 3);
        nt = sc * 8 + (sloc & 7);
    } else {
        mt = wgid / nbx; nt = wgid % nbx;
    }
    const int m0 = mt * 256;
    const int n0 = nt * 256;

    if constexpr (KSPLIT) {
        Ag  += (size_t)kidx * Kext;
        Btg += (size_t)kidx * Kext;
        Cg2 += (size_t)kidx * M * ldc;
    }
    const int NT = Kext >> 6;

    f32x4 acc[8][4];
    #pragma unroll
    for (int i = 0; i < 8; i++)
        #pragma unroll
        for (int j = 0; j < 4; j++) acc[i][j] = (f32x4){0.f,0.f,0.f,0.f};

    stage_half(&Ag [(size_t)(m0      ) * ldk      ], ldk, &smA[0][0][0], w, lane);
    stage_half(&Ag [(size_t)(m0 + 128) * ldk      ], ldk, &smA[0][1][0], w, lane);
    stage_half(&Btg[(size_t)(n0      ) * ldk      ], ldk, &smB[0][0][0], w, lane);
    stage_half(&Btg[(size_t)(n0 + 128) * ldk      ], ldk, &smB[0][1][0], w, lane);
    stage_half(&Ag [(size_t)(m0      ) * ldk + 64 ], ldk, &smA[1][0][0], w, lane);
    stage_half(&Btg[(size_t)(n0      ) * ldk + 64 ], ldk, &smB[1][0][0], w, lane);
    stage_half(&Btg[(size_t)(n0 + 128) * ldk + 64 ], ldk, &smB[1][1][0], w, lane);
    VMCNT(6);
    __builtin_amdgcn_s_barrier();

    for (int t = 0; t < NT; ++t) {
        const int d = t & 1;
        const u16* As = &smA[d][wm][0];
        const u16* Bs = &smB[d][wn >> 1][0];
        const int rb = (wn & 1) * 64;

        bf16x8 aF[4][2], bLo[2][2], bHi[2][2];

        // ---- phase 1: read A-lo + B-lo; stage Ah1(t+1)
        #pragma unroll
        for (int i = 0; i < 4; i++)
            #pragma unroll
            for (int ks = 0; ks < 2; ks++)
                aF[i][ks] = *(const bf16x8*)&As[(i*16 + lr)*64 + ((ks*32 + kh*8) ^ swz)];
        #pragma unroll
        for (int j = 0; j < 2; j++)
            #pragma unroll
            for (int ks = 0; ks < 2; ks++)
                bLo[j][ks] = *(const bf16x8*)&Bs[(rb + j*16 + lr)*64 + ((ks*32 + kh*8) ^ swz)];
        if (t + 1 < NT)
            stage_half(&Ag[(size_t)(m0 + 128) * ldk + (t+1)*64], ldk, &smA[d^1][1][0], w, lane);
        __builtin_amdgcn_s_barrier();
        __builtin_amdgcn_s_setprio(1);
        #pragma unroll
        for (int i = 0; i < 4; i++)
            #pragma unroll
            for (int j = 0; j < 2; j++)
                #pragma unroll
                for (int ks = 0; ks < 2; ks++)
                    acc[i][j] = __builtin_amdgcn_mfma_f32_16x16x32_bf16(aF[i][ks], bLo[j][ks], acc[i][j], 0, 0, 0);
        __builtin_amdgcn_s_setprio(0);
        __builtin_amdgcn_s_barrier();

        // ---- phase 2: read B-hi
        #pragma unroll
        for (int j = 0; j < 2; j++)
            #pragma unroll
            for (int ks = 0; ks < 2; ks++)
                bHi[j][ks] = *(const bf16x8*)&Bs[(rb + (2+j)*16 + lr)*64 + ((ks*32 + kh*8) ^ swz)];
        __builtin_amdgcn_s_barrier();
        __builtin_amdgcn_s_setprio(1);
        #pragma unroll
        for (int i = 0; i < 4; i++)
            #pragma unroll
            for (int j = 0; j < 2; j++)
                #pragma unroll
                for (int ks = 0; ks < 2; ks++)
                    acc[i][2+j] = __builtin_amdgcn_mfma_f32_16x16x32_bf16(aF[i][ks], bHi[j][ks], acc[i][2+j], 0, 0, 0);
        __builtin_amdgcn_s_setprio(0);
        __builtin_amdgcn_s_barrier();

        // ---- phase 3: read A-hi (overwrites aF); stage Bh0(t+2)
        #pragma unroll
        for (int i = 0; i < 4; i++)
            #pragma unroll
            for (int ks = 0; ks < 2; ks++)
                aF[i][ks] = *(const bf16x8*)&As[(64 + i*16 + lr)*64 + ((ks*32 + kh*8) ^ swz)];
        if (t + 2 < NT)
            stage_half(&Btg[(size_t)(n0) * ldk + (t+2)*64], ldk, &smB[d][0][0], w, lane);
        __builtin_amdgcn_s_barrier();
        __builtin_amdgcn_s_setprio(1);
        #pragma unroll
        for (int i = 0; i < 4; i++)
            #pragma unroll
            for (int j = 0; j < 2; j++)
                #pragma unroll
                for (int ks = 0; ks < 2; ks++)
                    acc[4+i][j] = __builtin_amdgcn_mfma_f32_16x16x32_bf16(aF[i][ks], bLo[j][ks], acc[4+i][j], 0, 0, 0);
        __builtin_amdgcn_s_setprio(0);
        __builtin_amdgcn_s_barrier();

        // ---- phase 4: stage Bh1(t+2)+Ah0(t+2); MFMA; counted vmcnt after
        if (t + 2 < NT) {
            stage_half(&Btg[(size_t)(n0 + 128) * ldk + (t+2)*64], ldk, &smB[d][1][0], w, lane);
            stage_half(&Ag [(size_t)(m0      ) * ldk + (t+2)*64], ldk, &smA[d][0][0], w, lane);
        }
        __builtin_amdgcn_s_barrier();
        __builtin_amdgcn_s_setprio(1);
        #pragma unroll
        for (int i = 0; i < 4; i++)
            #pragma unroll
            for (int j = 0; j < 2; j++)
                #pragma unroll
                for (int ks = 0; ks < 2; ks++)
                    acc[4+i][2+j] = __builtin_amdgcn_mfma_f32_16x16x32_bf16(aF[i][ks], bHi[j][ks], acc[4+i][2+j], 0, 0, 0);
        __builtin_amdgcn_s_setprio(0);
        if (t < NT - 2)       { VMCNT(6); }
        else if (t == NT - 2) { VMCNT(0); }
        __builtin_amdgcn_s_barrier();
    }

    #pragma unroll
    for (int mf = 0; mf < 8; mf++) {
        #pragma unroll
        for (int nf = 0; nf < 4; nf++) {
            int r = m0 + wm*128 + mf*16 + kh*4;
            int cidx = n0 + wn*64 + nf*16 + lr;
            #pragma unroll
            for (int q = 0; q < 4; q++) {
                if constexpr (KSPLIT) {
                    Cg2[(size_t)(r+q)*ldc + cidx] = f2us(acc[mf][nf][q]);
                } else if constexpr (sizeof(TC) == 4) {
                    Cg[(size_t)(r+q)*ldc + cidx] = acc[mf][nf][q];
                } else {
                    Cg[(size_t)(r+q)*ldc + cidx] = f2us(acc[mf][nf][q]);
                }
            }
        }
    }
}

// ---------- GEMM1 tail: N=512, K-split-4, 2-phase 128x128, f32 partials ----------
__global__ __launch_bounds__(256)
void gemm_tail_ks4(const u16* __restrict__ A, const u16* __restrict__ Bt,
                   float* __restrict__ Cp, int M, int ldk)
{
    __shared__ u16 Asm[128][32];
    __shared__ u16 Bsm[128][32];
    const int t = threadIdx.x;
    const int lane = t & 63, w = t >> 6;
    const int wr = w >> 1, wc = w & 1;
    const int lr = lane & 15, kh = lane >> 4;

    const int bid = blockIdx.x;
    const int kidx = bid & 3, tile = bid >> 2;
    const int m0 = (tile >> 2) * 128;
    const int n0 = (tile & 3) * 128;

    const u16* Ak = A  + kidx * 512;
    const u16* Bk = Bt + kidx * 512;
    float* C = Cp + (size_t)kidx * TSTRIDE;

    f32x4 acc[4][4];
    #pragma unroll
    for (int i = 0; i < 4; i++)
        #pragma unroll
        for (int j = 0; j < 4; j++) acc[i][j] = (f32x4){0.f,0.f,0.f,0.f};

    for (int k0 = 0; k0 < 512; k0 += 32) {
        #pragma unroll
        for (int i = 0; i < 2; i++) {
            int cb = i * 256 + w * 64;
            int chunk = cb + lane;
            int row = chunk >> 2, kb = chunk & 3;
            gload_lds16(&Ak[(size_t)(m0 + row) * ldk + k0 + kb * 8], &Asm[0][0] + cb * 8);
            gload_lds16(&Bk[(size_t)(n0 + row) * ldk + k0 + kb * 8], &Bsm[0][0] + cb * 8);
        }
        __syncthreads();
        bf16x8 af[4], bf[4];
        #pragma unroll
        for (int i = 0; i < 4; i++)
            af[i] = *(const bf16x8*)&Asm[wr*64 + i*16 + lr][kh*8];
        #pragma unroll
        for (int j = 0; j < 4; j++)
            bf[j] = *(const bf16x8*)&Bsm[wc*64 + j*16 + lr][kh*8];
        #pragma unroll
        for (int i = 0; i < 4; i++)
            #pragma unroll
            for (int j = 0; j < 4; j++)
                acc[i][j] = __builtin_amdgcn_mfma_f32_16x16x32_bf16(af[i], bf[j], acc[i][j], 0, 0, 0);
        __syncthreads();
    }
    #pragma unroll
    for (int i = 0; i < 4; i++) {
        #pragma unroll
        for (int j = 0; j < 4; j++) {
            int r = m0 + wr*64 + i*16 + kh*4;
            int cidx = n0 + wc*64 + j*16 + lr;
            #pragma unroll
            for (int q = 0; q < 4; q++)
                C[(size_t)(r+q)*512 + cidx] = acc[i][j][q];
        }
    }
}

// ---------------- conv1d + bias + SiLU; B/C channels read 4 tail partials directly ----------------
__global__ __launch_bounds__(256)
void conv_silu(const u16* __restrict__ zx, const float* __restrict__ tailp,
               const float* __restrict__ cw, const float* __restrict__ cb,
               u16* __restrict__ xconv, u16* __restrict__ Bbuf, u16* __restrict__ Cbuf)
{
    int idx = blockIdx.x * 256 + threadIdx.x;
    int cg = idx % (CONV_DIM / 8);
    int r  = idx / (CONV_DIM / 8);
    int c0 = cg * 8;
    int l  = r & (SEQ - 1);

    float y[8];
    {
        float4 b0 = *(const float4*)&cb[c0];
        float4 b1 = *(const float4*)&cb[c0 + 4];
        y[0]=b0.x; y[1]=b0.y; y[2]=b0.z; y[3]=b0.w;
        y[4]=b1.x; y[5]=b1.y; y[6]=b1.z; y[7]=b1.w;
    }
    float cwf[8][4];
    #pragma unroll
    for (int e = 0; e < 8; e++) {
        float4 v = *(const float4*)&cw[(c0 + e) * 4];
        cwf[e][0]=v.x; cwf[e][1]=v.y; cwf[e][2]=v.z; cwf[e][3]=v.w;
    }
    if (c0 < D_INNER) {                      // x channels: zx cols [4096, 8192)
        #pragma unroll
        for (int k = 0; k < 4; k++) {
            if (l + k - 3 >= 0) {
                u16x8 v = *(const u16x8*)&zx[(size_t)(r + k - 3) * LD_ZX + D_INNER + c0];
                #pragma unroll
                for (int e = 0; e < 8; e++) y[e] += us2f(v[e]) * cwf[e][k];
            }
        }
    } else {                                 // B/C channels: sum 4 tail partials
        int tc = c0 - D_INNER;
        #pragma unroll
        for (int k = 0; k < 4; k++) {
            if (l + k - 3 >= 0) {
                const float* tb = &tailp[(size_t)(r + k - 3) * 512 + tc];
                #pragma unroll
                for (int e = 0; e < 8; e++) {
                    float s = tb[e] + tb[TSTRIDE + e] + tb[2*TSTRIDE + e] + tb[3*TSTRIDE + e];
                    y[e] += s * cwf[e][k];
                }
            }
        }
    }
    u16x8 o;
    #pragma unroll
    for (int e = 0; e < 8; e++) {
        float s = y[e] / (1.f + expf(-y[e]));
        o[e] = f2us(s);
    }
    if (c0 < D_INNER)                *(u16x8*)&xconv[(size_t)r * D_INNER + c0] = o;
    else if (c0 < D_INNER + D_STATE) *(u16x8*)&Bbuf[(size_t)r * D_STATE + (c0 - D_INNER)] = o;
    else                             *(u16x8*)&Cbuf[(size_t)r * D_STATE + (c0 - D_INNER - D_STATE)] = o;
}

// ---------------- bc_prep: BT transpose (128) + S precompute (160) + dt_acs (1024) ----------------
// BT[bc][n=128][l=256] = Bbuf^T per (b,c): one 64x64 subtile per block (homogeneous blocks).
__global__ __launch_bounds__(256)
void bc_prep(const u16* __restrict__ Bbuf, const u16* __restrict__ Cbuf,
             u16* __restrict__ BT, u16* __restrict__ Sbuf,
             const float* __restrict__ tailp, const float* __restrict__ Aparam,
             const float* __restrict__ dt_bias, float* __restrict__ dtT,
             float* __restrict__ Acs)
{
    __shared__ u16 tile[64][72];
    __shared__ float sb[CHUNK];
    const int bid = blockIdx.x;
    const int t = threadIdx.x;

    if (bid < 128) {                        // BT: bc = bid>>3, sub = bid&7 (l-major 4 x n 2)
        int bc = bid >> 3, sub = bid & 7;
        int l0 = (sub >> 1) * 64, n0 = (sub & 1) * 64;
        int b = bc >> 3, c = bc & 7;
        const size_t rowbase = (size_t)(b * SEQ + c * CHUNK);
        u16* BTb = BT + (size_t)bc * 128 * 256;
        #pragma unroll
        for (int q = 0; q < 2; q++) {       // load 64 l x 64 n
            int lin = q * 256 + t;
            int r = lin >> 3, cc = (lin & 7) * 8;
            *(u16x8*)&tile[r][cc] = *(const u16x8*)&Bbuf[(rowbase + l0 + r) * D_STATE + n0 + cc];
        }
        __syncthreads();
        #pragma unroll
        for (int q = 0; q < 4; q++) {       // store transposed: BT[n][l]
            int lin = q * 256 + t;
            int rn = lin >> 4, cg = lin & 15;
            u16x4 v;
            #pragma unroll
            for (int e = 0; e < 4; e++) v[e] = tile[cg*4 + e][rn];
            *(u16x4*)&BTb[(size_t)(n0 + rn) * 256 + l0 + cg*4] = v;
        }
        return;
    }
    if (bid < 288) {                        // S precompute (r15 verified frag math)
        int p = (bid - 128) % 10, bc = (bid - 128) / 10;
        int q = (p >= 6) ? 3 : (p >= 3) ? 2 : (p >= 1) ? 1 : 0;
        int st = p - q * (q + 1) / 2;
        int b = bc >> 3, c = bc & 7;
        const int lane = t & 63, w = t >> 6;
        const int lr = lane & 15, kh = lane >> 4;
        const size_t rowbase = (size_t)(b * SEQ + c * CHUNK);

        f32x4 sacc[4];
        #pragma unroll
        for (int i = 0; i < 4; i++) sacc[i] = (f32x4){0.f,0.f,0.f,0.f};
        #pragma unroll
        for (int kk = 0; kk < 4; kk++) {
            bf16x8 bA = *(const bf16x8*)&Bbuf[(rowbase + st*64 + w*16 + lr) * D_STATE + kk*32 + kh*8];
            #pragma unroll
            for (int i = 0; i < 4; i++) {
                bf16x8 af = *(const bf16x8*)&Cbuf[(rowbase + q*64 + i*16 + lr) * D_STATE + kk*32 + kh*8];
                sacc[i] = __builtin_amdgcn_mfma_f32_16x16x32_bf16(bA, af, sacc[i], 0, 0, 0);
            }
        }
        u16* Sb = Sbuf + (size_t)bc * 256 * 256;
        #pragma unroll
        for (int i = 0; i < 4; i++) {
            u16x4 o;
            #pragma unroll
            for (int qq = 0; qq < 4; qq++) o[qq] = f2us(sacc[i][qq]);
            *(u16x4*)&Sb[(size_t)(q*64 + i*16 + lr) * 256 + st*64 + w*16 + kh*4] = o;
        }
        return;
    }
    // dt_acs
    {
        int blk = bid - 288;
        int c = blk & 7, h = (blk >> 3) & 63, b = blk >> 9;
        int lg = c * CHUNK + t;
        int row = b * SEQ + lg;
        const float* tb = &tailp[(size_t)row * 512 + 256 + h];
        float x = tb[0] + tb[TSTRIDE] + tb[2*TSTRIDE] + tb[3*TSTRIDE];
        x += dt_bias[h];
        float dt = (x > 20.f) ? x : log1pf(expf(x));
        float v = dt * Aparam[h];
        sb[t] = v; __syncthreads();
        #pragma unroll
        for (int off = 1; off < 256; off <<= 1) {
            float add = (t >= off) ? sb[t - off] : 0.f;
            __syncthreads();
            v += add; sb[t] = v;
            __syncthreads();
        }
        int o = (b * NHEADS + h) * SEQ + lg;
        dtT[o] = dt;
        Acs[o] = v;
    }
}

// ---------------- per-chunk states via MFMA; B^T staged by vector copies from BT ----------------
__global__ __launch_bounds__(256)
void chunk_states_mfma(const u16* __restrict__ xconv, const u16* __restrict__ BT,
                       const float* __restrict__ dtT, const float* __restrict__ Acs,
                       u16* __restrict__ states)
{
    __shared__ u16 Btsh[128][72];   // B^T [n][l]
    __shared__ u16 xtsh[64][72];    // (w*x)^T [p][l]
    __shared__ float acs_sh[CHUNK];
    __shared__ float dt_sh[CHUNK];

    const int blk = blockIdx.x;
    const int h = blk & 63, c = (blk >> 6) & 7, b = blk >> 9;
    const int t = threadIdx.x;
    const int lane = t & 63, w = t >> 6;
    const int wr = w >> 1, wc = w & 1;
    const int lr = lane & 15, kh = lane >> 4;
    const int bh = b * NHEADS + h;
    const int bc = b * NCHUNK + c;
    const size_t rowbase = (size_t)(b * SEQ + c * CHUNK);
    const u16* BTb = BT + (size_t)bc * 128 * 256;

    acs_sh[t] = Acs[(size_t)bh * SEQ + c * CHUNK + t];
    dt_sh[t]  = dtT[(size_t)bh * SEQ + c * CHUNK + t];
    __syncthreads();
    const float acs_last = acs_sh[CHUNK - 1];

    f32x4 acc[4][2];   // [j = n-block][i = p-block]
    #pragma unroll
    for (int j = 0; j < 4; j++)
        #pragma unroll
        for (int i = 0; i < 2; i++) acc[j][i] = (f32x4){0.f,0.f,0.f,0.f};

    for (int lt = 0; lt < 4; lt++) {
        __syncthreads();
        {   // B^T staging: vector copies from precomputed BT
            int n = t >> 1, lc = (t & 1) * 32;
            const u16* src = &BTb[(size_t)n * 256 + lt*64 + lc];
            #pragma unroll
            for (int q = 0; q < 4; q++)
                *(u16x8*)&Btsh[n][lc + q*8] = *(const u16x8*)&src[q*8];
        }
        {   // (w*x)^T staging, wgt folded
            const int s = t & 63;
            const int sg = lt * 64 + s;
            const float wgt = dt_sh[sg] * expf(acs_last - acs_sh[sg]);
            int pg = (t >> 6) * 16;
            const u16* src = &xconv[(rowbase + sg) * D_INNER + h * HEAD_DIM + pg];
            u16x8 v0 = *(const u16x8*)&src[0];
            u16x8 v1 = *(const u16x8*)&src[8];
            #pragma unroll
            for (int e = 0; e < 8; e++) {
                xtsh[pg + e][s]     = f2us(us2f(v0[e]) * wgt);
                xtsh[pg + 8 + e][s] = f2us(us2f(v1[e]) * wgt);
            }
        }
        __syncthreads();
        #pragma unroll
        for (int kk = 0; kk < 2; kk++) {
            bf16x8 xf[2], bf[4];
            #pragma unroll
            for (int i = 0; i < 2; i++)
                xf[i] = *(const bf16x8*)&xtsh[wr*32 + i*16 + lr][kk*32 + kh*8];
            #pragma unroll
            for (int j = 0; j < 4; j++)
                bf[j] = *(const bf16x8*)&Btsh[wc*64 + j*16 + lr][kk*32 + kh*8];
            #pragma unroll
            for (int j = 0; j < 4; j++)
                #pragma unroll
                for (int i = 0; i < 2; i++)
                    acc[j][i] = __builtin_amdgcn_mfma_f32_16x16x32_bf16(bf[j], xf[i], acc[j][i], 0, 0, 0);
        }
    }
    size_t base = ((size_t)(bc * NHEADS + h)) * (HEAD_DIM * D_STATE);
    #pragma unroll
    for (int j = 0; j < 4; j++) {
        #pragma unroll
        for (int i = 0; i < 2; i++) {
            int p = wr*32 + i*16 + lr;
            int n = wc*64 + j*16 + kh*4;
            u16x4 o;
            #pragma unroll
            for (int q = 0; q < 4; q++) o[q] = f2us(acc[j][i][q]);
            *(u16x4*)&states[base + (size_t)p * D_STATE + n] = o;
        }
    }
}

// ---------------- inter-chunk recurrence, bf16 states ----------------
__global__ __launch_bounds__(256)
void state_recurrence(u16* __restrict__ states, const float* __restrict__ Acs)
{
    int idx = blockIdx.x * 256 + threadIdx.x;
    int n8 = idx & 15;
    int p  = (idx >> 4) & 63;
    int bh = idx >> 10;
    int b = bh >> 6, h = bh & 63;
    float E[8];
    #pragma unroll
    for (int e = 0; e < 8; e++) E[e] = 0.f;
    for (int c = 0; c < NCHUNK; c++) {
        size_t off = ((size_t)((b*NCHUNK + c)*NHEADS + h)) * 8192 + (size_t)p * 128 + n8 * 8;
        u16x8 sv = *(const u16x8*)&states[off];
        u16x8 ev;
        #pragma unroll
        for (int e = 0; e < 8; e++) ev[e] = f2us(E[e]);
        *(u16x8*)&states[off] = ev;
        float g = expf(Acs[(size_t)(b*NHEADS + h) * SEQ + c*CHUNK + 255]);
        #pragma unroll
        for (int e = 0; e < 8; e++) E[e] = g * E[e] + us2f(sv[e]);
    }
}

// ---------------- chunk output: prev read from global; LDS 48 KB, 3 blocks/CU ----------------
__global__ __launch_bounds__(256, 3)
void chunk_output_mfma(const u16* __restrict__ xconv, const u16* __restrict__ Sbuf,
                       const u16* __restrict__ Cbuf, const float* __restrict__ dtT,
                       const float* __restrict__ Acs, const u16* __restrict__ states,
                       const float* __restrict__ Dparam, u16* __restrict__ Y)
{
    __shared__ u16 xt[64][72];         // x^T tile [p][s]
    __shared__ u16 Pt[4][64][72];      // per-wave P [l][s]
    __shared__ float acs_sh[CHUNK];
    __shared__ float dt_sh[CHUNK];

    const int blk = blockIdx.x;
    const int h = blk & 63, c = (blk >> 6) & 7, b = blk >> 9;
    const int t = threadIdx.x;
    const int lane = t & 63, w = t >> 6;
    const int lr = lane & 15, kh = lane >> 4;
    const int bh = b * NHEADS + h;
    const size_t rowbase = (size_t)(b * SEQ + c * CHUNK);
    const u16* Sblk = Sbuf + (size_t)(b * NCHUNK + c) * 256 * 256;
    const u16* prevg = &states[((size_t)((b*NCHUNK + c)*NHEADS + h)) * 8192];

    acs_sh[t] = Acs[(size_t)bh * SEQ + c * CHUNK + t];
    dt_sh[t]  = dtT[(size_t)bh * SEQ + c * CHUNK + t];

    bf16x8 af[4][4];
    #pragma unroll
    for (int i = 0; i < 4; i++)
        #pragma unroll
        for (int kk = 0; kk < 4; kk++)
            af[i][kk] = *(const bf16x8*)&Cbuf[(rowbase + w*64 + i*16 + lr) * D_STATE + kk*32 + kh*8];

    __syncthreads();
    float acs_l[4], el[4];
    #pragma unroll
    for (int i = 0; i < 4; i++) { acs_l[i] = acs_sh[w*64 + i*16 + lr]; el[i] = expf(acs_l[i]); }

    // Y_off raw: yacc[j][i] = prev . C (prev frags straight from global bf16 states)
    f32x4 yacc[4][4];
    #pragma unroll
    for (int j = 0; j < 4; j++)
        #pragma unroll
        for (int i = 0; i < 4; i++) yacc[j][i] = (f32x4){0.f,0.f,0.f,0.f};
    #pragma unroll
    for (int kk = 0; kk < 4; kk++) {
        bf16x8 pvA[4];
        #pragma unroll
        for (int j = 0; j < 4; j++)
            pvA[j] = *(const bf16x8*)&prevg[(size_t)(j*16 + lr) * 128 + kk*32 + kh*8];
        #pragma unroll
        for (int j = 0; j < 4; j++)
            #pragma unroll
            for (int i = 0; i < 4; i++)
                yacc[j][i] = __builtin_amdgcn_mfma_f32_16x16x32_bf16(pvA[j], af[i][kk], yacc[j][i], 0, 0, 0);
    }
    #pragma unroll
    for (int j = 0; j < 4; j++)
        #pragma unroll
        for (int i = 0; i < 4; i++)
            #pragma unroll
            for (int q = 0; q < 4; q++)
                yacc[j][i][q] *= el[i];

    for (int st = 0; st < 4; st++) {
        __syncthreads();
        {   // stage x^T tile [p][s]
            int s = t & 63, pg = t >> 6;
            const u16* src = &xconv[(rowbase + st*64 + s) * D_INNER + h*HEAD_DIM + pg*16];
            u16x8 v0 = *(const u16x8*)&src[0];
            u16x8 v1 = *(const u16x8*)&src[8];
            #pragma unroll
            for (int q = 0; q < 8; q++) { xt[pg*16 + q][s] = v0[q]; xt[pg*16 + 8 + q][s] = v1[q]; }
        }
        __syncthreads();
        if (st > w) continue;

        // P = mask(S) * dt, S loaded from head-shared Sbuf
        #pragma unroll
        for (int js = 0; js < 4; js++) {
            int s0 = st*64 + js*16;
            float as0 = acs_sh[s0];
            int sgq = s0 + kh*4;
            float eneg[4];
            #pragma unroll
            for (int q = 0; q < 4; q++)
                eneg[q] = expf(fminf(as0 - acs_sh[sgq + q], 60.f)) * dt_sh[sgq + q];
            #pragma unroll
            for (int i = 0; i < 4; i++) {
                int ll = w*64 + i*16 + lr;
                float eladj = expf(acs_l[i] - as0);
                u16x4 sv = *(const u16x4*)&Sblk[(size_t)ll * 256 + sgq];
                u16x4 pv;
                #pragma unroll
                for (int q = 0; q < 4; q++) {
                    float fac = (sgq + q <= ll) ? eladj * eneg[q] : 0.f;
                    pv[q] = f2us(us2f(sv[q]) * fac);
                }
                *(u16x4*)&Pt[w][i*16 + lr][js*16 + kh*4] = pv;
            }
        }
        #pragma unroll
        for (int kk2 = 0; kk2 < 2; kk2++) {
            bf16x8 xA[4], pB[4];
            #pragma unroll
            for (int j = 0; j < 4; j++)
                xA[j] = *(const bf16x8*)&xt[j*16 + lr][kk2*32 + kh*8];
            #pragma unroll
            for (int i = 0; i < 4; i++)
                pB[i] = *(const bf16x8*)&Pt[w][i*16 + lr][kk2*32 + kh*8];
            #pragma unroll
            for (int j = 0; j < 4; j++)
                #pragma unroll
                for (int i = 0; i < 4; i++)
                    yacc[j][i] = __builtin_amdgcn_mfma_f32_16x16x32_bf16(xA[j], pB[i], yacc[j][i], 0, 0, 0);
        }
    }

    float Dh = Dparam[h];
    #pragma unroll
    for (int i = 0; i < 4; i++) {
        #pragma unroll
        for (int j = 0; j < 4; j++) {
            size_t o = (rowbase + w*64 + i*16 + lr) * D_INNER + h*HEAD_DIM + j*16 + kh*4;
            u16x4 xv = *(const u16x4*)&xconv[o];
            u16x4 ov;
            #pragma unroll
            for (int q = 0; q < 4; q++)
                ov[q] = f2us(yacc[j][i][q] + Dh * us2f(xv[q]));
            *(u16x4*)&Y[o] = ov;
        }
    }
}

// ---------------- gated RMSNorm (register-resident) ----------------
__global__ __launch_bounds__(256)
void gated_rmsnorm_k(u16* __restrict__ Y, const u16* __restrict__ zx,
                     const float* __restrict__ nw)
{
    __shared__ float red[4];
    int row = blockIdx.x;
    int t = threadIdx.x;
    float x[16];
    float ss = 0.f;
    #pragma unroll
    for (int g = 0; g < 2; g++) {
        int i = g * 2048 + t * 8;
        u16x8 yv = *(const u16x8*)&Y[(size_t)row * D_INNER + i];
        u16x8 zv = *(const u16x8*)&zx[(size_t)row * LD_ZX + i];
        #pragma unroll
        for (int q = 0; q < 8; q++) {
            float xv = us2f(yv[q]) * siluf(us2f(zv[q]));
            x[g*8 + q] = xv;
            ss += xv * xv;
        }
    }
    #pragma unroll
    for (int off = 32; off > 0; off >>= 1) ss += __shfl_down(ss, off);
    int wid = t >> 6, lane = t & 63;
    if (lane == 0) red[wid] = ss;
    __syncthreads();
    float tot = red[0] + red[1] + red[2] + red[3];
    float sc = rsqrtf(tot / (float)D_INNER + EPS_RMS);
    #pragma unroll
    for (int g = 0; g < 2; g++) {
        int i = g * 2048 + t * 8;
        float4 w0 = *(const float4*)&nw[i];
        float4 w1 = *(const float4*)&nw[i + 4];
        float wv[8] = {w0.x, w0.y, w0.z, w0.w, w1.x, w1.y, w1.z, w1.w};
        u16x8 o;
        #pragma unroll
        for (int q = 0; q < 8; q++) o[q] = f2us(x[g*8 + q] * sc * wv[q]);
        *(u16x8*)&Y[(size_t)row * D_INNER + i] = o;
    }
}

__global__ void ws_fail_k(float* out, float mb){ out[threadIdx.x] = mb; }

// ---------------- launch ----------------
extern "C" void kernel_launch(void* const* d_in, const int* in_sizes, int n_in,
                              void* d_out, int out_size, void* d_ws, size_t ws_size,
                              hipStream_t stream)
{
    const float* hidden  = (const float*)d_in[0];
    const float* W_in    = (const float*)d_in[1];
    const float* conv_w  = (const float*)d_in[2];
    const float* conv_b  = (const float*)d_in[3];
    const float* Aparam  = (const float*)d_in[4];
    const float* Dparam  = (const float*)d_in[5];
    const float* dt_bias = (const float*)d_in[6];
    const float* norm_w  = (const float*)d_in[7];
    const float* W_out   = (const float*)d_in[8];
    float* out = (float*)d_out;

    const int M = BATCH * SEQ;  // 4096

    size_t off = 0;
    char* wsb = (char*)d_ws;
    u16*   zx     = (u16*)  (wsb + off); off += (size_t)M * LD_ZX * 2;
    u16*   xconv  = (u16*)  (wsb + off); off += (size_t)M * D_INNER * 2;
    u16*   Bbuf   = (u16*)  (wsb + off); off += (size_t)M * D_STATE * 2;
    u16*   Cbuf   = (u16*)  (wsb + off); off += (size_t)M * D_STATE * 2;
    float* dtT    = (float*)(wsb + off); off += (size_t)BATCH * NHEADS * SEQ * 4;
    float* Acs    = (float*)(wsb + off); off += (size_t)BATCH * NHEADS * SEQ * 4;
    u16*   states = (u16*)  (wsb + off); off += (size_t)BATCH * NCHUNK * NHEADS * HEAD_DIM * D_STATE * 2;
    u16*   Ybuf   = (u16*)  (wsb + off); off += (size_t)M * D_INNER * 2;
    u16*   hbf    = (u16*)  (wsb + off); off += (size_t)M * D_MODEL * 2;
    u16*   WtIn   = (u16*)  (wsb + off); off += (size_t)LD_ZX * D_MODEL * 2;
    u16*   WtOut  = (u16*)  (wsb + off); off += (size_t)D_MODEL * D_INNER * 2;
    float* tailp  = (float*)(wsb + off); off += 4 * TSTRIDE * 4;            // 33.5 MB
    u16*   Sbuf   = (u16*)  (wsb + off); off += (size_t)16 * 256 * 256 * 2; // 2 MB
    u16*   BT     = (u16*)  (wsb + off); off += (size_t)16 * 128 * 256 * 2; // 1 MB
    u16*   tmpf   = (u16*)zx;   // GEMM2 bf16 planes alias zx (dead after gated_rmsnorm)

    if (off > ws_size) {
        ws_fail_k<<<1, 64, 0, stream>>>(out, (float)(ws_size >> 20));
        return;
    }

    // fused preprocessing: hbf cvt (8192) + WtIn transpose (4352) + WtOut transpose (2048)
    prep_kernel<<<8192 + 4352 + 2048, 256, 0, stream>>>(hidden, hbf, W_in, WtIn, W_out, WtOut);

    // GEMM1 main: zx[:, 0:8192] — 512 blocks, 8x8 supertiled (FETCH 98 MB, r19)
    gemm_8ph<u16, false><<<(8192/256) * (M/256), 512, 0, stream>>>(
        hbf, WtIn, zx, nullptr, M, 8192, D_MODEL, D_MODEL, LD_ZX);
    // GEMM1 tail: cols [8192:8704] — K-split-4 f32 partials, consumed by conv/dt directly
    gemm_tail_ks4<<<512, 256, 0, stream>>>(hbf, WtIn + (size_t)8192 * D_MODEL, tailp, M, D_MODEL);

    conv_silu<<<(M * CONV_DIM / 8) / 256, 256, 0, stream>>>(zx, tailp, conv_w, conv_b, xconv, Bbuf, Cbuf);
    // bc_prep: BT transpose (128) + S precompute (160) + dt_acs (1024)
    bc_prep<<<128 + 160 + BATCH * NHEADS * NCHUNK, 256, 0, stream>>>(
        Bbuf, Cbuf, BT, Sbuf, tailp, Aparam, dt_bias, dtT, Acs);
    chunk_states_mfma<<<BATCH * NCHUNK * NHEADS, 256, 0, stream>>>(xconv, BT, dtT, Acs, states);
    state_recurrence<<<(BATCH * NHEADS * 64 * 16) / 256, 256, 0, stream>>>(states, Acs);
    chunk_output_mfma<<<BATCH * NCHUNK * NHEADS, 256, 0, stream>>>(xconv, Sbuf, Cbuf, dtT, Acs, states, Dparam, Ybuf);
    gated_rmsnorm_k<<<M, 256, 0, stream>>>(Ybuf, zx, norm_w);   // last reader of zx

    // GEMM2 K-split-2: 256 blocks = 1 CU-round; both halves bf16; out = t0 + t1
    gemm_8ph<float, true><<<2 * (D_MODEL/256) * (M/256), 512, 0, stream>>>(
        Ybuf, WtOut, out, tmpf, M, D_MODEL, D_INNER/2, D_INNER, D_MODEL);
    add2_bf16<<<(M * D_MODEL / 8 + 255) / 256, 256, 0, stream>>>(
        out, tmpf, tmpf + (size_t)M * D_MODEL, M * D_MODEL / 8);
}